// Round 11
// baseline (304.666 us; speedup 1.0000x reference)
//
#include <hip/hip_runtime.h>
#include <hip/hip_bf16.h>
#include <math.h>

typedef unsigned short u16;
typedef unsigned int   u32;
typedef __attribute__((ext_vector_type(8))) short short8;   // 8 bf16
typedef __attribute__((ext_vector_type(4))) float f32x4;    // MFMA acc

// Problem constants
constexpr int G  = 8;
constexpr int D  = 128;
constexpr int H  = 256;
constexpr int DM = 1024;
constexpr int PK = 1024;
constexpr int NTOK = 8 * 2048;   // 16384

// f32 param ws layout (floats): [0]pre_g(128) [128]pre_b(128) [256]b1(256)
// [512]b2(128) [640]pack_g(1024) [1664]pack_b(1024) [2688]bm(1024) -> 3712
constexpr int PF_N = 3712;

// ---------- scalar helpers ----------
__device__ __forceinline__ float bf2f(u16 u) {
    union { u32 i; float f; } v; v.i = ((u32)u) << 16; return v.f;
}
__device__ __forceinline__ u16 f2bf(float f) {
    union { float f; u32 i; } v; v.f = f;
    u32 x = v.i;
    return (u16)((x + 0x7fffu + ((x >> 16) & 1u)) >> 16);  // RNE
}
// packed f32x2 -> bf16x2 (RNE), single VALU op
__device__ __forceinline__ u32 pk_bf16(float lo, float hi) {
    u32 d;
    asm("v_cvt_pk_bf16_f32 %0, %1, %2" : "=v"(d) : "v"(lo), "v"(hi));
    return d;
}
__device__ __forceinline__ float f4c(const float4 v, int j) {
    return j == 0 ? v.x : j == 1 ? v.y : j == 2 ? v.z : v.w;
}
template <bool ISBF>
__device__ __forceinline__ float ld1(const void* p, size_t i) {
    if (ISBF) return bf2f(((const u16*)p)[i]);
    else      return ((const float*)p)[i];
}
template <bool ISBF>
__device__ __forceinline__ float4 ld4(const void* p, size_t i) {  // i % 4 == 0
    if (ISBF) {
        ushort4 v = *(const ushort4*)((const u16*)p + i);
        return make_float4(bf2f(v.x), bf2f(v.y), bf2f(v.z), bf2f(v.w));
    } else {
        return *(const float4*)((const float*)p + i);
    }
}
// runtime-dtype variants (uniform branch on flag)
__device__ __forceinline__ float ld1rt(const void* p, size_t i, bool isbf) {
    return isbf ? bf2f(((const u16*)p)[i]) : ((const float*)p)[i];
}
__device__ __forceinline__ float4 ld4rt(const void* p, size_t i, bool isbf) {
    if (isbf) {
        ushort4 v = *(const ushort4*)((const u16*)p + i);
        return make_float4(bf2f(v.x), bf2f(v.y), bf2f(v.z), bf2f(v.w));
    } else {
        return *(const float4*)((const float*)p + i);
    }
}
template <bool ISBF>
__device__ __forceinline__ void st4(void* p, size_t i, float4 v) {
    if (ISBF) {
        ushort4 o; o.x = f2bf(v.x); o.y = f2bf(v.y); o.z = f2bf(v.z); o.w = f2bf(v.w);
        *(ushort4*)((u16*)p + i) = o;
    } else {
        *(float4*)((float*)p + i) = v;
    }
}
__device__ __forceinline__ void st4rt(void* p, size_t i, float4 v, bool isbf) {
    if (isbf) {
        ushort4 o; o.x = f2bf(v.x); o.y = f2bf(v.y); o.z = f2bf(v.z); o.w = f2bf(v.w);
        *(ushort4*)((u16*)p + i) = o;
    } else {
        *(float4*)((float*)p + i) = v;
    }
}
// tanh-form GELU (max dev vs exact erf-GELU ~3e-4, tolerance 6.4e-2)
__device__ __forceinline__ float gelu_f(float v) {
    float u = v * (0.7978845608028654f + 0.0356774081f * v * v);
    float e = __expf(2.f * u);
    float th = 1.f - 2.f / (e + 1.f);
    return 0.5f * v * (1.f + th);
}
// async global->LDS, 16B per lane; LDS dest = wave-uniform base + lane*16
__device__ __forceinline__ void gload_lds16(const void* gp, void* lp) {
    __builtin_amdgcn_global_load_lds(
        (const __attribute__((address_space(1))) void*)gp,
        (__attribute__((address_space(3))) void*)lp, 16, 0, 0);
}

// ---------- dtype detect (proven R2) ----------
__global__ void detect_dtype(const void* xraw, int* flag) {
    __shared__ int cnt[256];
    const u32* xw = (const u32*)xraw;
    int tid = threadIdx.x, c = 0;
#pragma unroll
    for (int k = 0; k < 4; ++k) {
        u32 w = xw[tid * 4 + k];
#pragma unroll
        for (int h = 0; h < 2; ++h) {
            u16 u = (u16)(w >> (16 * h));
            int e = (u >> 7) & 0xFF;
            if ((u & 0x7FFF) == 0 || (e >= 112 && e <= 143)) ++c;
        }
    }
    cnt[tid] = c;
    __syncthreads();
    for (int s = 128; s > 0; s >>= 1) {
        if (tid < s) cnt[tid] += cnt[tid + s];
        __syncthreads();
    }
    if (tid == 0) flag[0] = (cnt[0] >= 1900) ? 1 : 0;
}

// ---------- gate pre-pass: xg = bf16(x * 2*sigmoid(slot_gate) + slot_bias) ----------
// Single dispatch (runtime isbf). Written into zws (aliased with z output).
__global__ __launch_bounds__(256)
void gatex(const void* __restrict__ x, const void* __restrict__ sg,
           const void* __restrict__ sb, u16* __restrict__ xg,
           const int* __restrict__ flag) {
    const bool isbf = (flag[0] != 0);
    const int tid = threadIdx.x, e0 = 4 * tid;
    float4 g4 = ld4rt(sg, e0, isbf);
    float4 b4 = ld4rt(sb, e0, isbf);
    float gf[4], bf[4];
#pragma unroll
    for (int j = 0; j < 4; ++j) {
        gf[j] = 2.f / (1.f + __expf(-f4c(g4, j)));
        bf[j] = f4c(b4, j);
    }
    const size_t tok0 = (size_t)blockIdx.x * 8;
#pragma unroll
    for (int t = 0; t < 8; ++t) {
        float4 x4 = ld4rt(x, (tok0 + t) * PK + e0, isbf);
        uint2 o;
        o.x = pk_bf16(f4c(x4, 0) * gf[0] + bf[0], f4c(x4, 1) * gf[1] + bf[1]);
        o.y = pk_bf16(f4c(x4, 2) * gf[2] + bf[2], f4c(x4, 3) * gf[3] + bf[3]);
        *(uint2*)(xg + (tok0 + t) * PK + e0) = o;
    }
}

// ---------- MFMA-path weight prep (single dispatch, runtime isbf) ----------
// blocks [0,256): Wm -> wmt (WmT, bf16) via LDS 64x64 tile transpose
// blocks [256,640): fragment-major conv weights + f32 param conversion.
__global__ __launch_bounds__(256)
void prep_mfma(const void* __restrict__ w1, const void* __restrict__ w2,
               const void* __restrict__ Wm,
               const void* __restrict__ pre_g, const void* __restrict__ pre_b,
               const void* __restrict__ b1, const void* __restrict__ b2,
               const void* __restrict__ pkg, const void* __restrict__ pkb,
               const void* __restrict__ bm,
               u16* __restrict__ w1p, u16* __restrict__ w2p,
               u16* __restrict__ wmt, float* __restrict__ pf,
               const int* __restrict__ flag) {
    const bool isbf = (flag[0] != 0);
    __shared__ u16 tile[64][72];
    const int tid = threadIdx.x;
    if (blockIdx.x < 256) {
        const int kk0 = (blockIdx.x >> 4) * 64, n0 = (blockIdx.x & 15) * 64;
        const int r = tid >> 2, q = tid & 3;
#pragma unroll
        for (int j4 = 0; j4 < 4; ++j4) {
            float4 v = ld4rt(Wm, (size_t)(kk0 + r) * DM + n0 + q * 16 + j4 * 4, isbf);
            tile[r][q * 16 + j4 * 4 + 0] = f2bf(v.x);
            tile[r][q * 16 + j4 * 4 + 1] = f2bf(v.y);
            tile[r][q * 16 + j4 * 4 + 2] = f2bf(v.z);
            tile[r][q * 16 + j4 * 4 + 3] = f2bf(v.w);
        }
        __syncthreads();
        u16 op[16];
#pragma unroll
        for (int j = 0; j < 16; ++j) op[j] = tile[q * 16 + j][r];
        u16* dst = wmt + (size_t)(n0 + r) * DM + kk0 + q * 16;
        *(short8*)dst       = *(const short8*)&op[0];
        *(short8*)(dst + 8) = *(const short8*)&op[8];
        return;
    }
    int idx = (blockIdx.x - 256) * 256 + tid;
    if (idx < 3 * 4 * H * 32) {          // 98304 for each of w1p/w2p
        int jq = idx & 31;
        int t2 = idx >> 5;
        int h  = t2 & (H - 1);
        int ik = t2 >> 8;                // 0..11
        int kt1 = ik >> 2, kk1 = ik & 3;
        int dd = kk1 * 32 + jq;
        w1p[idx] = f2bf(ld1rt(w1, (size_t)(h * D + dd) * 3 + kt1, isbf));
        int d   = t2 & (D - 1);
        int ik2 = t2 >> 7;               // 0..23
        int kt2 = ik2 >> 3, kk2 = ik2 & 7;
        int hh = kk2 * 32 + jq;
        w2p[idx] = f2bf(ld1rt(w2, (size_t)(d * H + hh) * 3 + kt2, isbf));
    }
    if (idx < D) {
        pf[idx]       = ld1rt(pre_g, idx, isbf);
        pf[128 + idx] = ld1rt(pre_b, idx, isbf);
        pf[512 + idx] = ld1rt(b2, idx, isbf);
    }
    if (idx < H) pf[256 + idx] = ld1rt(b1, idx, isbf);
    if (idx < PK) {
        pf[640  + idx] = ld1rt(pkg, idx, isbf);
        pf[1664 + idx] = ld1rt(pkb, idx, isbf);
        pf[2688 + idx] = ld1rt(bm, idx, isbf);
    }
}

// ---------- fused LN1+conv1+GELU+conv2+LN2 : xg (bf16) -> z (bf16, in place) ----------
// R10-proven: single dispatch, bf16 xg in, params f32 ws; 119 us, FETCH 18MB,
// WRITE 33MB. (256,3); (256,4) spills (R6/R9). DO NOT raise occupancy bound.
__global__ __launch_bounds__(256, 3)
void conv_fused(u16* __restrict__ xz,          // in: xg rows; out: z rows (aliased)
                const u16* __restrict__ w1p,
                const u16* __restrict__ w2p,
                const float* __restrict__ pf) {
    __shared__ u16 uni[74 * 256];          // 37888 B union
    __shared__ float red_s[8][4], red_ss[8][4];

    const int tid  = threadIdx.x;
    const int lane = tid & 63, w = tid >> 6;
    const int quad = lane >> 4, col = lane & 15;
    const size_t tok0 = (size_t)blockIdx.x * 8;

    // ---- stage 0: zero xnpad halo rows (9 x 128) + M_hi halo rows {45,54,63,72} ----
    if (tid < 72) {
        int li = tid * 16, hr = li >> 7, e = li & 127;
        u16* p = &uni[hr * 9 * 128 + e];
#pragma unroll
        for (int q = 0; q < 4; ++q) *(ushort4*)(p + 4 * q) = make_ushort4(0, 0, 0, 0);
    } else if (tid >= 128) {
        int li = (tid - 128) * 8, hr = li >> 8, e = li & 255;
        int row = 45 + hr * 9;                       // 45,54,63,72
        u16* p = &uni[row * 256 + 256 + e];          // M_hi mapping
        *(ushort4*)p       = make_ushort4(0, 0, 0, 0);
        *(ushort4*)(p + 4) = make_ushort4(0, 0, 0, 0);
    }

    const int e0 = 4 * tid;
    const int d0 = e0 & (D - 1);
    const int g0 = tid >> 5;
    float4 pg4s = *(const float4*)(pf + d0);        // pre_g
    float4 pb4s = *(const float4*)(pf + 128 + d0);  // pre_b

    // ---- stage 1: LN1 over pre-gated xg, write xn (bf16, swizzled) ----
#pragma unroll
    for (int t = 0; t < 8; ++t) {
        ushort4 xv = *(const ushort4*)(xz + (tok0 + t) * PK + e0);
        float v[4] = { bf2f(xv.x), bf2f(xv.y), bf2f(xv.z), bf2f(xv.w) };
        float s = v[0] + v[1] + v[2] + v[3];
        float ss = v[0]*v[0] + v[1]*v[1] + v[2]*v[2] + v[3]*v[3];
#pragma unroll
        for (int m = 1; m < 32; m <<= 1) {
            s  += __shfl_xor(s,  m);
            ss += __shfl_xor(ss, m);
        }
        float mean = s * (1.f / 128.f);
        float var  = ss * (1.f / 128.f) - mean * mean;
        float rstd = rsqrtf(var + 1e-5f);
        uint2 o;
        o.x = pk_bf16((v[0] - mean) * rstd * pg4s.x + pb4s.x,
                      (v[1] - mean) * rstd * pg4s.y + pb4s.y);
        o.y = pk_bf16((v[2] - mean) * rstd * pg4s.z + pb4s.z,
                      (v[3] - mean) * rstd * pg4s.w + pb4s.w);
        int row  = t * 9 + g0 + 1;
        int addr = row * 128 + (((d0 >> 3) ^ (row & 7)) << 3) + (d0 & 7);
        *(uint2*)&uni[addr] = o;
    }
    __syncthreads();

    int rowb[4];
#pragma unroll
    for (int nt = 0; nt < 4; ++nt) {
        int n = nt * 16 + col;
        rowb[nt] = (n >> 3) * 9 + (n & 7);
    }
    const int alane1 = (w * 64 + col) * 32 + quad * 8;
    const int alane2 = (w * 32 + col) * 32 + quad * 8;

    // ---- stage 2: conv1 via MFMA, two nt-passes (32-AGPR live acc each) ----
#pragma unroll
    for (int pass = 0; pass < 2; ++pass) {
        const int ntb = (pass == 0) ? 2 : 0;
        f32x4 acc[4][2] = {};
#pragma unroll
        for (int it = 0; it < 12; ++it) {
            const int ktap = it >> 2, kk = it & 3;
            short8 afr[4];
#pragma unroll
            for (int mtl = 0; mtl < 4; ++mtl)
                afr[mtl] = *(const short8*)(w1p + it * 8192 + mtl * 512 + alane1);
            short8 bfr[2];
#pragma unroll
            for (int ntl = 0; ntl < 2; ++ntl) {
                int rr = rowb[ntb + ntl] + ktap;
                int a  = rr * 128 + (((kk * 4 + quad) ^ (rr & 7)) << 3);
                bfr[ntl] = *(const short8*)&uni[a];
            }
#pragma unroll
            for (int mtl = 0; mtl < 4; ++mtl)
#pragma unroll
                for (int ntl = 0; ntl < 2; ++ntl)
                    acc[mtl][ntl] = __builtin_amdgcn_mfma_f32_16x16x32_bf16(
                        afr[mtl], bfr[ntl], acc[mtl][ntl], 0, 0, 0);
        }
        if (pass == 1) {
            __syncthreads();
            if (tid < 160) {
                int li = tid * 8, hr = li >> 8, e = li & 255;
                u16* p = &uni[hr * 9 * 256 + e];
                *(ushort4*)p       = make_ushort4(0, 0, 0, 0);
                *(ushort4*)(p + 4) = make_ushort4(0, 0, 0, 0);
            }
        }
#pragma unroll
        for (int mtl = 0; mtl < 4; ++mtl) {
            int hq = w * 64 + mtl * 16 + quad * 4;
            float4 b1q = *(const float4*)(pf + 256 + hq);
#pragma unroll
            for (int ntl = 0; ntl < 2; ++ntl) {
                int row = rowb[ntb + ntl] + 1;
                uint2 o;
                o.x = pk_bf16(gelu_f(acc[mtl][ntl][0] + b1q.x),
                              gelu_f(acc[mtl][ntl][1] + b1q.y));
                o.y = pk_bf16(gelu_f(acc[mtl][ntl][2] + b1q.z),
                              gelu_f(acc[mtl][ntl][3] + b1q.w));
                int mb = row * 256 + ((row >= 37) ? 256 : 0);
                int a  = mb + (((hq >> 3) ^ (row & 7)) << 3) + (hq & 7);
                *(uint2*)&uni[a] = o;
            }
        }
    }
    __syncthreads();

    // ---- stage 3: conv2 via MFMA + bias + residual + LN2 + pack ----
    f32x4 acc2[2][4] = {};
#pragma unroll
    for (int it = 0; it < 24; ++it) {
        const int ktap = it >> 3, kk = it & 7;
        short8 cfr[2];
#pragma unroll
        for (int mtl = 0; mtl < 2; ++mtl)
            cfr[mtl] = *(const short8*)(w2p + it * 4096 + mtl * 512 + alane2);
        short8 bfr[4];
#pragma unroll
        for (int nt = 0; nt < 4; ++nt) {
            int rr = rowb[nt] + ktap;
            int mb = rr * 256 + ((rr >= 37) ? 256 : 0);
            int a  = mb + (((kk * 4 + quad) ^ (rr & 7)) << 3);
            bfr[nt] = *(const short8*)&uni[a];
        }
#pragma unroll
        for (int mtl = 0; mtl < 2; ++mtl)
#pragma unroll
            for (int nt = 0; nt < 4; ++nt)
                acc2[mtl][nt] = __builtin_amdgcn_mfma_f32_16x16x32_bf16(
                    cfr[mtl], bfr[nt], acc2[mtl][nt], 0, 0, 0);
    }
    {
        float vals[2][4][4];
        float s[4] = {0.f, 0.f, 0.f, 0.f}, ss[4] = {0.f, 0.f, 0.f, 0.f};
#pragma unroll
        for (int mtl = 0; mtl < 2; ++mtl) {
            int dq = w * 32 + mtl * 16 + quad * 4;
            float4 b2q = *(const float4*)(pf + 512 + dq);
#pragma unroll
            for (int nt = 0; nt < 4; ++nt) {
                int n = nt * 16 + col; int t = n >> 3, g = n & 7;
                int e = g * D + dq;
                ushort4 xr = *(const ushort4*)(xz + (tok0 + t) * PK + e);
#pragma unroll
                for (int r = 0; r < 4; ++r) {
                    float resid = bf2f(((const u16*)&xr)[r]);
                    float val = acc2[mtl][nt][r] + f4c(b2q, r) + resid;
                    vals[mtl][nt][r] = val;
                    s[nt] += val; ss[nt] += val * val;
                }
            }
        }
#pragma unroll
        for (int nt = 0; nt < 4; ++nt) {
            s[nt] += __shfl_xor(s[nt], 1);  ss[nt] += __shfl_xor(ss[nt], 1);
            s[nt] += __shfl_xor(s[nt], 2);  ss[nt] += __shfl_xor(ss[nt], 2);
            s[nt] += __shfl_xor(s[nt], 4);  ss[nt] += __shfl_xor(ss[nt], 4);
            s[nt] += __shfl_xor(s[nt], 16); ss[nt] += __shfl_xor(ss[nt], 16);
            s[nt] += __shfl_xor(s[nt], 32); ss[nt] += __shfl_xor(ss[nt], 32);
        }
        if (quad == 0 && (col & 7) == 0) {
#pragma unroll
            for (int nt = 0; nt < 4; ++nt) {
                int t = 2 * nt + (col >> 3);
                red_s[t][w] = s[nt]; red_ss[t][w] = ss[nt];
            }
        }
        __syncthreads();   // also orders ALL xg reads before z overwrites below
        float mean[4], rstd[4];
#pragma unroll
        for (int nt = 0; nt < 4; ++nt) {
            int t = 2 * nt + (col >> 3);
            float st  = red_s[t][0] + red_s[t][1] + red_s[t][2] + red_s[t][3];
            float sst = red_ss[t][0] + red_ss[t][1] + red_ss[t][2] + red_ss[t][3];
            mean[nt] = st * (1.f / 1024.f);
            float var = sst * (1.f / 1024.f) - mean[nt] * mean[nt];
            rstd[nt] = rsqrtf(var + 1e-5f);
        }
#pragma unroll
        for (int mtl = 0; mtl < 2; ++mtl) {
            int dq = w * 32 + mtl * 16 + quad * 4;
#pragma unroll
            for (int nt = 0; nt < 4; ++nt) {
                int n = nt * 16 + col; int t = n >> 3, g = n & 7;
                int e = g * D + dq;
                float4 pg4 = *(const float4*)(pf + 640 + e);
                float4 pb4 = *(const float4*)(pf + 1664 + e);
                float zv[4];
#pragma unroll
                for (int r = 0; r < 4; ++r)
                    zv[r] = (vals[mtl][nt][r] - mean[nt]) * rstd[nt] * f4c(pg4, r)
                            + f4c(pb4, r);
                uint2 o;
                o.x = pk_bf16(zv[0], zv[1]);
                o.y = pk_bf16(zv[2], zv[3]);
                *(uint2*)(xz + (tok0 + t) * PK + e) = o;
            }
        }
    }
}

// ---------- z @ Wm + bm via MFMA ----------
// R11: double-buffered BK=32 + COUNTED vmcnt (T4) + raw s_barrier.
// Per iter: issue 4 gloads into nxt -> s_waitcnt vmcnt(4) (cur's loads done,
// nxt's stay IN FLIGHT across the barrier) -> s_barrier -> 8 ds_read + 16 MFMA
// -> lgkmcnt(0) + s_barrier (reads done before nxt-iter overwrites cur).
// NO vmcnt(0) in the main loop (the m97-ceiling stall). Chunk-XOR swizzle
// both-sides (src jj=(c&3)^(r&3); read chunk=quad^(row&3)).
// LDS 2x(8+8)KB = 32KB; (256,3) -> 3 blocks/CU, regs fit 170 cap.
__global__ __launch_bounds__(256, 3)
void gemm_out(const u16* __restrict__ z, const u16* __restrict__ wmt,
              const float* __restrict__ bmf, void* __restrict__ out,
              const int* __restrict__ flag) {
    const bool isbf = (flag[0] != 0);
    __shared__ u16 As[2][128 * 32];
    __shared__ u16 Bs[2][128 * 32];
    const int tid = threadIdx.x, lane = tid & 63, w = tid >> 6;
    const int quad = lane >> 4, col = lane & 15;
    // XCD-bijective swizzle (nwg = 1024, % 8 == 0)
    const int swz = ((blockIdx.x & 7) << 7) | ((int)blockIdx.x >> 3);
    const int bm0 = (swz >> 3) * 128, bn0 = (swz & 7) * 128;
    const int wm = w >> 1, wn = w & 1;
    f32x4 acc[4][4] = {};            // [nt][mt]

    const u16* zrow0 = z   + (size_t)bm0 * DM;
    const u16* wrow0 = wmt + (size_t)bn0 * DM;

    // stage one 128x32 tile pair: 512 chunks each, 2/thread -> 4 gloads/thread
    auto stage = [&](int buf, int k0) {
#pragma unroll
        for (int q = 0; q < 2; ++q) {
            int c = q * 256 + tid;
            int r = c >> 2;                    // row 0..127
            int jj = (c & 3) ^ (r & 3);        // pre-swizzled source chunk
            const int ldsoff = (q * 256 + w * 64) * 8;   // wave-uniform, u16
            gload_lds16(zrow0 + (size_t)r * DM + k0 + jj * 8, &As[buf][ldsoff]);
            gload_lds16(wrow0 + (size_t)r * DM + k0 + jj * 8, &Bs[buf][ldsoff]);
        }
    };

    stage(0, 0);
    asm volatile("s_waitcnt vmcnt(0)" ::: "memory");
    __builtin_amdgcn_s_barrier();
    for (int t = 0; t < 32; ++t) {
        const int cur = t & 1;
        if (t < 31) {
            stage(cur ^ 1, (t + 1) * 32);
            asm volatile("s_waitcnt vmcnt(4)" ::: "memory");   // cur done; nxt in flight
        } else {
            asm volatile("s_waitcnt vmcnt(0)" ::: "memory");
        }
        __builtin_amdgcn_s_barrier();          // all waves' cur tile landed
        __builtin_amdgcn_sched_barrier(0);
        short8 zfr[4], wfr[4];
#pragma unroll
        for (int mt = 0; mt < 4; ++mt) {
            int row = wm * 64 + mt * 16 + col;
            zfr[mt] = *(const short8*)
                &As[cur][row * 32 + ((quad ^ (row & 3)) << 3)];
        }
#pragma unroll
        for (int nt = 0; nt < 4; ++nt) {
            int row = wn * 64 + nt * 16 + col;
            wfr[nt] = *(const short8*)
                &Bs[cur][row * 32 + ((quad ^ (row & 3)) << 3)];
        }
#pragma unroll
        for (int nt = 0; nt < 4; ++nt)
#pragma unroll
            for (int mt = 0; mt < 4; ++mt)
                acc[nt][mt] = __builtin_amdgcn_mfma_f32_16x16x32_bf16(
                    wfr[nt], zfr[mt], acc[nt][mt], 0, 0, 0);
        asm volatile("s_waitcnt lgkmcnt(0)" ::: "memory");  // ds_reads retired
        __builtin_amdgcn_s_barrier();          // reads done before cur overwrite
    }
    // epilogue: C rows = n (quad*4+r), cols = m
#pragma unroll
    for (int nt = 0; nt < 4; ++nt) {
        int n = bn0 + wn * 64 + nt * 16 + quad * 4;
        float4 bq = *(const float4*)(bmf + n);
#pragma unroll
        for (int mt = 0; mt < 4; ++mt) {
            int m = bm0 + wm * 64 + mt * 16 + col;
            float4 o = make_float4(acc[nt][mt][0] + bq.x, acc[nt][mt][1] + bq.y,
                                   acc[nt][mt][2] + bq.z, acc[nt][mt][3] + bq.w);
            st4rt(out, (size_t)m * DM + n, o, isbf);
        }
    }
}

// ---------- scalar fallback (R2-proven), raw weights ----------
template <bool ISBF>
__global__ __launch_bounds__(256)
void slotconv_scalar(const void* __restrict__ x,
                     const void* __restrict__ slot_gate,
                     const void* __restrict__ slot_bias,
                     const void* __restrict__ pre_g,
                     const void* __restrict__ pre_b,
                     const void* __restrict__ w1raw,
                     const void* __restrict__ b1,
                     const void* __restrict__ w2raw,
                     const void* __restrict__ b2,
                     const void* __restrict__ pack_g,
                     const void* __restrict__ pack_b,
                     const void* __restrict__ Wm,
                     const void* __restrict__ bm,
                     void* __restrict__ out,
                     const int* __restrict__ flag) {
    if ((flag[0] != 0) != ISBF) return;
    __shared__ float resid[G * D];
    __shared__ float xnpadf[(G + 2) * D];
    __shared__ float midpadf[(G + 2) * H];
    __shared__ float zbuf[4][PK];
    __shared__ float red[8];
    const int tid = threadIdx.x;
    if (tid < D) { xnpadf[tid] = 0.f; xnpadf[(G + 1) * D + tid] = 0.f; }
    midpadf[tid] = 0.f; midpadf[(G + 1) * H + tid] = 0.f;
    const int e0 = 4 * tid;
    const int d0 = e0 & (D - 1);
    const int g0 = tid >> 5;
    float gate[4], bias[4], pgf[4], pbf[4];
    {
        float4 sg4 = ld4<ISBF>(slot_gate, e0);
        float4 sb4 = ld4<ISBF>(slot_bias, e0);
        float4 pg4 = ld4<ISBF>(pre_g, d0);
        float4 pb4 = ld4<ISBF>(pre_b, d0);
#pragma unroll
        for (int j = 0; j < 4; ++j) {
            gate[j] = 2.f / (1.f + __expf(-f4c(sg4, j)));
            bias[j] = f4c(sb4, j);
            pgf[j] = f4c(pg4, j); pbf[j] = f4c(pb4, j);
        }
    }
    for (int t = 0; t < 4; ++t) {
        __syncthreads();
        const size_t tok = (size_t)blockIdx.x * 4 + t;
        {
            float4 x4 = ld4<ISBF>(x, tok * PK + e0);
            float v[4];
#pragma unroll
            for (int j = 0; j < 4; ++j) v[j] = f4c(x4, j) * gate[j] + bias[j];
            *(float4*)&resid[e0] = make_float4(v[0], v[1], v[2], v[3]);
            float s = v[0]+v[1]+v[2]+v[3], ss = v[0]*v[0]+v[1]*v[1]+v[2]*v[2]+v[3]*v[3];
#pragma unroll
            for (int m = 1; m < 32; m <<= 1) { s += __shfl_xor(s, m); ss += __shfl_xor(ss, m); }
            float mean = s * (1.f/128.f), var = ss * (1.f/128.f) - mean*mean;
            float rstd = rsqrtf(var + 1e-5f);
            float xn[4];
#pragma unroll
            for (int j = 0; j < 4; ++j) xn[j] = (v[j]-mean)*rstd*pgf[j]+pbf[j];
            *(float4*)&xnpadf[(g0+1)*D + d0] = make_float4(xn[0],xn[1],xn[2],xn[3]);
        }
        __syncthreads();
        {
            const int h = tid;
            float acc[G];
#pragma unroll
            for (int g = 0; g < G; ++g) acc[g] = 0.f;
            for (int d4 = 0; d4 < D; d4 += 4) {
                float4 xr4[G + 2];
#pragma unroll
                for (int r = 0; r < G + 2; ++r) xr4[r] = *(const float4*)&xnpadf[r * D + d4];
#pragma unroll
                for (int j = 0; j < 4; ++j) {
                    size_t o = (size_t)h * (D * 3) + (d4 + j) * 3;
                    float wk0 = ld1<ISBF>(w1raw, o), wk1 = ld1<ISBF>(w1raw, o+1), wk2 = ld1<ISBF>(w1raw, o+2);
#pragma unroll
                    for (int g = 0; g < G; ++g) {
                        acc[g] += f4c(xr4[g+0], j) * wk0;
                        acc[g] += f4c(xr4[g+1], j) * wk1;
                        acc[g] += f4c(xr4[g+2], j) * wk2;
                    }
                }
            }
            float b1h = ld1<ISBF>(b1, tid);
#pragma unroll
            for (int g = 0; g < G; ++g) {
                float m = acc[g] + b1h;
                midpadf[(g+1)*H + h] = 0.5f * m * (1.f + erff(m * 0.70710678118654752f));
            }
        }
        __syncthreads();
        {
            const int dd = tid & (D - 1);
            const int gh = tid >> 7;
            float acc2[4] = {0.f,0.f,0.f,0.f};
            for (int h4 = 0; h4 < H; h4 += 4) {
                float4 mr4[6];
#pragma unroll
                for (int r = 0; r < 6; ++r) mr4[r] = *(const float4*)&midpadf[(gh*4+r)*H + h4];
#pragma unroll
                for (int j = 0; j < 4; ++j) {
                    size_t o = (size_t)dd * (H * 3) + (h4 + j) * 3;
                    float wk0 = ld1<ISBF>(w2raw, o), wk1 = ld1<ISBF>(w2raw, o+1), wk2 = ld1<ISBF>(w2raw, o+2);
#pragma unroll
                    for (int jj = 0; jj < 4; ++jj) {
                        acc2[jj] += f4c(mr4[jj+0], j) * wk0;
                        acc2[jj] += f4c(mr4[jj+1], j) * wk1;
                        acc2[jj] += f4c(mr4[jj+2], j) * wk2;
                    }
                }
            }
            float b2d = ld1<ISBF>(b2, dd);
            float vz[4], s = 0.f, ss = 0.f;
#pragma unroll
            for (int j = 0; j < 4; ++j) {
                int e = (gh*4+j)*D + dd;
                float val = acc2[j] + b2d + resid[e];
                vz[j] = val; s += val; ss += val*val;
            }
#pragma unroll
            for (int m = 1; m < 64; m <<= 1) { s += __shfl_xor(s, m); ss += __shfl_xor(ss, m); }
            const int wid = tid >> 6;
            if ((tid & 63) == 0) { red[wid*2] = s; red[wid*2+1] = ss; }
            __syncthreads();
            float st = red[0]+red[2]+red[4]+red[6], sst = red[1]+red[3]+red[5]+red[7];
            float mean = st * (1.f/1024.f), var = sst * (1.f/1024.f) - mean*mean;
            float rstd = rsqrtf(var + 1e-5f);
#pragma unroll
            for (int j = 0; j < 4; ++j) {
                int e = (gh*4+j)*D + dd;
                zbuf[t][e] = (vz[j]-mean)*rstd*ld1<ISBF>(pack_g, e) + ld1<ISBF>(pack_b, e);
            }
        }
    }
    __syncthreads();
    {
        float accm[4][4];
#pragma unroll
        for (int t = 0; t < 4; ++t)
#pragma unroll
            for (int j = 0; j < 4; ++j) accm[t][j] = 0.f;
        for (int p4 = 0; p4 < PK; p4 += 4) {
            float4 z4[4];
#pragma unroll
            for (int t = 0; t < 4; ++t) z4[t] = *(const float4*)&zbuf[t][p4];
#pragma unroll
            for (int pp = 0; pp < 4; ++pp) {
                float4 w4 = ld4<ISBF>(Wm, (size_t)(p4 + pp) * DM + e0);
#pragma unroll
                for (int t = 0; t < 4; ++t) {
                    float zp = f4c(z4[t], pp);
                    accm[t][0] += zp * w4.x; accm[t][1] += zp * w4.y;
                    accm[t][2] += zp * w4.z; accm[t][3] += zp * w4.w;
                }
            }
        }
        float4 bm4 = ld4<ISBF>(bm, e0);
#pragma unroll
        for (int t = 0; t < 4; ++t) {
            const size_t tok = (size_t)blockIdx.x * 4 + t;
            st4<ISBF>(out, tok * DM + e0,
                      make_float4(accm[t][0]+bm4.x, accm[t][1]+bm4.y,
                                  accm[t][2]+bm4.z, accm[t][3]+bm4.w));
        }
    }
}

extern "C" void kernel_launch(void* const* d_in, const int* in_sizes, int n_in,
                              void* d_out, int out_size, void* d_ws, size_t ws_size,
                              hipStream_t stream) {
    const void* x   = d_in[0];
    const void* sg  = d_in[1];
    const void* sb  = d_in[2];
    const void* pg  = d_in[3];
    const void* pb  = d_in[4];
    const void* w1  = d_in[5];
    const void* b1  = d_in[6];
    const void* w2  = d_in[7];
    const void* b2  = d_in[8];
    const void* pkg = d_in[9];
    const void* pkb = d_in[10];
    const void* Wm  = d_in[11];
    const void* bm  = d_in[12];

    int* flag = (int*)d_ws;
    u16* base = (u16*)((char*)d_ws + 16);
    u16* w1p = base;                       // 98304 el
    u16* w2p = base + 98304;               // 98304 el
    u16* wmt = base + 196608;              // 1048576 el
    u16* zws = base + 196608 + 1048576;    // 16777216 el (xg, then z, in place)
    float* pf = (float*)(base + 18022400); // 3712 f32 params
    const size_t ws_needed = 16 + (size_t)18022400 * sizeof(u16) + PF_N * sizeof(float);

    detect_dtype<<<1, 256, 0, stream>>>(x, flag);

    if (ws_size >= ws_needed) {
        prep_mfma<<<640, 256, 0, stream>>>(w1, w2, Wm, pg, pb, b1, b2, pkg, pkb, bm,
                                           w1p, w2p, wmt, pf, flag);
        gatex<<<NTOK / 8, 256, 0, stream>>>(x, sg, sb, zws, flag);
        conv_fused<<<NTOK / 8, 256, 0, stream>>>(zws, w1p, w2p, pf);
        gemm_out<<<(NTOK / 128) * (DM / 128), 256, 0, stream>>>(zws, wmt, pf + 2688, d_out, flag);
    } else {
        slotconv_scalar<true ><<<NTOK / 4, 256, 0, stream>>>(
            x, sg, sb, pg, pb, w1, b1, w2, b2, pkg, pkb, Wm, bm, d_out, flag);
        slotconv_scalar<false><<<NTOK / 4, 256, 0, stream>>>(
            x, sg, sb, pg, pb, w1, b1, w2, b2, pkg, pkb, Wm, bm, d_out, flag);
    }
}

// Round 12
// 294.328 us; speedup vs baseline: 1.0351x; 1.0351x over previous
//
#include <hip/hip_runtime.h>
#include <hip/hip_bf16.h>
#include <math.h>

typedef unsigned short u16;
typedef unsigned int   u32;
typedef __attribute__((ext_vector_type(8))) short short8;   // 8 bf16
typedef __attribute__((ext_vector_type(4))) float f32x4;    // MFMA acc

// Problem constants
constexpr int G  = 8;
constexpr int D  = 128;
constexpr int H  = 256;
constexpr int DM = 1024;
constexpr int PK = 1024;
constexpr int NTOK = 8 * 2048;   // 16384

// f32 param ws layout (floats): [0]pre_g(128) [128]pre_b(128) [256]b1(256)
// [512]b2(128) [640]pack_g(1024) [1664]pack_b(1024) [2688]bm(1024)
// [3712]gate=2*sigmoid(slot_gate)(1024) [4736]slot_bias(1024) -> 5760
constexpr int PF_N = 5760;

// ---------- scalar helpers ----------
__device__ __forceinline__ float bf2f(u16 u) {
    union { u32 i; float f; } v; v.i = ((u32)u) << 16; return v.f;
}
__device__ __forceinline__ u16 f2bf(float f) {
    union { float f; u32 i; } v; v.f = f;
    u32 x = v.i;
    return (u16)((x + 0x7fffu + ((x >> 16) & 1u)) >> 16);  // RNE
}
// packed f32x2 -> bf16x2 (RNE), single VALU op
__device__ __forceinline__ u32 pk_bf16(float lo, float hi) {
    u32 d;
    asm("v_cvt_pk_bf16_f32 %0, %1, %2" : "=v"(d) : "v"(lo), "v"(hi));
    return d;
}
__device__ __forceinline__ float f4c(const float4 v, int j) {
    return j == 0 ? v.x : j == 1 ? v.y : j == 2 ? v.z : v.w;
}
template <bool ISBF>
__device__ __forceinline__ float ld1(const void* p, size_t i) {
    if (ISBF) return bf2f(((const u16*)p)[i]);
    else      return ((const float*)p)[i];
}
template <bool ISBF>
__device__ __forceinline__ float4 ld4(const void* p, size_t i) {  // i % 4 == 0
    if (ISBF) {
        ushort4 v = *(const ushort4*)((const u16*)p + i);
        return make_float4(bf2f(v.x), bf2f(v.y), bf2f(v.z), bf2f(v.w));
    } else {
        return *(const float4*)((const float*)p + i);
    }
}
// runtime-dtype variants (uniform branch on flag)
__device__ __forceinline__ float ld1rt(const void* p, size_t i, bool isbf) {
    return isbf ? bf2f(((const u16*)p)[i]) : ((const float*)p)[i];
}
__device__ __forceinline__ float4 ld4rt(const void* p, size_t i, bool isbf) {
    if (isbf) {
        ushort4 v = *(const ushort4*)((const u16*)p + i);
        return make_float4(bf2f(v.x), bf2f(v.y), bf2f(v.z), bf2f(v.w));
    } else {
        return *(const float4*)((const float*)p + i);
    }
}
template <bool ISBF>
__device__ __forceinline__ void st4(void* p, size_t i, float4 v) {
    if (ISBF) {
        ushort4 o; o.x = f2bf(v.x); o.y = f2bf(v.y); o.z = f2bf(v.z); o.w = f2bf(v.w);
        *(ushort4*)((u16*)p + i) = o;
    } else {
        *(float4*)((float*)p + i) = v;
    }
}
__device__ __forceinline__ void st4rt(void* p, size_t i, float4 v, bool isbf) {
    if (isbf) {
        ushort4 o; o.x = f2bf(v.x); o.y = f2bf(v.y); o.z = f2bf(v.z); o.w = f2bf(v.w);
        *(ushort4*)((u16*)p + i) = o;
    } else {
        *(float4*)((float*)p + i) = v;
    }
}
// tanh-form GELU (max dev vs exact erf-GELU ~3e-4, tolerance 6.4e-2)
__device__ __forceinline__ float gelu_f(float v) {
    float u = v * (0.7978845608028654f + 0.0356774081f * v * v);
    float e = __expf(2.f * u);
    float th = 1.f - 2.f / (e + 1.f);
    return 0.5f * v * (1.f + th);
}
// async global->LDS, 16B per lane; LDS dest = wave-uniform base + lane*16
__device__ __forceinline__ void gload_lds16(const void* gp, void* lp) {
    __builtin_amdgcn_global_load_lds(
        (const __attribute__((address_space(1))) void*)gp,
        (__attribute__((address_space(3))) void*)lp, 16, 0, 0);
}

// ---------- dtype detect (proven R2) ----------
__global__ void detect_dtype(const void* xraw, int* flag) {
    __shared__ int cnt[256];
    const u32* xw = (const u32*)xraw;
    int tid = threadIdx.x, c = 0;
#pragma unroll
    for (int k = 0; k < 4; ++k) {
        u32 w = xw[tid * 4 + k];
#pragma unroll
        for (int h = 0; h < 2; ++h) {
            u16 u = (u16)(w >> (16 * h));
            int e = (u >> 7) & 0xFF;
            if ((u & 0x7FFF) == 0 || (e >= 112 && e <= 143)) ++c;
        }
    }
    cnt[tid] = c;
    __syncthreads();
    for (int s = 128; s > 0; s >>= 1) {
        if (tid < s) cnt[tid] += cnt[tid + s];
        __syncthreads();
    }
    if (tid == 0) flag[0] = (cnt[0] >= 1900) ? 1 : 0;
}

// ---------- MFMA-path weight prep (single dispatch, runtime isbf) ----------
// blocks [0,256): Wm -> wmt (WmT, bf16) via LDS 64x64 tile transpose
// blocks [256,640): fragment-major conv weights + f32 param conversion
// (incl. gate = 2*sigmoid(slot_gate) and slot_bias, both f32).
__global__ __launch_bounds__(256)
void prep_mfma(const void* __restrict__ w1, const void* __restrict__ w2,
               const void* __restrict__ Wm,
               const void* __restrict__ pre_g, const void* __restrict__ pre_b,
               const void* __restrict__ b1, const void* __restrict__ b2,
               const void* __restrict__ pkg, const void* __restrict__ pkb,
               const void* __restrict__ bm,
               const void* __restrict__ sg, const void* __restrict__ sb,
               u16* __restrict__ w1p, u16* __restrict__ w2p,
               u16* __restrict__ wmt, float* __restrict__ pf,
               const int* __restrict__ flag) {
    const bool isbf = (flag[0] != 0);
    __shared__ u16 tile[64][72];
    const int tid = threadIdx.x;
    if (blockIdx.x < 256) {
        const int kk0 = (blockIdx.x >> 4) * 64, n0 = (blockIdx.x & 15) * 64;
        const int r = tid >> 2, q = tid & 3;
#pragma unroll
        for (int j4 = 0; j4 < 4; ++j4) {
            float4 v = ld4rt(Wm, (size_t)(kk0 + r) * DM + n0 + q * 16 + j4 * 4, isbf);
            tile[r][q * 16 + j4 * 4 + 0] = f2bf(v.x);
            tile[r][q * 16 + j4 * 4 + 1] = f2bf(v.y);
            tile[r][q * 16 + j4 * 4 + 2] = f2bf(v.z);
            tile[r][q * 16 + j4 * 4 + 3] = f2bf(v.w);
        }
        __syncthreads();
        u16 op[16];
#pragma unroll
        for (int j = 0; j < 16; ++j) op[j] = tile[q * 16 + j][r];
        u16* dst = wmt + (size_t)(n0 + r) * DM + kk0 + q * 16;
        *(short8*)dst       = *(const short8*)&op[0];
        *(short8*)(dst + 8) = *(const short8*)&op[8];
        return;
    }
    int idx = (blockIdx.x - 256) * 256 + tid;
    if (idx < 3 * 4 * H * 32) {          // 98304 for each of w1p/w2p
        int jq = idx & 31;
        int t2 = idx >> 5;
        int h  = t2 & (H - 1);
        int ik = t2 >> 8;                // 0..11
        int kt1 = ik >> 2, kk1 = ik & 3;
        int dd = kk1 * 32 + jq;
        w1p[idx] = f2bf(ld1rt(w1, (size_t)(h * D + dd) * 3 + kt1, isbf));
        int d   = t2 & (D - 1);
        int ik2 = t2 >> 7;               // 0..23
        int kt2 = ik2 >> 3, kk2 = ik2 & 7;
        int hh = kk2 * 32 + jq;
        w2p[idx] = f2bf(ld1rt(w2, (size_t)(d * H + hh) * 3 + kt2, isbf));
    }
    if (idx < D) {
        pf[idx]       = ld1rt(pre_g, idx, isbf);
        pf[128 + idx] = ld1rt(pre_b, idx, isbf);
        pf[512 + idx] = ld1rt(b2, idx, isbf);
    }
    if (idx < H) pf[256 + idx] = ld1rt(b1, idx, isbf);
    if (idx < PK) {
        pf[640  + idx] = ld1rt(pkg, idx, isbf);
        pf[1664 + idx] = ld1rt(pkb, idx, isbf);
        pf[2688 + idx] = ld1rt(bm, idx, isbf);
        pf[3712 + idx] = 2.f / (1.f + __expf(-ld1rt(sg, idx, isbf)));
        pf[4736 + idx] = ld1rt(sb, idx, isbf);
    }
}

// ---------- fused gate+LN1+conv1+GELU+conv2+LN2 : x -> z (bf16, into zws) ----------
// R12: gatex fused into stage 1. conv reads x (raw dtype, runtime isbf) ONCE,
// writes xg=bf16(x*gate+sbias) to zws (for the epilogue residual; lines stay
// L2-resident, re-read + overwritten by z before eviction), and LN1s the f32
// gated values. Epilogue reads xg (L2-hot) and overwrites with z.
// Cross-thread xg visibility: stage-1 global stores are drained by the
// __syncthreads (vmcnt(0)) before any epilogue read; addresses never L1-cached
// earlier in this kernel. Block-private token rows -> no cross-block hazard.
// (256,3) PROVEN; (256,4) spills (R6/R9). Gate regs die before MFMA sections.
__global__ __launch_bounds__(256, 3)
void conv_fused(const void* __restrict__ x,
                u16* __restrict__ xz,          // xg staging, then z out (aliased)
                const u16* __restrict__ w1p,
                const u16* __restrict__ w2p,
                const float* __restrict__ pf,
                const int* __restrict__ flag) {
    const bool isbf = (flag[0] != 0);
    __shared__ u16 uni[74 * 256];          // 37888 B union
    __shared__ float red_s[8][4], red_ss[8][4];

    const int tid  = threadIdx.x;
    const int lane = tid & 63, w = tid >> 6;
    const int quad = lane >> 4, col = lane & 15;
    const size_t tok0 = (size_t)blockIdx.x * 8;

    // ---- stage 0: zero xnpad halo rows (9 x 128) + M_hi halo rows {45,54,63,72} ----
    if (tid < 72) {
        int li = tid * 16, hr = li >> 7, e = li & 127;
        u16* p = &uni[hr * 9 * 128 + e];
#pragma unroll
        for (int q = 0; q < 4; ++q) *(ushort4*)(p + 4 * q) = make_ushort4(0, 0, 0, 0);
    } else if (tid >= 128) {
        int li = (tid - 128) * 8, hr = li >> 8, e = li & 255;
        int row = 45 + hr * 9;                       // 45,54,63,72
        u16* p = &uni[row * 256 + 256 + e];          // M_hi mapping
        *(ushort4*)p       = make_ushort4(0, 0, 0, 0);
        *(ushort4*)(p + 4) = make_ushort4(0, 0, 0, 0);
    }

    const int e0 = 4 * tid;
    const int d0 = e0 & (D - 1);
    const int g0 = tid >> 5;
    float4 gg   = *(const float4*)(pf + 3712 + e0);   // 2*sigmoid(slot_gate)
    float4 sbb  = *(const float4*)(pf + 4736 + e0);   // slot_bias
    float4 pg4s = *(const float4*)(pf + d0);          // pre_g
    float4 pb4s = *(const float4*)(pf + 128 + d0);    // pre_b

    // ---- stage 1: gate+bias (f32), stash xg -> global, LN1 -> xnpad ----
#pragma unroll
    for (int t = 0; t < 8; ++t) {
        float4 x4 = ld4rt(x, (tok0 + t) * PK + e0, isbf);
        float v[4];
#pragma unroll
        for (int j = 0; j < 4; ++j) v[j] = f4c(x4, j) * f4c(gg, j) + f4c(sbb, j);
        uint2 og;
        og.x = pk_bf16(v[0], v[1]);
        og.y = pk_bf16(v[2], v[3]);
        *(uint2*)(xz + (tok0 + t) * PK + e0) = og;    // xg for epilogue resid
        float s = v[0] + v[1] + v[2] + v[3];
        float ss = v[0]*v[0] + v[1]*v[1] + v[2]*v[2] + v[3]*v[3];
#pragma unroll
        for (int m = 1; m < 32; m <<= 1) {
            s  += __shfl_xor(s,  m);
            ss += __shfl_xor(ss, m);
        }
        float mean = s * (1.f / 128.f);
        float var  = ss * (1.f / 128.f) - mean * mean;
        float rstd = rsqrtf(var + 1e-5f);
        uint2 o;
        o.x = pk_bf16((v[0] - mean) * rstd * pg4s.x + pb4s.x,
                      (v[1] - mean) * rstd * pg4s.y + pb4s.y);
        o.y = pk_bf16((v[2] - mean) * rstd * pg4s.z + pb4s.z,
                      (v[3] - mean) * rstd * pg4s.w + pb4s.w);
        int row  = t * 9 + g0 + 1;
        int addr = row * 128 + (((d0 >> 3) ^ (row & 7)) << 3) + (d0 & 7);
        *(uint2*)&uni[addr] = o;
    }
    __syncthreads();   // LDS ready AND xg stores drained (vmcnt(0))

    int rowb[4];
#pragma unroll
    for (int nt = 0; nt < 4; ++nt) {
        int n = nt * 16 + col;
        rowb[nt] = (n >> 3) * 9 + (n & 7);
    }
    const int alane1 = (w * 64 + col) * 32 + quad * 8;
    const int alane2 = (w * 32 + col) * 32 + quad * 8;

    // ---- stage 2: conv1 via MFMA, two nt-passes (32-AGPR live acc each) ----
#pragma unroll
    for (int pass = 0; pass < 2; ++pass) {
        const int ntb = (pass == 0) ? 2 : 0;
        f32x4 acc[4][2] = {};
#pragma unroll
        for (int it = 0; it < 12; ++it) {
            const int ktap = it >> 2, kk = it & 3;
            short8 afr[4];
#pragma unroll
            for (int mtl = 0; mtl < 4; ++mtl)
                afr[mtl] = *(const short8*)(w1p + it * 8192 + mtl * 512 + alane1);
            short8 bfr[2];
#pragma unroll
            for (int ntl = 0; ntl < 2; ++ntl) {
                int rr = rowb[ntb + ntl] + ktap;
                int a  = rr * 128 + (((kk * 4 + quad) ^ (rr & 7)) << 3);
                bfr[ntl] = *(const short8*)&uni[a];
            }
#pragma unroll
            for (int mtl = 0; mtl < 4; ++mtl)
#pragma unroll
                for (int ntl = 0; ntl < 2; ++ntl)
                    acc[mtl][ntl] = __builtin_amdgcn_mfma_f32_16x16x32_bf16(
                        afr[mtl], bfr[ntl], acc[mtl][ntl], 0, 0, 0);
        }
        if (pass == 1) {
            __syncthreads();
            if (tid < 160) {
                int li = tid * 8, hr = li >> 8, e = li & 255;
                u16* p = &uni[hr * 9 * 256 + e];
                *(ushort4*)p       = make_ushort4(0, 0, 0, 0);
                *(ushort4*)(p + 4) = make_ushort4(0, 0, 0, 0);
            }
        }
#pragma unroll
        for (int mtl = 0; mtl < 4; ++mtl) {
            int hq = w * 64 + mtl * 16 + quad * 4;
            float4 b1q = *(const float4*)(pf + 256 + hq);
#pragma unroll
            for (int ntl = 0; ntl < 2; ++ntl) {
                int row = rowb[ntb + ntl] + 1;
                uint2 o;
                o.x = pk_bf16(gelu_f(acc[mtl][ntl][0] + b1q.x),
                              gelu_f(acc[mtl][ntl][1] + b1q.y));
                o.y = pk_bf16(gelu_f(acc[mtl][ntl][2] + b1q.z),
                              gelu_f(acc[mtl][ntl][3] + b1q.w));
                int mb = row * 256 + ((row >= 37) ? 256 : 0);
                int a  = mb + (((hq >> 3) ^ (row & 7)) << 3) + (hq & 7);
                *(uint2*)&uni[a] = o;
            }
        }
    }
    __syncthreads();

    // ---- stage 3: conv2 via MFMA + bias + residual + LN2 + pack ----
    f32x4 acc2[2][4] = {};
#pragma unroll
    for (int it = 0; it < 24; ++it) {
        const int ktap = it >> 3, kk = it & 7;
        short8 cfr[2];
#pragma unroll
        for (int mtl = 0; mtl < 2; ++mtl)
            cfr[mtl] = *(const short8*)(w2p + it * 4096 + mtl * 512 + alane2);
        short8 bfr[4];
#pragma unroll
        for (int nt = 0; nt < 4; ++nt) {
            int rr = rowb[nt] + ktap;
            int mb = rr * 256 + ((rr >= 37) ? 256 : 0);
            int a  = mb + (((kk * 4 + quad) ^ (rr & 7)) << 3);
            bfr[nt] = *(const short8*)&uni[a];
        }
#pragma unroll
        for (int mtl = 0; mtl < 2; ++mtl)
#pragma unroll
            for (int nt = 0; nt < 4; ++nt)
                acc2[mtl][nt] = __builtin_amdgcn_mfma_f32_16x16x32_bf16(
                    cfr[mtl], bfr[nt], acc2[mtl][nt], 0, 0, 0);
    }
    {
        float vals[2][4][4];
        float s[4] = {0.f, 0.f, 0.f, 0.f}, ss[4] = {0.f, 0.f, 0.f, 0.f};
#pragma unroll
        for (int mtl = 0; mtl < 2; ++mtl) {
            int dq = w * 32 + mtl * 16 + quad * 4;
            float4 b2q = *(const float4*)(pf + 512 + dq);
#pragma unroll
            for (int nt = 0; nt < 4; ++nt) {
                int n = nt * 16 + col; int t = n >> 3, g = n & 7;
                int e = g * D + dq;
                ushort4 xr = *(const ushort4*)(xz + (tok0 + t) * PK + e);
#pragma unroll
                for (int r = 0; r < 4; ++r) {
                    float resid = bf2f(((const u16*)&xr)[r]);
                    float val = acc2[mtl][nt][r] + f4c(b2q, r) + resid;
                    vals[mtl][nt][r] = val;
                    s[nt] += val; ss[nt] += val * val;
                }
            }
        }
#pragma unroll
        for (int nt = 0; nt < 4; ++nt) {
            s[nt] += __shfl_xor(s[nt], 1);  ss[nt] += __shfl_xor(ss[nt], 1);
            s[nt] += __shfl_xor(s[nt], 2);  ss[nt] += __shfl_xor(ss[nt], 2);
            s[nt] += __shfl_xor(s[nt], 4);  ss[nt] += __shfl_xor(ss[nt], 4);
            s[nt] += __shfl_xor(s[nt], 16); ss[nt] += __shfl_xor(ss[nt], 16);
            s[nt] += __shfl_xor(s[nt], 32); ss[nt] += __shfl_xor(ss[nt], 32);
        }
        if (quad == 0 && (col & 7) == 0) {
#pragma unroll
            for (int nt = 0; nt < 4; ++nt) {
                int t = 2 * nt + (col >> 3);
                red_s[t][w] = s[nt]; red_ss[t][w] = ss[nt];
            }
        }
        __syncthreads();   // also orders ALL xg reads before z overwrites below
        float mean[4], rstd[4];
#pragma unroll
        for (int nt = 0; nt < 4; ++nt) {
            int t = 2 * nt + (col >> 3);
            float st  = red_s[t][0] + red_s[t][1] + red_s[t][2] + red_s[t][3];
            float sst = red_ss[t][0] + red_ss[t][1] + red_ss[t][2] + red_ss[t][3];
            mean[nt] = st * (1.f / 1024.f);
            float var = sst * (1.f / 1024.f) - mean[nt] * mean[nt];
            rstd[nt] = rsqrtf(var + 1e-5f);
        }
#pragma unroll
        for (int mtl = 0; mtl < 2; ++mtl) {
            int dq = w * 32 + mtl * 16 + quad * 4;
#pragma unroll
            for (int nt = 0; nt < 4; ++nt) {
                int n = nt * 16 + col; int t = n >> 3, g = n & 7;
                int e = g * D + dq;
                float4 pg4 = *(const float4*)(pf + 640 + e);
                float4 pb4 = *(const float4*)(pf + 1664 + e);
                float zv[4];
#pragma unroll
                for (int r = 0; r < 4; ++r)
                    zv[r] = (vals[mtl][nt][r] - mean[nt]) * rstd[nt] * f4c(pg4, r)
                            + f4c(pb4, r);
                uint2 o;
                o.x = pk_bf16(zv[0], zv[1]);
                o.y = pk_bf16(zv[2], zv[3]);
                *(uint2*)(xz + (tok0 + t) * PK + e) = o;
            }
        }
    }
}

// ---------- z @ Wm + bm via MFMA ----------
// R8/R10-PROVEN config (R11's counted-vmcnt graft was null-to-negative;
// reverted): BK=64 single-buffer, 16 K-steps, 32 MFMA per barrier-drain,
// both-sides chunk-XOR swizzle (rule #21), (256,3), 32KB LDS.
__global__ __launch_bounds__(256, 3)
void gemm_out(const u16* __restrict__ z, const u16* __restrict__ wmt,
              const float* __restrict__ bmf, void* __restrict__ out,
              const int* __restrict__ flag) {
    const bool isbf = (flag[0] != 0);
    __shared__ u16 As[128 * 64];   // z tile   [m][k], chunk-swizzled contents
    __shared__ u16 Bs[128 * 64];   // WmT tile [n][k], chunk-swizzled contents
    const int tid = threadIdx.x, lane = tid & 63, w = tid >> 6;
    const int quad = lane >> 4, col = lane & 15;
    // XCD-bijective swizzle (nwg = 1024, % 8 == 0)
    const int swz = ((blockIdx.x & 7) << 7) | ((int)blockIdx.x >> 3);
    const int bm0 = (swz >> 3) * 128, bn0 = (swz & 7) * 128;
    const int wm = w >> 1, wn = w & 1;
    f32x4 acc[4][4] = {};            // [nt][mt]

    const u16* zrow0 = z   + (size_t)bm0 * DM;
    const u16* wrow0 = wmt + (size_t)bn0 * DM;

    for (int k0 = 0; k0 < DM; k0 += 64) {
#pragma unroll
        for (int q = 0; q < 4; ++q) {
            int c = q * 256 + tid;
            int r = c >> 3;                    // row 0..127
            int jj = (c & 7) ^ (r & 7);        // pre-swizzled source chunk
            const int ldsoff = (q * 256 + w * 64) * 8;   // wave-uniform, u16
            gload_lds16(zrow0 + (size_t)r * DM + k0 + jj * 8, &As[ldsoff]);
            gload_lds16(wrow0 + (size_t)r * DM + k0 + jj * 8, &Bs[ldsoff]);
        }
        __syncthreads();   // vmcnt(0) drain + barrier: tile ready
#pragma unroll
        for (int kk = 0; kk < 2; ++kk) {
            short8 zfr[4], wfr[4];
#pragma unroll
            for (int mt = 0; mt < 4; ++mt) {
                int row = wm * 64 + mt * 16 + col;
                zfr[mt] = *(const short8*)
                    &As[row * 64 + (((kk * 4 + quad) ^ (row & 7)) << 3)];
            }
#pragma unroll
            for (int nt = 0; nt < 4; ++nt) {
                int row = wn * 64 + nt * 16 + col;
                wfr[nt] = *(const short8*)
                    &Bs[row * 64 + (((kk * 4 + quad) ^ (row & 7)) << 3)];
            }
#pragma unroll
            for (int nt = 0; nt < 4; ++nt)
#pragma unroll
                for (int mt = 0; mt < 4; ++mt)
                    acc[nt][mt] = __builtin_amdgcn_mfma_f32_16x16x32_bf16(
                        wfr[nt], zfr[mt], acc[nt][mt], 0, 0, 0);
        }
        __syncthreads();   // all reads done before next stage overwrites
    }
    // epilogue: C rows = n (quad*4+r), cols = m
#pragma unroll
    for (int nt = 0; nt < 4; ++nt) {
        int n = bn0 + wn * 64 + nt * 16 + quad * 4;
        float4 bq = *(const float4*)(bmf + n);
#pragma unroll
        for (int mt = 0; mt < 4; ++mt) {
            int m = bm0 + wm * 64 + mt * 16 + col;
            float4 o = make_float4(acc[nt][mt][0] + bq.x, acc[nt][mt][1] + bq.y,
                                   acc[nt][mt][2] + bq.z, acc[nt][mt][3] + bq.w);
            st4rt(out, (size_t)m * DM + n, o, isbf);
        }
    }
}

// ---------- scalar fallback (R2-proven), raw weights ----------
template <bool ISBF>
__global__ __launch_bounds__(256)
void slotconv_scalar(const void* __restrict__ x,
                     const void* __restrict__ slot_gate,
                     const void* __restrict__ slot_bias,
                     const void* __restrict__ pre_g,
                     const void* __restrict__ pre_b,
                     const void* __restrict__ w1raw,
                     const void* __restrict__ b1,
                     const void* __restrict__ w2raw,
                     const void* __restrict__ b2,
                     const void* __restrict__ pack_g,
                     const void* __restrict__ pack_b,
                     const void* __restrict__ Wm,
                     const void* __restrict__ bm,
                     void* __restrict__ out,
                     const int* __restrict__ flag) {
    if ((flag[0] != 0) != ISBF) return;
    __shared__ float resid[G * D];
    __shared__ float xnpadf[(G + 2) * D];
    __shared__ float midpadf[(G + 2) * H];
    __shared__ float zbuf[4][PK];
    __shared__ float red[8];
    const int tid = threadIdx.x;
    if (tid < D) { xnpadf[tid] = 0.f; xnpadf[(G + 1) * D + tid] = 0.f; }
    midpadf[tid] = 0.f; midpadf[(G + 1) * H + tid] = 0.f;
    const int e0 = 4 * tid;
    const int d0 = e0 & (D - 1);
    const int g0 = tid >> 5;
    float gate[4], bias[4], pgf[4], pbf[4];
    {
        float4 sg4 = ld4<ISBF>(slot_gate, e0);
        float4 sb4 = ld4<ISBF>(slot_bias, e0);
        float4 pg4 = ld4<ISBF>(pre_g, d0);
        float4 pb4 = ld4<ISBF>(pre_b, d0);
#pragma unroll
        for (int j = 0; j < 4; ++j) {
            gate[j] = 2.f / (1.f + __expf(-f4c(sg4, j)));
            bias[j] = f4c(sb4, j);
            pgf[j] = f4c(pg4, j); pbf[j] = f4c(pb4, j);
        }
    }
    for (int t = 0; t < 4; ++t) {
        __syncthreads();
        const size_t tok = (size_t)blockIdx.x * 4 + t;
        {
            float4 x4 = ld4<ISBF>(x, tok * PK + e0);
            float v[4];
#pragma unroll
            for (int j = 0; j < 4; ++j) v[j] = f4c(x4, j) * gate[j] + bias[j];
            *(float4*)&resid[e0] = make_float4(v[0], v[1], v[2], v[3]);
            float s = v[0]+v[1]+v[2]+v[3], ss = v[0]*v[0]+v[1]*v[1]+v[2]*v[2]+v[3]*v[3];
#pragma unroll
            for (int m = 1; m < 32; m <<= 1) { s += __shfl_xor(s, m); ss += __shfl_xor(ss, m); }
            float mean = s * (1.f/128.f), var = ss * (1.f/128.f) - mean*mean;
            float rstd = rsqrtf(var + 1e-5f);
            float xn[4];
#pragma unroll
            for (int j = 0; j < 4; ++j) xn[j] = (v[j]-mean)*rstd*pgf[j]+pbf[j];
            *(float4*)&xnpadf[(g0+1)*D + d0] = make_float4(xn[0],xn[1],xn[2],xn[3]);
        }
        __syncthreads();
        {
            const int h = tid;
            float acc[G];
#pragma unroll
            for (int g = 0; g < G; ++g) acc[g] = 0.f;
            for (int d4 = 0; d4 < D; d4 += 4) {
                float4 xr4[G + 2];
#pragma unroll
                for (int r = 0; r < G + 2; ++r) xr4[r] = *(const float4*)&xnpadf[r * D + d4];
#pragma unroll
                for (int j = 0; j < 4; ++j) {
                    size_t o = (size_t)h * (D * 3) + (d4 + j) * 3;
                    float wk0 = ld1<ISBF>(w1raw, o), wk1 = ld1<ISBF>(w1raw, o+1), wk2 = ld1<ISBF>(w1raw, o+2);
#pragma unroll
                    for (int g = 0; g < G; ++g) {
                        acc[g] += f4c(xr4[g+0], j) * wk0;
                        acc[g] += f4c(xr4[g+1], j) * wk1;
                        acc[g] += f4c(xr4[g+2], j) * wk2;
                    }
                }
            }
            float b1h = ld1<ISBF>(b1, tid);
#pragma unroll
            for (int g = 0; g < G; ++g) {
                float m = acc[g] + b1h;
                midpadf[(g+1)*H + h] = 0.5f * m * (1.f + erff(m * 0.70710678118654752f));
            }
        }
        __syncthreads();
        {
            const int dd = tid & (D - 1);
            const int gh = tid >> 7;
            float acc2[4] = {0.f,0.f,0.f,0.f};
            for (int h4 = 0; h4 < H; h4 += 4) {
                float4 mr4[6];
#pragma unroll
                for (int r = 0; r < 6; ++r) mr4[r] = *(const float4*)&midpadf[(gh*4+r)*H + h4];
#pragma unroll
                for (int j = 0; j < 4; ++j) {
                    size_t o = (size_t)dd * (H * 3) + (h4 + j) * 3;
                    float wk0 = ld1<ISBF>(w2raw, o), wk1 = ld1<ISBF>(w2raw, o+1), wk2 = ld1<ISBF>(w2raw, o+2);
#pragma unroll
                    for (int jj = 0; jj < 4; ++jj) {
                        acc2[jj] += f4c(mr4[jj+0], j) * wk0;
                        acc2[jj] += f4c(mr4[jj+1], j) * wk1;
                        acc2[jj] += f4c(mr4[jj+2], j) * wk2;
                    }
                }
            }
            float b2d = ld1<ISBF>(b2, dd);
            float vz[4], s = 0.f, ss = 0.f;
#pragma unroll
            for (int j = 0; j < 4; ++j) {
                int e = (gh*4+j)*D + dd;
                float val = acc2[j] + b2d + resid[e];
                vz[j] = val; s += val; ss += val*val;
            }
#pragma unroll
            for (int m = 1; m < 64; m <<= 1) { s += __shfl_xor(s, m); ss += __shfl_xor(ss, m); }
            const int wid = tid >> 6;
            if ((tid & 63) == 0) { red[wid*2] = s; red[wid*2+1] = ss; }
            __syncthreads();
            float st = red[0]+red[2]+red[4]+red[6], sst = red[1]+red[3]+red[5]+red[7];
            float mean = st * (1.f/1024.f), var = sst * (1.f/1024.f) - mean*mean;
            float rstd = rsqrtf(var + 1e-5f);
#pragma unroll
            for (int j = 0; j < 4; ++j) {
                int e = (gh*4+j)*D + dd;
                zbuf[t][e] = (vz[j]-mean)*rstd*ld1<ISBF>(pack_g, e) + ld1<ISBF>(pack_b, e);
            }
        }
    }
    __syncthreads();
    {
        float accm[4][4];
#pragma unroll
        for (int t = 0; t < 4; ++t)
#pragma unroll
            for (int j = 0; j < 4; ++j) accm[t][j] = 0.f;
        for (int p4 = 0; p4 < PK; p4 += 4) {
            float4 z4[4];
#pragma unroll
            for (int t = 0; t < 4; ++t) z4[t] = *(const float4*)&zbuf[t][p4];
#pragma unroll
            for (int pp = 0; pp < 4; ++pp) {
                float4 w4 = ld4<ISBF>(Wm, (size_t)(p4 + pp) * DM + e0);
#pragma unroll
                for (int t = 0; t < 4; ++t) {
                    float zp = f4c(z4[t], pp);
                    accm[t][0] += zp * w4.x; accm[t][1] += zp * w4.y;
                    accm[t][2] += zp * w4.z; accm[t][3] += zp * w4.w;
                }
            }
        }
        float4 bm4 = ld4<ISBF>(bm, e0);
#pragma unroll
        for (int t = 0; t < 4; ++t) {
            const size_t tok = (size_t)blockIdx.x * 4 + t;
            st4<ISBF>(out, tok * DM + e0,
                      make_float4(accm[t][0]+bm4.x, accm[t][1]+bm4.y,
                                  accm[t][2]+bm4.z, accm[t][3]+bm4.w));
        }
    }
}

extern "C" void kernel_launch(void* const* d_in, const int* in_sizes, int n_in,
                              void* d_out, int out_size, void* d_ws, size_t ws_size,
                              hipStream_t stream) {
    const void* x   = d_in[0];
    const void* sg  = d_in[1];
    const void* sb  = d_in[2];
    const void* pg  = d_in[3];
    const void* pb  = d_in[4];
    const void* w1  = d_in[5];
    const void* b1  = d_in[6];
    const void* w2  = d_in[7];
    const void* b2  = d_in[8];
    const void* pkg = d_in[9];
    const void* pkb = d_in[10];
    const void* Wm  = d_in[11];
    const void* bm  = d_in[12];

    int* flag = (int*)d_ws;
    u16* base = (u16*)((char*)d_ws + 16);
    u16* w1p = base;                       // 98304 el
    u16* w2p = base + 98304;               // 98304 el
    u16* wmt = base + 196608;              // 1048576 el
    u16* zws = base + 196608 + 1048576;    // 16777216 el (xg, then z, in place)
    float* pf = (float*)(base + 18022400); // 5760 f32 params
    const size_t ws_needed = 16 + (size_t)18022400 * sizeof(u16) + PF_N * sizeof(float);

    detect_dtype<<<1, 256, 0, stream>>>(x, flag);

    if (ws_size >= ws_needed) {
        prep_mfma<<<640, 256, 0, stream>>>(w1, w2, Wm, pg, pb, b1, b2, pkg, pkb, bm,
                                           sg, sb, w1p, w2p, wmt, pf, flag);
        conv_fused<<<NTOK / 8, 256, 0, stream>>>(x, zws, w1p, w2p, pf, flag);
        gemm_out<<<(NTOK / 128) * (DM / 128), 256, 0, stream>>>(zws, wmt, pf + 2688, d_out, flag);
    } else {
        slotconv_scalar<true ><<<NTOK / 4, 256, 0, stream>>>(
            x, sg, sb, pg, pb, w1, b1, w2, b2, pkg, pkb, Wm, bm, d_out, flag);
        slotconv_scalar<false><<<NTOK / 4, 256, 0, stream>>>(
            x, sg, sb, pg, pb, w1, b1, w2, b2, pkg, pkb, Wm, bm, d_out, flag);
    }
}

// Round 13
// 291.901 us; speedup vs baseline: 1.0437x; 1.0083x over previous
//
#include <hip/hip_runtime.h>
#include <hip/hip_bf16.h>
#include <math.h>

typedef unsigned short u16;
typedef unsigned int   u32;
typedef __attribute__((ext_vector_type(8))) short short8;   // 8 bf16
typedef __attribute__((ext_vector_type(4))) float f32x4;    // MFMA acc

// Problem constants
constexpr int G  = 8;
constexpr int D  = 128;
constexpr int H  = 256;
constexpr int DM = 1024;
constexpr int PK = 1024;
constexpr int NTOK = 8 * 2048;   // 16384

// f32 param ws layout (floats): [0]pre_g(128) [128]pre_b(128) [256]b1(256)
// [512]b2(128) [640]pack_g(1024) [1664]pack_b(1024) [2688]bm(1024)
// [3712]gate=2*sigmoid(slot_gate)(1024) [4736]slot_bias(1024) -> 5760
constexpr int PF_N = 5760;

// ---------- scalar helpers ----------
__device__ __forceinline__ float bf2f(u16 u) {
    union { u32 i; float f; } v; v.i = ((u32)u) << 16; return v.f;
}
__device__ __forceinline__ u16 f2bf(float f) {
    union { float f; u32 i; } v; v.f = f;
    u32 x = v.i;
    return (u16)((x + 0x7fffu + ((x >> 16) & 1u)) >> 16);  // RNE
}
// packed f32x2 -> bf16x2 (RNE), single VALU op
__device__ __forceinline__ u32 pk_bf16(float lo, float hi) {
    u32 d;
    asm("v_cvt_pk_bf16_f32 %0, %1, %2" : "=v"(d) : "v"(lo), "v"(hi));
    return d;
}
__device__ __forceinline__ float f4c(const float4 v, int j) {
    return j == 0 ? v.x : j == 1 ? v.y : j == 2 ? v.z : v.w;
}
template <bool ISBF>
__device__ __forceinline__ float ld1(const void* p, size_t i) {
    if (ISBF) return bf2f(((const u16*)p)[i]);
    else      return ((const float*)p)[i];
}
template <bool ISBF>
__device__ __forceinline__ float4 ld4(const void* p, size_t i) {  // i % 4 == 0
    if (ISBF) {
        ushort4 v = *(const ushort4*)((const u16*)p + i);
        return make_float4(bf2f(v.x), bf2f(v.y), bf2f(v.z), bf2f(v.w));
    } else {
        return *(const float4*)((const float*)p + i);
    }
}
// runtime-dtype variants (uniform branch on flag)
__device__ __forceinline__ float ld1rt(const void* p, size_t i, bool isbf) {
    return isbf ? bf2f(((const u16*)p)[i]) : ((const float*)p)[i];
}
__device__ __forceinline__ float4 ld4rt(const void* p, size_t i, bool isbf) {
    if (isbf) {
        ushort4 v = *(const ushort4*)((const u16*)p + i);
        return make_float4(bf2f(v.x), bf2f(v.y), bf2f(v.z), bf2f(v.w));
    } else {
        return *(const float4*)((const float*)p + i);
    }
}
template <bool ISBF>
__device__ __forceinline__ void st4(void* p, size_t i, float4 v) {
    if (ISBF) {
        ushort4 o; o.x = f2bf(v.x); o.y = f2bf(v.y); o.z = f2bf(v.z); o.w = f2bf(v.w);
        *(ushort4*)((u16*)p + i) = o;
    } else {
        *(float4*)((float*)p + i) = v;
    }
}
__device__ __forceinline__ void st4rt(void* p, size_t i, float4 v, bool isbf) {
    if (isbf) {
        ushort4 o; o.x = f2bf(v.x); o.y = f2bf(v.y); o.z = f2bf(v.z); o.w = f2bf(v.w);
        *(ushort4*)((u16*)p + i) = o;
    } else {
        *(float4*)((float*)p + i) = v;
    }
}
// tanh-form GELU (max dev vs exact erf-GELU ~3e-4, tolerance 6.4e-2)
__device__ __forceinline__ float gelu_f(float v) {
    float u = v * (0.7978845608028654f + 0.0356774081f * v * v);
    float e = __expf(2.f * u);
    float th = 1.f - 2.f / (e + 1.f);
    return 0.5f * v * (1.f + th);
}
// async global->LDS, 16B per lane; LDS dest = wave-uniform base + lane*16
__device__ __forceinline__ void gload_lds16(const void* gp, void* lp) {
    __builtin_amdgcn_global_load_lds(
        (const __attribute__((address_space(1))) void*)gp,
        (__attribute__((address_space(3))) void*)lp, 16, 0, 0);
}

// ---------- dtype detect (proven R2) ----------
__global__ void detect_dtype(const void* xraw, int* flag) {
    __shared__ int cnt[256];
    const u32* xw = (const u32*)xraw;
    int tid = threadIdx.x, c = 0;
#pragma unroll
    for (int k = 0; k < 4; ++k) {
        u32 w = xw[tid * 4 + k];
#pragma unroll
        for (int h = 0; h < 2; ++h) {
            u16 u = (u16)(w >> (16 * h));
            int e = (u >> 7) & 0xFF;
            if ((u & 0x7FFF) == 0 || (e >= 112 && e <= 143)) ++c;
        }
    }
    cnt[tid] = c;
    __syncthreads();
    for (int s = 128; s > 0; s >>= 1) {
        if (tid < s) cnt[tid] += cnt[tid + s];
        __syncthreads();
    }
    if (tid == 0) flag[0] = (cnt[0] >= 1900) ? 1 : 0;
}

// ---------- MFMA-path weight prep (single dispatch, runtime isbf) ----------
// blocks [0,256): Wm -> wmt (WmT, bf16) via LDS 64x64 tile transpose
// blocks [256,640): fragment-major conv weights + f32 param conversion
// (incl. gate = 2*sigmoid(slot_gate) and slot_bias, both f32).
__global__ __launch_bounds__(256)
void prep_mfma(const void* __restrict__ w1, const void* __restrict__ w2,
               const void* __restrict__ Wm,
               const void* __restrict__ pre_g, const void* __restrict__ pre_b,
               const void* __restrict__ b1, const void* __restrict__ b2,
               const void* __restrict__ pkg, const void* __restrict__ pkb,
               const void* __restrict__ bm,
               const void* __restrict__ sg, const void* __restrict__ sb,
               u16* __restrict__ w1p, u16* __restrict__ w2p,
               u16* __restrict__ wmt, float* __restrict__ pf,
               const int* __restrict__ flag) {
    const bool isbf = (flag[0] != 0);
    __shared__ u16 tile[64][72];
    const int tid = threadIdx.x;
    if (blockIdx.x < 256) {
        const int kk0 = (blockIdx.x >> 4) * 64, n0 = (blockIdx.x & 15) * 64;
        const int r = tid >> 2, q = tid & 3;
#pragma unroll
        for (int j4 = 0; j4 < 4; ++j4) {
            float4 v = ld4rt(Wm, (size_t)(kk0 + r) * DM + n0 + q * 16 + j4 * 4, isbf);
            tile[r][q * 16 + j4 * 4 + 0] = f2bf(v.x);
            tile[r][q * 16 + j4 * 4 + 1] = f2bf(v.y);
            tile[r][q * 16 + j4 * 4 + 2] = f2bf(v.z);
            tile[r][q * 16 + j4 * 4 + 3] = f2bf(v.w);
        }
        __syncthreads();
        u16 op[16];
#pragma unroll
        for (int j = 0; j < 16; ++j) op[j] = tile[q * 16 + j][r];
        u16* dst = wmt + (size_t)(n0 + r) * DM + kk0 + q * 16;
        *(short8*)dst       = *(const short8*)&op[0];
        *(short8*)(dst + 8) = *(const short8*)&op[8];
        return;
    }
    int idx = (blockIdx.x - 256) * 256 + tid;
    if (idx < 3 * 4 * H * 32) {          // 98304 for each of w1p/w2p
        int jq = idx & 31;
        int t2 = idx >> 5;
        int h  = t2 & (H - 1);
        int ik = t2 >> 8;                // 0..11
        int kt1 = ik >> 2, kk1 = ik & 3;
        int dd = kk1 * 32 + jq;
        w1p[idx] = f2bf(ld1rt(w1, (size_t)(h * D + dd) * 3 + kt1, isbf));
        int d   = t2 & (D - 1);
        int ik2 = t2 >> 7;               // 0..23
        int kt2 = ik2 >> 3, kk2 = ik2 & 7;
        int hh = kk2 * 32 + jq;
        w2p[idx] = f2bf(ld1rt(w2, (size_t)(d * H + hh) * 3 + kt2, isbf));
    }
    if (idx < D) {
        pf[idx]       = ld1rt(pre_g, idx, isbf);
        pf[128 + idx] = ld1rt(pre_b, idx, isbf);
        pf[512 + idx] = ld1rt(b2, idx, isbf);
    }
    if (idx < H) pf[256 + idx] = ld1rt(b1, idx, isbf);
    if (idx < PK) {
        pf[640  + idx] = ld1rt(pkg, idx, isbf);
        pf[1664 + idx] = ld1rt(pkb, idx, isbf);
        pf[2688 + idx] = ld1rt(bm, idx, isbf);
        pf[3712 + idx] = 2.f / (1.f + __expf(-ld1rt(sg, idx, isbf)));
        pf[4736 + idx] = ld1rt(sb, idx, isbf);
    }
}

// ---------- fused gate+LN1+conv1+GELU+conv2+LN2 : x -> z (bf16, into zws) ----------
// R13: CONSOLIDATION to the best-measured configuration (R8 = 291.0 us total).
// Self-contained: gate computed in-kernel from f32 pf (gate, slot_bias); x
// read twice (epilogue read is L2-hot: 32KB/block working set); no xg staging
// (R12's fused staging ran conv at 172 us — reverted). Single dispatch,
// runtime isbf for x loads only.
// PROVEN: (256,3) -> VGPR ~80, WRITE 33MB clean, conv ~135 us.
// (256,4) spills (R6/R9: footprint ~150 > 128-reg cap). DO NOT raise.
// LDS union uni[74*256 u16] (37888 B):
//   xnpad  rows 0..72  : u16 base r*128
//   midpad rows 0..36  : u16 base r*256            [M_lo]
//   midpad rows 37..72 : u16 base r*256+256        [M_hi]
__global__ __launch_bounds__(256, 3)
void conv_fused(const void* __restrict__ x,
                u16* __restrict__ zout,
                const u16* __restrict__ w1p,
                const u16* __restrict__ w2p,
                const float* __restrict__ pf,
                const int* __restrict__ flag) {
    const bool isbf = (flag[0] != 0);
    __shared__ u16 uni[74 * 256];          // 37888 B union
    __shared__ float red_s[8][4], red_ss[8][4];

    const int tid  = threadIdx.x;
    const int lane = tid & 63, w = tid >> 6;
    const int quad = lane >> 4, col = lane & 15;
    const size_t tok0 = (size_t)blockIdx.x * 8;

    // ---- stage 0: zero xnpad halo rows (9 x 128) + M_hi halo rows {45,54,63,72} ----
    if (tid < 72) {
        int li = tid * 16, hr = li >> 7, e = li & 127;
        u16* p = &uni[hr * 9 * 128 + e];
#pragma unroll
        for (int q = 0; q < 4; ++q) *(ushort4*)(p + 4 * q) = make_ushort4(0, 0, 0, 0);
    } else if (tid >= 128) {
        int li = (tid - 128) * 8, hr = li >> 8, e = li & 255;
        int row = 45 + hr * 9;                       // 45,54,63,72
        u16* p = &uni[row * 256 + 256 + e];          // M_hi mapping
        *(ushort4*)p       = make_ushort4(0, 0, 0, 0);
        *(ushort4*)(p + 4) = make_ushort4(0, 0, 0, 0);
    }

    const int e0 = 4 * tid;
    const int d0 = e0 & (D - 1);
    const int g0 = tid >> 5;
    float4 gg   = *(const float4*)(pf + 3712 + e0);   // 2*sigmoid(slot_gate)
    float4 sbb  = *(const float4*)(pf + 4736 + e0);   // slot_bias
    float4 pg4s = *(const float4*)(pf + d0);          // pre_g
    float4 pb4s = *(const float4*)(pf + 128 + d0);    // pre_b

    // ---- stage 1: gate+bias (f32), LN1 -> xnpad (bf16, swizzled) ----
#pragma unroll
    for (int t = 0; t < 8; ++t) {
        float4 x4 = ld4rt(x, (tok0 + t) * PK + e0, isbf);
        float v[4];
#pragma unroll
        for (int j = 0; j < 4; ++j) v[j] = f4c(x4, j) * f4c(gg, j) + f4c(sbb, j);
        float s = v[0] + v[1] + v[2] + v[3];
        float ss = v[0]*v[0] + v[1]*v[1] + v[2]*v[2] + v[3]*v[3];
#pragma unroll
        for (int m = 1; m < 32; m <<= 1) {
            s  += __shfl_xor(s,  m);
            ss += __shfl_xor(ss, m);
        }
        float mean = s * (1.f / 128.f);
        float var  = ss * (1.f / 128.f) - mean * mean;
        float rstd = rsqrtf(var + 1e-5f);
        uint2 o;
        o.x = pk_bf16((v[0] - mean) * rstd * pg4s.x + pb4s.x,
                      (v[1] - mean) * rstd * pg4s.y + pb4s.y);
        o.y = pk_bf16((v[2] - mean) * rstd * pg4s.z + pb4s.z,
                      (v[3] - mean) * rstd * pg4s.w + pb4s.w);
        int row  = t * 9 + g0 + 1;
        int addr = row * 128 + (((d0 >> 3) ^ (row & 7)) << 3) + (d0 & 7);
        *(uint2*)&uni[addr] = o;
    }
    __syncthreads();

    int rowb[4];
#pragma unroll
    for (int nt = 0; nt < 4; ++nt) {
        int n = nt * 16 + col;
        rowb[nt] = (n >> 3) * 9 + (n & 7);
    }
    const int alane1 = (w * 64 + col) * 32 + quad * 8;
    const int alane2 = (w * 32 + col) * 32 + quad * 8;

    // ---- stage 2: conv1 via MFMA, two nt-passes (32-AGPR live acc each) ----
#pragma unroll
    for (int pass = 0; pass < 2; ++pass) {
        const int ntb = (pass == 0) ? 2 : 0;
        f32x4 acc[4][2] = {};
#pragma unroll
        for (int it = 0; it < 12; ++it) {
            const int ktap = it >> 2, kk = it & 3;
            short8 afr[4];
#pragma unroll
            for (int mtl = 0; mtl < 4; ++mtl)
                afr[mtl] = *(const short8*)(w1p + it * 8192 + mtl * 512 + alane1);
            short8 bfr[2];
#pragma unroll
            for (int ntl = 0; ntl < 2; ++ntl) {
                int rr = rowb[ntb + ntl] + ktap;
                int a  = rr * 128 + (((kk * 4 + quad) ^ (rr & 7)) << 3);
                bfr[ntl] = *(const short8*)&uni[a];
            }
#pragma unroll
            for (int mtl = 0; mtl < 4; ++mtl)
#pragma unroll
                for (int ntl = 0; ntl < 2; ++ntl)
                    acc[mtl][ntl] = __builtin_amdgcn_mfma_f32_16x16x32_bf16(
                        afr[mtl], bfr[ntl], acc[mtl][ntl], 0, 0, 0);
        }
        if (pass == 1) {
            __syncthreads();
            if (tid < 160) {
                int li = tid * 8, hr = li >> 8, e = li & 255;
                u16* p = &uni[hr * 9 * 256 + e];
                *(ushort4*)p       = make_ushort4(0, 0, 0, 0);
                *(ushort4*)(p + 4) = make_ushort4(0, 0, 0, 0);
            }
        }
#pragma unroll
        for (int mtl = 0; mtl < 4; ++mtl) {
            int hq = w * 64 + mtl * 16 + quad * 4;
            float4 b1q = *(const float4*)(pf + 256 + hq);
#pragma unroll
            for (int ntl = 0; ntl < 2; ++ntl) {
                int row = rowb[ntb + ntl] + 1;
                uint2 o;
                o.x = pk_bf16(gelu_f(acc[mtl][ntl][0] + b1q.x),
                              gelu_f(acc[mtl][ntl][1] + b1q.y));
                o.y = pk_bf16(gelu_f(acc[mtl][ntl][2] + b1q.z),
                              gelu_f(acc[mtl][ntl][3] + b1q.w));
                int mb = row * 256 + ((row >= 37) ? 256 : 0);
                int a  = mb + (((hq >> 3) ^ (row & 7)) << 3) + (hq & 7);
                *(uint2*)&uni[a] = o;
            }
        }
    }
    __syncthreads();

    // ---- stage 3: conv2 via MFMA + bias + residual + LN2 + pack ----
    f32x4 acc2[2][4] = {};
#pragma unroll
    for (int it = 0; it < 24; ++it) {
        const int ktap = it >> 3, kk = it & 7;
        short8 cfr[2];
#pragma unroll
        for (int mtl = 0; mtl < 2; ++mtl)
            cfr[mtl] = *(const short8*)(w2p + it * 4096 + mtl * 512 + alane2);
        short8 bfr[4];
#pragma unroll
        for (int nt = 0; nt < 4; ++nt) {
            int rr = rowb[nt] + ktap;
            int mb = rr * 256 + ((rr >= 37) ? 256 : 0);
            int a  = mb + (((kk * 4 + quad) ^ (rr & 7)) << 3);
            bfr[nt] = *(const short8*)&uni[a];
        }
#pragma unroll
        for (int mtl = 0; mtl < 2; ++mtl)
#pragma unroll
            for (int nt = 0; nt < 4; ++nt)
                acc2[mtl][nt] = __builtin_amdgcn_mfma_f32_16x16x32_bf16(
                    cfr[mtl], bfr[nt], acc2[mtl][nt], 0, 0, 0);
    }
    {
        float vals[2][4][4];
        float s[4] = {0.f, 0.f, 0.f, 0.f}, ss[4] = {0.f, 0.f, 0.f, 0.f};
#pragma unroll
        for (int mtl = 0; mtl < 2; ++mtl) {
            int dq = w * 32 + mtl * 16 + quad * 4;
            float4 b2q = *(const float4*)(pf + 512 + dq);
#pragma unroll
            for (int nt = 0; nt < 4; ++nt) {
                int n = nt * 16 + col; int t = n >> 3, g = n & 7;
                int e = g * D + dq;
                float4 xr = ld4rt(x, (tok0 + t) * PK + e, isbf);   // L2-hot re-read
                float4 gq = *(const float4*)(pf + 3712 + e);
                float4 bq = *(const float4*)(pf + 4736 + e);
#pragma unroll
                for (int r = 0; r < 4; ++r) {
                    float resid = f4c(xr, r) * f4c(gq, r) + f4c(bq, r);
                    float val = acc2[mtl][nt][r] + f4c(b2q, r) + resid;
                    vals[mtl][nt][r] = val;
                    s[nt] += val; ss[nt] += val * val;
                }
            }
        }
        // reduce over lanes sharing token t: masks {1,2,4,16,32}
#pragma unroll
        for (int nt = 0; nt < 4; ++nt) {
            s[nt] += __shfl_xor(s[nt], 1);  ss[nt] += __shfl_xor(ss[nt], 1);
            s[nt] += __shfl_xor(s[nt], 2);  ss[nt] += __shfl_xor(ss[nt], 2);
            s[nt] += __shfl_xor(s[nt], 4);  ss[nt] += __shfl_xor(ss[nt], 4);
            s[nt] += __shfl_xor(s[nt], 16); ss[nt] += __shfl_xor(ss[nt], 16);
            s[nt] += __shfl_xor(s[nt], 32); ss[nt] += __shfl_xor(ss[nt], 32);
        }
        if (quad == 0 && (col & 7) == 0) {
#pragma unroll
            for (int nt = 0; nt < 4; ++nt) {
                int t = 2 * nt + (col >> 3);
                red_s[t][w] = s[nt]; red_ss[t][w] = ss[nt];
            }
        }
        __syncthreads();
        float mean[4], rstd[4];
#pragma unroll
        for (int nt = 0; nt < 4; ++nt) {
            int t = 2 * nt + (col >> 3);
            float st  = red_s[t][0] + red_s[t][1] + red_s[t][2] + red_s[t][3];
            float sst = red_ss[t][0] + red_ss[t][1] + red_ss[t][2] + red_ss[t][3];
            mean[nt] = st * (1.f / 1024.f);
            float var = sst * (1.f / 1024.f) - mean[nt] * mean[nt];
            rstd[nt] = rsqrtf(var + 1e-5f);
        }
#pragma unroll
        for (int mtl = 0; mtl < 2; ++mtl) {
            int dq = w * 32 + mtl * 16 + quad * 4;
#pragma unroll
            for (int nt = 0; nt < 4; ++nt) {
                int n = nt * 16 + col; int t = n >> 3, g = n & 7;
                int e = g * D + dq;
                float4 pg4 = *(const float4*)(pf + 640 + e);
                float4 pb4 = *(const float4*)(pf + 1664 + e);
                float zv[4];
#pragma unroll
                for (int r = 0; r < 4; ++r)
                    zv[r] = (vals[mtl][nt][r] - mean[nt]) * rstd[nt] * f4c(pg4, r)
                            + f4c(pb4, r);
                uint2 o;
                o.x = pk_bf16(zv[0], zv[1]);
                o.y = pk_bf16(zv[2], zv[3]);
                *(uint2*)(zout + (tok0 + t) * PK + e) = o;
            }
        }
    }
}

// ---------- z @ Wm + bm via MFMA ----------
// R8/R10-PROVEN config: BK=64 single-buffer, 16 K-steps, 32 MFMA per
// barrier-drain, both-sides chunk-XOR swizzle (rule #21), (256,3), 32KB LDS.
// (R11's counted-vmcnt graft measured null-to-negative; do not re-add.)
__global__ __launch_bounds__(256, 3)
void gemm_out(const u16* __restrict__ z, const u16* __restrict__ wmt,
              const float* __restrict__ bmf, void* __restrict__ out,
              const int* __restrict__ flag) {
    const bool isbf = (flag[0] != 0);
    __shared__ u16 As[128 * 64];   // z tile   [m][k], chunk-swizzled contents
    __shared__ u16 Bs[128 * 64];   // WmT tile [n][k], chunk-swizzled contents
    const int tid = threadIdx.x, lane = tid & 63, w = tid >> 6;
    const int quad = lane >> 4, col = lane & 15;
    // XCD-bijective swizzle (nwg = 1024, % 8 == 0)
    const int swz = ((blockIdx.x & 7) << 7) | ((int)blockIdx.x >> 3);
    const int bm0 = (swz >> 3) * 128, bn0 = (swz & 7) * 128;
    const int wm = w >> 1, wn = w & 1;
    f32x4 acc[4][4] = {};            // [nt][mt]

    const u16* zrow0 = z   + (size_t)bm0 * DM;
    const u16* wrow0 = wmt + (size_t)bn0 * DM;

    for (int k0 = 0; k0 < DM; k0 += 64) {
#pragma unroll
        for (int q = 0; q < 4; ++q) {
            int c = q * 256 + tid;
            int r = c >> 3;                    // row 0..127
            int jj = (c & 7) ^ (r & 7);        // pre-swizzled source chunk
            const int ldsoff = (q * 256 + w * 64) * 8;   // wave-uniform, u16
            gload_lds16(zrow0 + (size_t)r * DM + k0 + jj * 8, &As[ldsoff]);
            gload_lds16(wrow0 + (size_t)r * DM + k0 + jj * 8, &Bs[ldsoff]);
        }
        __syncthreads();   // vmcnt(0) drain + barrier: tile ready
#pragma unroll
        for (int kk = 0; kk < 2; ++kk) {
            short8 zfr[4], wfr[4];
#pragma unroll
            for (int mt = 0; mt < 4; ++mt) {
                int row = wm * 64 + mt * 16 + col;
                zfr[mt] = *(const short8*)
                    &As[row * 64 + (((kk * 4 + quad) ^ (row & 7)) << 3)];
            }
#pragma unroll
            for (int nt = 0; nt < 4; ++nt) {
                int row = wn * 64 + nt * 16 + col;
                wfr[nt] = *(const short8*)
                    &Bs[row * 64 + (((kk * 4 + quad) ^ (row & 7)) << 3)];
            }
#pragma unroll
            for (int nt = 0; nt < 4; ++nt)
#pragma unroll
                for (int mt = 0; mt < 4; ++mt)
                    acc[nt][mt] = __builtin_amdgcn_mfma_f32_16x16x32_bf16(
                        wfr[nt], zfr[mt], acc[nt][mt], 0, 0, 0);
        }
        __syncthreads();   // all reads done before next stage overwrites
    }
    // epilogue: C rows = n (quad*4+r), cols = m
#pragma unroll
    for (int nt = 0; nt < 4; ++nt) {
        int n = bn0 + wn * 64 + nt * 16 + quad * 4;
        float4 bq = *(const float4*)(bmf + n);
#pragma unroll
        for (int mt = 0; mt < 4; ++mt) {
            int m = bm0 + wm * 64 + mt * 16 + col;
            float4 o = make_float4(acc[nt][mt][0] + bq.x, acc[nt][mt][1] + bq.y,
                                   acc[nt][mt][2] + bq.z, acc[nt][mt][3] + bq.w);
            st4rt(out, (size_t)m * DM + n, o, isbf);
        }
    }
}

// ---------- scalar fallback (R2-proven), raw weights ----------
template <bool ISBF>
__global__ __launch_bounds__(256)
void slotconv_scalar(const void* __restrict__ x,
                     const void* __restrict__ slot_gate,
                     const void* __restrict__ slot_bias,
                     const void* __restrict__ pre_g,
                     const void* __restrict__ pre_b,
                     const void* __restrict__ w1raw,
                     const void* __restrict__ b1,
                     const void* __restrict__ w2raw,
                     const void* __restrict__ b2,
                     const void* __restrict__ pack_g,
                     const void* __restrict__ pack_b,
                     const void* __restrict__ Wm,
                     const void* __restrict__ bm,
                     void* __restrict__ out,
                     const int* __restrict__ flag) {
    if ((flag[0] != 0) != ISBF) return;
    __shared__ float resid[G * D];
    __shared__ float xnpadf[(G + 2) * D];
    __shared__ float midpadf[(G + 2) * H];
    __shared__ float zbuf[4][PK];
    __shared__ float red[8];
    const int tid = threadIdx.x;
    if (tid < D) { xnpadf[tid] = 0.f; xnpadf[(G + 1) * D + tid] = 0.f; }
    midpadf[tid] = 0.f; midpadf[(G + 1) * H + tid] = 0.f;
    const int e0 = 4 * tid;
    const int d0 = e0 & (D - 1);
    const int g0 = tid >> 5;
    float gate[4], bias[4], pgf[4], pbf[4];
    {
        float4 sg4 = ld4<ISBF>(slot_gate, e0);
        float4 sb4 = ld4<ISBF>(slot_bias, e0);
        float4 pg4 = ld4<ISBF>(pre_g, d0);
        float4 pb4 = ld4<ISBF>(pre_b, d0);
#pragma unroll
        for (int j = 0; j < 4; ++j) {
            gate[j] = 2.f / (1.f + __expf(-f4c(sg4, j)));
            bias[j] = f4c(sb4, j);
            pgf[j] = f4c(pg4, j); pbf[j] = f4c(pb4, j);
        }
    }
    for (int t = 0; t < 4; ++t) {
        __syncthreads();
        const size_t tok = (size_t)blockIdx.x * 4 + t;
        {
            float4 x4 = ld4<ISBF>(x, tok * PK + e0);
            float v[4];
#pragma unroll
            for (int j = 0; j < 4; ++j) v[j] = f4c(x4, j) * gate[j] + bias[j];
            *(float4*)&resid[e0] = make_float4(v[0], v[1], v[2], v[3]);
            float s = v[0]+v[1]+v[2]+v[3], ss = v[0]*v[0]+v[1]*v[1]+v[2]*v[2]+v[3]*v[3];
#pragma unroll
            for (int m = 1; m < 32; m <<= 1) { s += __shfl_xor(s, m); ss += __shfl_xor(ss, m); }
            float mean = s * (1.f/128.f), var = ss * (1.f/128.f) - mean*mean;
            float rstd = rsqrtf(var + 1e-5f);
            float xn[4];
#pragma unroll
            for (int j = 0; j < 4; ++j) xn[j] = (v[j]-mean)*rstd*pgf[j]+pbf[j];
            *(float4*)&xnpadf[(g0+1)*D + d0] = make_float4(xn[0],xn[1],xn[2],xn[3]);
        }
        __syncthreads();
        {
            const int h = tid;
            float acc[G];
#pragma unroll
            for (int g = 0; g < G; ++g) acc[g] = 0.f;
            for (int d4 = 0; d4 < D; d4 += 4) {
                float4 xr4[G + 2];
#pragma unroll
                for (int r = 0; r < G + 2; ++r) xr4[r] = *(const float4*)&xnpadf[r * D + d4];
#pragma unroll
                for (int j = 0; j < 4; ++j) {
                    size_t o = (size_t)h * (D * 3) + (d4 + j) * 3;
                    float wk0 = ld1<ISBF>(w1raw, o), wk1 = ld1<ISBF>(w1raw, o+1), wk2 = ld1<ISBF>(w1raw, o+2);
#pragma unroll
                    for (int g = 0; g < G; ++g) {
                        acc[g] += f4c(xr4[g+0], j) * wk0;
                        acc[g] += f4c(xr4[g+1], j) * wk1;
                        acc[g] += f4c(xr4[g+2], j) * wk2;
                    }
                }
            }
            float b1h = ld1<ISBF>(b1, tid);
#pragma unroll
            for (int g = 0; g < G; ++g) {
                float m = acc[g] + b1h;
                midpadf[(g+1)*H + h] = 0.5f * m * (1.f + erff(m * 0.70710678118654752f));
            }
        }
        __syncthreads();
        {
            const int dd = tid & (D - 1);
            const int gh = tid >> 7;
            float acc2[4] = {0.f,0.f,0.f,0.f};
            for (int h4 = 0; h4 < H; h4 += 4) {
                float4 mr4[6];
#pragma unroll
                for (int r = 0; r < 6; ++r) mr4[r] = *(const float4*)&midpadf[(gh*4+r)*H + h4];
#pragma unroll
                for (int j = 0; j < 4; ++j) {
                    size_t o = (size_t)dd * (H * 3) + (h4 + j) * 3;
                    float wk0 = ld1<ISBF>(w2raw, o), wk1 = ld1<ISBF>(w2raw, o+1), wk2 = ld1<ISBF>(w2raw, o+2);
#pragma unroll
                    for (int jj = 0; jj < 4; ++jj) {
                        acc2[jj] += f4c(mr4[jj+0], j) * wk0;
                        acc2[jj] += f4c(mr4[jj+1], j) * wk1;
                        acc2[jj] += f4c(mr4[jj+2], j) * wk2;
                    }
                }
            }
            float b2d = ld1<ISBF>(b2, dd);
            float vz[4], s = 0.f, ss = 0.f;
#pragma unroll
            for (int j = 0; j < 4; ++j) {
                int e = (gh*4+j)*D + dd;
                float val = acc2[j] + b2d + resid[e];
                vz[j] = val; s += val; ss += val*val;
            }
#pragma unroll
            for (int m = 1; m < 64; m <<= 1) { s += __shfl_xor(s, m); ss += __shfl_xor(ss, m); }
            const int wid = tid >> 6;
            if ((tid & 63) == 0) { red[wid*2] = s; red[wid*2+1] = ss; }
            __syncthreads();
            float st = red[0]+red[2]+red[4]+red[6], sst = red[1]+red[3]+red[5]+red[7];
            float mean = st * (1.f/1024.f), var = sst * (1.f/1024.f) - mean*mean;
            float rstd = rsqrtf(var + 1e-5f);
#pragma unroll
            for (int j = 0; j < 4; ++j) {
                int e = (gh*4+j)*D + dd;
                zbuf[t][e] = (vz[j]-mean)*rstd*ld1<ISBF>(pack_g, e) + ld1<ISBF>(pack_b, e);
            }
        }
    }
    __syncthreads();
    {
        float accm[4][4];
#pragma unroll
        for (int t = 0; t < 4; ++t)
#pragma unroll
            for (int j = 0; j < 4; ++j) accm[t][j] = 0.f;
        for (int p4 = 0; p4 < PK; p4 += 4) {
            float4 z4[4];
#pragma unroll
            for (int t = 0; t < 4; ++t) z4[t] = *(const float4*)&zbuf[t][p4];
#pragma unroll
            for (int pp = 0; pp < 4; ++pp) {
                float4 w4 = ld4<ISBF>(Wm, (size_t)(p4 + pp) * DM + e0);
#pragma unroll
                for (int t = 0; t < 4; ++t) {
                    float zp = f4c(z4[t], pp);
                    accm[t][0] += zp * w4.x; accm[t][1] += zp * w4.y;
                    accm[t][2] += zp * w4.z; accm[t][3] += zp * w4.w;
                }
            }
        }
        float4 bm4 = ld4<ISBF>(bm, e0);
#pragma unroll
        for (int t = 0; t < 4; ++t) {
            const size_t tok = (size_t)blockIdx.x * 4 + t;
            st4<ISBF>(out, tok * DM + e0,
                      make_float4(accm[t][0]+bm4.x, accm[t][1]+bm4.y,
                                  accm[t][2]+bm4.z, accm[t][3]+bm4.w));
        }
    }
}

extern "C" void kernel_launch(void* const* d_in, const int* in_sizes, int n_in,
                              void* d_out, int out_size, void* d_ws, size_t ws_size,
                              hipStream_t stream) {
    const void* x   = d_in[0];
    const void* sg  = d_in[1];
    const void* sb  = d_in[2];
    const void* pg  = d_in[3];
    const void* pb  = d_in[4];
    const void* w1  = d_in[5];
    const void* b1  = d_in[6];
    const void* w2  = d_in[7];
    const void* b2  = d_in[8];
    const void* pkg = d_in[9];
    const void* pkb = d_in[10];
    const void* Wm  = d_in[11];
    const void* bm  = d_in[12];

    int* flag = (int*)d_ws;
    u16* base = (u16*)((char*)d_ws + 16);
    u16* w1p = base;                       // 98304 el
    u16* w2p = base + 98304;               // 98304 el
    u16* wmt = base + 196608;              // 1048576 el
    u16* zws = base + 196608 + 1048576;    // 16777216 el
    float* pf = (float*)(base + 18022400); // 5760 f32 params
    const size_t ws_needed = 16 + (size_t)18022400 * sizeof(u16) + PF_N * sizeof(float);

    detect_dtype<<<1, 256, 0, stream>>>(x, flag);

    if (ws_size >= ws_needed) {
        prep_mfma<<<640, 256, 0, stream>>>(w1, w2, Wm, pg, pb, b1, b2, pkg, pkb, bm,
                                           sg, sb, w1p, w2p, wmt, pf, flag);
        conv_fused<<<NTOK / 8, 256, 0, stream>>>(x, zws, w1p, w2p, pf, flag);
        gemm_out<<<(NTOK / 128) * (DM / 128), 256, 0, stream>>>(zws, wmt, pf + 2688, d_out, flag);
    } else {
        slotconv_scalar<true ><<<NTOK / 4, 256, 0, stream>>>(
            x, sg, sb, pg, pb, w1, b1, w2, b2, pkg, pkb, Wm, bm, d_out, flag);
        slotconv_scalar<false><<<NTOK / 4, 256, 0, stream>>>(
            x, sg, sb, pg, pb, w1, b1, w2, b2, pkg, pkb, Wm, bm, d_out, flag);
    }
}

// Round 14
// 291.481 us; speedup vs baseline: 1.0452x; 1.0014x over previous
//
#include <hip/hip_runtime.h>
#include <hip/hip_bf16.h>
#include <math.h>

typedef unsigned short u16;
typedef unsigned int   u32;
typedef __attribute__((ext_vector_type(8))) short short8;   // 8 bf16
typedef __attribute__((ext_vector_type(4))) float f32x4;    // MFMA acc

// Problem constants
constexpr int G  = 8;
constexpr int D  = 128;
constexpr int H  = 256;
constexpr int DM = 1024;
constexpr int PK = 1024;
constexpr int NTOK = 8 * 2048;   // 16384

// f32 param ws layout (floats): [0]pre_g(128) [128]pre_b(128) [256]b1(256)
// [512]b2(128) [640]pack_g(1024) [1664]pack_b(1024) [2688]bm(1024)
// [3712]gate=2*sigmoid(slot_gate)(1024) [4736]slot_bias(1024) -> 5760
constexpr int PF_N = 5760;

// ---------- scalar helpers ----------
__device__ __forceinline__ float bf2f(u16 u) {
    union { u32 i; float f; } v; v.i = ((u32)u) << 16; return v.f;
}
__device__ __forceinline__ u16 f2bf(float f) {
    union { float f; u32 i; } v; v.f = f;
    u32 x = v.i;
    return (u16)((x + 0x7fffu + ((x >> 16) & 1u)) >> 16);  // RNE
}
// packed f32x2 -> bf16x2 (RNE), single VALU op
__device__ __forceinline__ u32 pk_bf16(float lo, float hi) {
    u32 d;
    asm("v_cvt_pk_bf16_f32 %0, %1, %2" : "=v"(d) : "v"(lo), "v"(hi));
    return d;
}
__device__ __forceinline__ float f4c(const float4 v, int j) {
    return j == 0 ? v.x : j == 1 ? v.y : j == 2 ? v.z : v.w;
}
template <bool ISBF>
__device__ __forceinline__ float ld1(const void* p, size_t i) {
    if (ISBF) return bf2f(((const u16*)p)[i]);
    else      return ((const float*)p)[i];
}
template <bool ISBF>
__device__ __forceinline__ float4 ld4(const void* p, size_t i) {  // i % 4 == 0
    if (ISBF) {
        ushort4 v = *(const ushort4*)((const u16*)p + i);
        return make_float4(bf2f(v.x), bf2f(v.y), bf2f(v.z), bf2f(v.w));
    } else {
        return *(const float4*)((const float*)p + i);
    }
}
// runtime-dtype variants (uniform branch on flag) — OK for prologue/epilogue
// one-shot loads; NOT for hot loops (R12/R13: branchy x loads cost conv +36us)
__device__ __forceinline__ float ld1rt(const void* p, size_t i, bool isbf) {
    return isbf ? bf2f(((const u16*)p)[i]) : ((const float*)p)[i];
}
__device__ __forceinline__ float4 ld4rt(const void* p, size_t i, bool isbf) {
    if (isbf) {
        ushort4 v = *(const ushort4*)((const u16*)p + i);
        return make_float4(bf2f(v.x), bf2f(v.y), bf2f(v.z), bf2f(v.w));
    } else {
        return *(const float4*)((const float*)p + i);
    }
}
template <bool ISBF>
__device__ __forceinline__ void st4(void* p, size_t i, float4 v) {
    if (ISBF) {
        ushort4 o; o.x = f2bf(v.x); o.y = f2bf(v.y); o.z = f2bf(v.z); o.w = f2bf(v.w);
        *(ushort4*)((u16*)p + i) = o;
    } else {
        *(float4*)((float*)p + i) = v;
    }
}
__device__ __forceinline__ void st4rt(void* p, size_t i, float4 v, bool isbf) {
    if (isbf) {
        ushort4 o; o.x = f2bf(v.x); o.y = f2bf(v.y); o.z = f2bf(v.z); o.w = f2bf(v.w);
        *(ushort4*)((u16*)p + i) = o;
    } else {
        *(float4*)((float*)p + i) = v;
    }
}
// tanh-form GELU (max dev vs exact erf-GELU ~3e-4, tolerance 6.4e-2)
__device__ __forceinline__ float gelu_f(float v) {
    float u = v * (0.7978845608028654f + 0.0356774081f * v * v);
    float e = __expf(2.f * u);
    float th = 1.f - 2.f / (e + 1.f);
    return 0.5f * v * (1.f + th);
}
// async global->LDS, 16B per lane; LDS dest = wave-uniform base + lane*16
__device__ __forceinline__ void gload_lds16(const void* gp, void* lp) {
    __builtin_amdgcn_global_load_lds(
        (const __attribute__((address_space(1))) void*)gp,
        (__attribute__((address_space(3))) void*)lp, 16, 0, 0);
}

// ---------- dtype detect (proven R2) ----------
__global__ void detect_dtype(const void* xraw, int* flag) {
    __shared__ int cnt[256];
    const u32* xw = (const u32*)xraw;
    int tid = threadIdx.x, c = 0;
#pragma unroll
    for (int k = 0; k < 4; ++k) {
        u32 w = xw[tid * 4 + k];
#pragma unroll
        for (int h = 0; h < 2; ++h) {
            u16 u = (u16)(w >> (16 * h));
            int e = (u >> 7) & 0xFF;
            if ((u & 0x7FFF) == 0 || (e >= 112 && e <= 143)) ++c;
        }
    }
    cnt[tid] = c;
    __syncthreads();
    for (int s = 128; s > 0; s >>= 1) {
        if (tid < s) cnt[tid] += cnt[tid + s];
        __syncthreads();
    }
    if (tid == 0) flag[0] = (cnt[0] >= 1900) ? 1 : 0;
}

// ---------- MFMA-path weight prep (single dispatch, runtime isbf) ----------
// blocks [0,256): Wm -> wmt (WmT, bf16) via LDS 64x64 tile transpose
// blocks [256,640): fragment-major conv weights + f32 param conversion
// (incl. gate = 2*sigmoid(slot_gate) and slot_bias, both f32).
__global__ __launch_bounds__(256)
void prep_mfma(const void* __restrict__ w1, const void* __restrict__ w2,
               const void* __restrict__ Wm,
               const void* __restrict__ pre_g, const void* __restrict__ pre_b,
               const void* __restrict__ b1, const void* __restrict__ b2,
               const void* __restrict__ pkg, const void* __restrict__ pkb,
               const void* __restrict__ bm,
               const void* __restrict__ sg, const void* __restrict__ sb,
               u16* __restrict__ w1p, u16* __restrict__ w2p,
               u16* __restrict__ wmt, float* __restrict__ pf,
               const int* __restrict__ flag) {
    const bool isbf = (flag[0] != 0);
    __shared__ u16 tile[64][72];
    const int tid = threadIdx.x;
    if (blockIdx.x < 256) {
        const int kk0 = (blockIdx.x >> 4) * 64, n0 = (blockIdx.x & 15) * 64;
        const int r = tid >> 2, q = tid & 3;
#pragma unroll
        for (int j4 = 0; j4 < 4; ++j4) {
            float4 v = ld4rt(Wm, (size_t)(kk0 + r) * DM + n0 + q * 16 + j4 * 4, isbf);
            tile[r][q * 16 + j4 * 4 + 0] = f2bf(v.x);
            tile[r][q * 16 + j4 * 4 + 1] = f2bf(v.y);
            tile[r][q * 16 + j4 * 4 + 2] = f2bf(v.z);
            tile[r][q * 16 + j4 * 4 + 3] = f2bf(v.w);
        }
        __syncthreads();
        u16 op[16];
#pragma unroll
        for (int j = 0; j < 16; ++j) op[j] = tile[q * 16 + j][r];
        u16* dst = wmt + (size_t)(n0 + r) * DM + kk0 + q * 16;
        *(short8*)dst       = *(const short8*)&op[0];
        *(short8*)(dst + 8) = *(const short8*)&op[8];
        return;
    }
    int idx = (blockIdx.x - 256) * 256 + tid;
    if (idx < 3 * 4 * H * 32) {          // 98304 for each of w1p/w2p
        int jq = idx & 31;
        int t2 = idx >> 5;
        int h  = t2 & (H - 1);
        int ik = t2 >> 8;                // 0..11
        int kt1 = ik >> 2, kk1 = ik & 3;
        int dd = kk1 * 32 + jq;
        w1p[idx] = f2bf(ld1rt(w1, (size_t)(h * D + dd) * 3 + kt1, isbf));
        int d   = t2 & (D - 1);
        int ik2 = t2 >> 7;               // 0..23
        int kt2 = ik2 >> 3, kk2 = ik2 & 7;
        int hh = kk2 * 32 + jq;
        w2p[idx] = f2bf(ld1rt(w2, (size_t)(d * H + hh) * 3 + kt2, isbf));
    }
    if (idx < D) {
        pf[idx]       = ld1rt(pre_g, idx, isbf);
        pf[128 + idx] = ld1rt(pre_b, idx, isbf);
        pf[512 + idx] = ld1rt(b2, idx, isbf);
    }
    if (idx < H) pf[256 + idx] = ld1rt(b1, idx, isbf);
    if (idx < PK) {
        pf[640  + idx] = ld1rt(pkg, idx, isbf);
        pf[1664 + idx] = ld1rt(pkb, idx, isbf);
        pf[2688 + idx] = ld1rt(bm, idx, isbf);
        pf[3712 + idx] = 2.f / (1.f + __expf(-ld1rt(sg, idx, isbf)));
        pf[4736 + idx] = ld1rt(sb, idx, isbf);
    }
}

// ---------- fused gate+LN1+conv1+GELU+conv2+LN2 : x -> z (bf16, into zws) ----------
// R14: conv RE-TEMPLATED on ISBF. Measured A/B across 4 rounds:
//   template x-loads (R7/R8): 135 us.  runtime-branch ld4rt (R12/R13): 171 us.
// The uniform branch around each x load blocks load hoisting/batching ->
// exposed latency. Twin dispatch; ghost early-exits (~3 us).
// Gate from f32 pf (R10-proven fine); x read twice (epilogue L2-hot).
// PROVEN: (256,3) -> VGPR ~80, WRITE 33MB clean. (256,4) spills (R6/R9).
// LDS union uni[74*256 u16] (37888 B):
//   xnpad rows 0..72: r*128 | midpad M_lo r*256 | M_hi r*256+256
template <bool ISBF>
__global__ __launch_bounds__(256, 3)
void conv_fused(const void* __restrict__ x,
                u16* __restrict__ zout,
                const u16* __restrict__ w1p,
                const u16* __restrict__ w2p,
                const float* __restrict__ pf,
                const int* __restrict__ flag) {
    if ((flag[0] != 0) != ISBF) return;
    __shared__ u16 uni[74 * 256];          // 37888 B union
    __shared__ float red_s[8][4], red_ss[8][4];

    const int tid  = threadIdx.x;
    const int lane = tid & 63, w = tid >> 6;
    const int quad = lane >> 4, col = lane & 15;
    const size_t tok0 = (size_t)blockIdx.x * 8;

    // ---- stage 0: zero xnpad halo rows (9 x 128) + M_hi halo rows {45,54,63,72} ----
    if (tid < 72) {
        int li = tid * 16, hr = li >> 7, e = li & 127;
        u16* p = &uni[hr * 9 * 128 + e];
#pragma unroll
        for (int q = 0; q < 4; ++q) *(ushort4*)(p + 4 * q) = make_ushort4(0, 0, 0, 0);
    } else if (tid >= 128) {
        int li = (tid - 128) * 8, hr = li >> 8, e = li & 255;
        int row = 45 + hr * 9;                       // 45,54,63,72
        u16* p = &uni[row * 256 + 256 + e];          // M_hi mapping
        *(ushort4*)p       = make_ushort4(0, 0, 0, 0);
        *(ushort4*)(p + 4) = make_ushort4(0, 0, 0, 0);
    }

    const int e0 = 4 * tid;
    const int d0 = e0 & (D - 1);
    const int g0 = tid >> 5;
    float4 gg   = *(const float4*)(pf + 3712 + e0);   // 2*sigmoid(slot_gate)
    float4 sbb  = *(const float4*)(pf + 4736 + e0);   // slot_bias
    float4 pg4s = *(const float4*)(pf + d0);          // pre_g
    float4 pb4s = *(const float4*)(pf + 128 + d0);    // pre_b

    // ---- stage 1: gate+bias (f32), LN1 -> xnpad (bf16, swizzled) ----
#pragma unroll
    for (int t = 0; t < 8; ++t) {
        float4 x4 = ld4<ISBF>(x, (tok0 + t) * PK + e0);
        float v[4];
#pragma unroll
        for (int j = 0; j < 4; ++j) v[j] = f4c(x4, j) * f4c(gg, j) + f4c(sbb, j);
        float s = v[0] + v[1] + v[2] + v[3];
        float ss = v[0]*v[0] + v[1]*v[1] + v[2]*v[2] + v[3]*v[3];
#pragma unroll
        for (int m = 1; m < 32; m <<= 1) {
            s  += __shfl_xor(s,  m);
            ss += __shfl_xor(ss, m);
        }
        float mean = s * (1.f / 128.f);
        float var  = ss * (1.f / 128.f) - mean * mean;
        float rstd = rsqrtf(var + 1e-5f);
        uint2 o;
        o.x = pk_bf16((v[0] - mean) * rstd * pg4s.x + pb4s.x,
                      (v[1] - mean) * rstd * pg4s.y + pb4s.y);
        o.y = pk_bf16((v[2] - mean) * rstd * pg4s.z + pb4s.z,
                      (v[3] - mean) * rstd * pg4s.w + pb4s.w);
        int row  = t * 9 + g0 + 1;
        int addr = row * 128 + (((d0 >> 3) ^ (row & 7)) << 3) + (d0 & 7);
        *(uint2*)&uni[addr] = o;
    }
    __syncthreads();

    int rowb[4];
#pragma unroll
    for (int nt = 0; nt < 4; ++nt) {
        int n = nt * 16 + col;
        rowb[nt] = (n >> 3) * 9 + (n & 7);
    }
    const int alane1 = (w * 64 + col) * 32 + quad * 8;
    const int alane2 = (w * 32 + col) * 32 + quad * 8;

    // ---- stage 2: conv1 via MFMA, two nt-passes (32-AGPR live acc each) ----
#pragma unroll
    for (int pass = 0; pass < 2; ++pass) {
        const int ntb = (pass == 0) ? 2 : 0;
        f32x4 acc[4][2] = {};
#pragma unroll
        for (int it = 0; it < 12; ++it) {
            const int ktap = it >> 2, kk = it & 3;
            short8 afr[4];
#pragma unroll
            for (int mtl = 0; mtl < 4; ++mtl)
                afr[mtl] = *(const short8*)(w1p + it * 8192 + mtl * 512 + alane1);
            short8 bfr[2];
#pragma unroll
            for (int ntl = 0; ntl < 2; ++ntl) {
                int rr = rowb[ntb + ntl] + ktap;
                int a  = rr * 128 + (((kk * 4 + quad) ^ (rr & 7)) << 3);
                bfr[ntl] = *(const short8*)&uni[a];
            }
#pragma unroll
            for (int mtl = 0; mtl < 4; ++mtl)
#pragma unroll
                for (int ntl = 0; ntl < 2; ++ntl)
                    acc[mtl][ntl] = __builtin_amdgcn_mfma_f32_16x16x32_bf16(
                        afr[mtl], bfr[ntl], acc[mtl][ntl], 0, 0, 0);
        }
        if (pass == 1) {
            __syncthreads();
            if (tid < 160) {
                int li = tid * 8, hr = li >> 8, e = li & 255;
                u16* p = &uni[hr * 9 * 256 + e];
                *(ushort4*)p       = make_ushort4(0, 0, 0, 0);
                *(ushort4*)(p + 4) = make_ushort4(0, 0, 0, 0);
            }
        }
#pragma unroll
        for (int mtl = 0; mtl < 4; ++mtl) {
            int hq = w * 64 + mtl * 16 + quad * 4;
            float4 b1q = *(const float4*)(pf + 256 + hq);
#pragma unroll
            for (int ntl = 0; ntl < 2; ++ntl) {
                int row = rowb[ntb + ntl] + 1;
                uint2 o;
                o.x = pk_bf16(gelu_f(acc[mtl][ntl][0] + b1q.x),
                              gelu_f(acc[mtl][ntl][1] + b1q.y));
                o.y = pk_bf16(gelu_f(acc[mtl][ntl][2] + b1q.z),
                              gelu_f(acc[mtl][ntl][3] + b1q.w));
                int mb = row * 256 + ((row >= 37) ? 256 : 0);
                int a  = mb + (((hq >> 3) ^ (row & 7)) << 3) + (hq & 7);
                *(uint2*)&uni[a] = o;
            }
        }
    }
    __syncthreads();

    // ---- stage 3: conv2 via MFMA + bias + residual + LN2 + pack ----
    f32x4 acc2[2][4] = {};
#pragma unroll
    for (int it = 0; it < 24; ++it) {
        const int ktap = it >> 3, kk = it & 7;
        short8 cfr[2];
#pragma unroll
        for (int mtl = 0; mtl < 2; ++mtl)
            cfr[mtl] = *(const short8*)(w2p + it * 4096 + mtl * 512 + alane2);
        short8 bfr[4];
#pragma unroll
        for (int nt = 0; nt < 4; ++nt) {
            int rr = rowb[nt] + ktap;
            int mb = rr * 256 + ((rr >= 37) ? 256 : 0);
            int a  = mb + (((kk * 4 + quad) ^ (rr & 7)) << 3);
            bfr[nt] = *(const short8*)&uni[a];
        }
#pragma unroll
        for (int mtl = 0; mtl < 2; ++mtl)
#pragma unroll
            for (int nt = 0; nt < 4; ++nt)
                acc2[mtl][nt] = __builtin_amdgcn_mfma_f32_16x16x32_bf16(
                    cfr[mtl], bfr[nt], acc2[mtl][nt], 0, 0, 0);
    }
    {
        float vals[2][4][4];
        float s[4] = {0.f, 0.f, 0.f, 0.f}, ss[4] = {0.f, 0.f, 0.f, 0.f};
#pragma unroll
        for (int mtl = 0; mtl < 2; ++mtl) {
            int dq = w * 32 + mtl * 16 + quad * 4;
            float4 b2q = *(const float4*)(pf + 512 + dq);
#pragma unroll
            for (int nt = 0; nt < 4; ++nt) {
                int n = nt * 16 + col; int t = n >> 3, g = n & 7;
                int e = g * D + dq;
                float4 xr = ld4<ISBF>(x, (tok0 + t) * PK + e);   // L2-hot re-read
                float4 gq = *(const float4*)(pf + 3712 + e);
                float4 bq = *(const float4*)(pf + 4736 + e);
#pragma unroll
                for (int r = 0; r < 4; ++r) {
                    float resid = f4c(xr, r) * f4c(gq, r) + f4c(bq, r);
                    float val = acc2[mtl][nt][r] + f4c(b2q, r) + resid;
                    vals[mtl][nt][r] = val;
                    s[nt] += val; ss[nt] += val * val;
                }
            }
        }
        // reduce over lanes sharing token t: masks {1,2,4,16,32}
#pragma unroll
        for (int nt = 0; nt < 4; ++nt) {
            s[nt] += __shfl_xor(s[nt], 1);  ss[nt] += __shfl_xor(ss[nt], 1);
            s[nt] += __shfl_xor(s[nt], 2);  ss[nt] += __shfl_xor(ss[nt], 2);
            s[nt] += __shfl_xor(s[nt], 4);  ss[nt] += __shfl_xor(ss[nt], 4);
            s[nt] += __shfl_xor(s[nt], 16); ss[nt] += __shfl_xor(ss[nt], 16);
            s[nt] += __shfl_xor(s[nt], 32); ss[nt] += __shfl_xor(ss[nt], 32);
        }
        if (quad == 0 && (col & 7) == 0) {
#pragma unroll
            for (int nt = 0; nt < 4; ++nt) {
                int t = 2 * nt + (col >> 3);
                red_s[t][w] = s[nt]; red_ss[t][w] = ss[nt];
            }
        }
        __syncthreads();
        float mean[4], rstd[4];
#pragma unroll
        for (int nt = 0; nt < 4; ++nt) {
            int t = 2 * nt + (col >> 3);
            float st  = red_s[t][0] + red_s[t][1] + red_s[t][2] + red_s[t][3];
            float sst = red_ss[t][0] + red_ss[t][1] + red_ss[t][2] + red_ss[t][3];
            mean[nt] = st * (1.f / 1024.f);
            float var = sst * (1.f / 1024.f) - mean[nt] * mean[nt];
            rstd[nt] = rsqrtf(var + 1e-5f);
        }
#pragma unroll
        for (int mtl = 0; mtl < 2; ++mtl) {
            int dq = w * 32 + mtl * 16 + quad * 4;
#pragma unroll
            for (int nt = 0; nt < 4; ++nt) {
                int n = nt * 16 + col; int t = n >> 3, g = n & 7;
                int e = g * D + dq;
                float4 pg4 = *(const float4*)(pf + 640 + e);
                float4 pb4 = *(const float4*)(pf + 1664 + e);
                float zv[4];
#pragma unroll
                for (int r = 0; r < 4; ++r)
                    zv[r] = (vals[mtl][nt][r] - mean[nt]) * rstd[nt] * f4c(pg4, r)
                            + f4c(pb4, r);
                uint2 o;
                o.x = pk_bf16(zv[0], zv[1]);
                o.y = pk_bf16(zv[2], zv[3]);
                *(uint2*)(zout + (tok0 + t) * PK + e) = o;
            }
        }
    }
}

// ---------- z @ Wm + bm via MFMA ----------
// R8/R10-PROVEN config: BK=64 single-buffer, 16 K-steps, 32 MFMA per
// barrier-drain, both-sides chunk-XOR swizzle (rule #21), (256,3), 32KB LDS.
// (R11's counted-vmcnt graft measured null-to-negative; do not re-add.)
__global__ __launch_bounds__(256, 3)
void gemm_out(const u16* __restrict__ z, const u16* __restrict__ wmt,
              const float* __restrict__ bmf, void* __restrict__ out,
              const int* __restrict__ flag) {
    const bool isbf = (flag[0] != 0);
    __shared__ u16 As[128 * 64];   // z tile   [m][k], chunk-swizzled contents
    __shared__ u16 Bs[128 * 64];   // WmT tile [n][k], chunk-swizzled contents
    const int tid = threadIdx.x, lane = tid & 63, w = tid >> 6;
    const int quad = lane >> 4, col = lane & 15;
    // XCD-bijective swizzle (nwg = 1024, % 8 == 0)
    const int swz = ((blockIdx.x & 7) << 7) | ((int)blockIdx.x >> 3);
    const int bm0 = (swz >> 3) * 128, bn0 = (swz & 7) * 128;
    const int wm = w >> 1, wn = w & 1;
    f32x4 acc[4][4] = {};            // [nt][mt]

    const u16* zrow0 = z   + (size_t)bm0 * DM;
    const u16* wrow0 = wmt + (size_t)bn0 * DM;

    for (int k0 = 0; k0 < DM; k0 += 64) {
#pragma unroll
        for (int q = 0; q < 4; ++q) {
            int c = q * 256 + tid;
            int r = c >> 3;                    // row 0..127
            int jj = (c & 7) ^ (r & 7);        // pre-swizzled source chunk
            const int ldsoff = (q * 256 + w * 64) * 8;   // wave-uniform, u16
            gload_lds16(zrow0 + (size_t)r * DM + k0 + jj * 8, &As[ldsoff]);
            gload_lds16(wrow0 + (size_t)r * DM + k0 + jj * 8, &Bs[ldsoff]);
        }
        __syncthreads();   // vmcnt(0) drain + barrier: tile ready
#pragma unroll
        for (int kk = 0; kk < 2; ++kk) {
            short8 zfr[4], wfr[4];
#pragma unroll
            for (int mt = 0; mt < 4; ++mt) {
                int row = wm * 64 + mt * 16 + col;
                zfr[mt] = *(const short8*)
                    &As[row * 64 + (((kk * 4 + quad) ^ (row & 7)) << 3)];
            }
#pragma unroll
            for (int nt = 0; nt < 4; ++nt) {
                int row = wn * 64 + nt * 16 + col;
                wfr[nt] = *(const short8*)
                    &Bs[row * 64 + (((kk * 4 + quad) ^ (row & 7)) << 3)];
            }
#pragma unroll
            for (int nt = 0; nt < 4; ++nt)
#pragma unroll
                for (int mt = 0; mt < 4; ++mt)
                    acc[nt][mt] = __builtin_amdgcn_mfma_f32_16x16x32_bf16(
                        wfr[nt], zfr[mt], acc[nt][mt], 0, 0, 0);
        }
        __syncthreads();   // all reads done before next stage overwrites
    }
    // epilogue: C rows = n (quad*4+r), cols = m
#pragma unroll
    for (int nt = 0; nt < 4; ++nt) {
        int n = bn0 + wn * 64 + nt * 16 + quad * 4;
        float4 bq = *(const float4*)(bmf + n);
#pragma unroll
        for (int mt = 0; mt < 4; ++mt) {
            int m = bm0 + wm * 64 + mt * 16 + col;
            float4 o = make_float4(acc[nt][mt][0] + bq.x, acc[nt][mt][1] + bq.y,
                                   acc[nt][mt][2] + bq.z, acc[nt][mt][3] + bq.w);
            st4rt(out, (size_t)m * DM + n, o, isbf);
        }
    }
}

// ---------- scalar fallback (R2-proven), raw weights ----------
template <bool ISBF>
__global__ __launch_bounds__(256)
void slotconv_scalar(const void* __restrict__ x,
                     const void* __restrict__ slot_gate,
                     const void* __restrict__ slot_bias,
                     const void* __restrict__ pre_g,
                     const void* __restrict__ pre_b,
                     const void* __restrict__ w1raw,
                     const void* __restrict__ b1,
                     const void* __restrict__ w2raw,
                     const void* __restrict__ b2,
                     const void* __restrict__ pack_g,
                     const void* __restrict__ pack_b,
                     const void* __restrict__ Wm,
                     const void* __restrict__ bm,
                     void* __restrict__ out,
                     const int* __restrict__ flag) {
    if ((flag[0] != 0) != ISBF) return;
    __shared__ float resid[G * D];
    __shared__ float xnpadf[(G + 2) * D];
    __shared__ float midpadf[(G + 2) * H];
    __shared__ float zbuf[4][PK];
    __shared__ float red[8];
    const int tid = threadIdx.x;
    if (tid < D) { xnpadf[tid] = 0.f; xnpadf[(G + 1) * D + tid] = 0.f; }
    midpadf[tid] = 0.f; midpadf[(G + 1) * H + tid] = 0.f;
    const int e0 = 4 * tid;
    const int d0 = e0 & (D - 1);
    const int g0 = tid >> 5;
    float gate[4], bias[4], pgf[4], pbf[4];
    {
        float4 sg4 = ld4<ISBF>(slot_gate, e0);
        float4 sb4 = ld4<ISBF>(slot_bias, e0);
        float4 pg4 = ld4<ISBF>(pre_g, d0);
        float4 pb4 = ld4<ISBF>(pre_b, d0);
#pragma unroll
        for (int j = 0; j < 4; ++j) {
            gate[j] = 2.f / (1.f + __expf(-f4c(sg4, j)));
            bias[j] = f4c(sb4, j);
            pgf[j] = f4c(pg4, j); pbf[j] = f4c(pb4, j);
        }
    }
    for (int t = 0; t < 4; ++t) {
        __syncthreads();
        const size_t tok = (size_t)blockIdx.x * 4 + t;
        {
            float4 x4 = ld4<ISBF>(x, tok * PK + e0);
            float v[4];
#pragma unroll
            for (int j = 0; j < 4; ++j) v[j] = f4c(x4, j) * gate[j] + bias[j];
            *(float4*)&resid[e0] = make_float4(v[0], v[1], v[2], v[3]);
            float s = v[0]+v[1]+v[2]+v[3], ss = v[0]*v[0]+v[1]*v[1]+v[2]*v[2]+v[3]*v[3];
#pragma unroll
            for (int m = 1; m < 32; m <<= 1) { s += __shfl_xor(s, m); ss += __shfl_xor(ss, m); }
            float mean = s * (1.f/128.f), var = ss * (1.f/128.f) - mean*mean;
            float rstd = rsqrtf(var + 1e-5f);
            float xn[4];
#pragma unroll
            for (int j = 0; j < 4; ++j) xn[j] = (v[j]-mean)*rstd*pgf[j]+pbf[j];
            *(float4*)&xnpadf[(g0+1)*D + d0] = make_float4(xn[0],xn[1],xn[2],xn[3]);
        }
        __syncthreads();
        {
            const int h = tid;
            float acc[G];
#pragma unroll
            for (int g = 0; g < G; ++g) acc[g] = 0.f;
            for (int d4 = 0; d4 < D; d4 += 4) {
                float4 xr4[G + 2];
#pragma unroll
                for (int r = 0; r < G + 2; ++r) xr4[r] = *(const float4*)&xnpadf[r * D + d4];
#pragma unroll
                for (int j = 0; j < 4; ++j) {
                    size_t o = (size_t)h * (D * 3) + (d4 + j) * 3;
                    float wk0 = ld1<ISBF>(w1raw, o), wk1 = ld1<ISBF>(w1raw, o+1), wk2 = ld1<ISBF>(w1raw, o+2);
#pragma unroll
                    for (int g = 0; g < G; ++g) {
                        acc[g] += f4c(xr4[g+0], j) * wk0;
                        acc[g] += f4c(xr4[g+1], j) * wk1;
                        acc[g] += f4c(xr4[g+2], j) * wk2;
                    }
                }
            }
            float b1h = ld1<ISBF>(b1, tid);
#pragma unroll
            for (int g = 0; g < G; ++g) {
                float m = acc[g] + b1h;
                midpadf[(g+1)*H + h] = 0.5f * m * (1.f + erff(m * 0.70710678118654752f));
            }
        }
        __syncthreads();
        {
            const int dd = tid & (D - 1);
            const int gh = tid >> 7;
            float acc2[4] = {0.f,0.f,0.f,0.f};
            for (int h4 = 0; h4 < H; h4 += 4) {
                float4 mr4[6];
#pragma unroll
                for (int r = 0; r < 6; ++r) mr4[r] = *(const float4*)&midpadf[(gh*4+r)*H + h4];
#pragma unroll
                for (int j = 0; j < 4; ++j) {
                    size_t o = (size_t)dd * (H * 3) + (h4 + j) * 3;
                    float wk0 = ld1<ISBF>(w2raw, o), wk1 = ld1<ISBF>(w2raw, o+1), wk2 = ld1<ISBF>(w2raw, o+2);
#pragma unroll
                    for (int jj = 0; jj < 4; ++jj) {
                        acc2[jj] += f4c(mr4[jj+0], j) * wk0;
                        acc2[jj] += f4c(mr4[jj+1], j) * wk1;
                        acc2[jj] += f4c(mr4[jj+2], j) * wk2;
                    }
                }
            }
            float b2d = ld1<ISBF>(b2, dd);
            float vz[4], s = 0.f, ss = 0.f;
#pragma unroll
            for (int j = 0; j < 4; ++j) {
                int e = (gh*4+j)*D + dd;
                float val = acc2[j] + b2d + resid[e];
                vz[j] = val; s += val; ss += val*val;
            }
#pragma unroll
            for (int m = 1; m < 64; m <<= 1) { s += __shfl_xor(s, m); ss += __shfl_xor(ss, m); }
            const int wid = tid >> 6;
            if ((tid & 63) == 0) { red[wid*2] = s; red[wid*2+1] = ss; }
            __syncthreads();
            float st = red[0]+red[2]+red[4]+red[6], sst = red[1]+red[3]+red[5]+red[7];
            float mean = st * (1.f/1024.f), var = sst * (1.f/1024.f) - mean*mean;
            float rstd = rsqrtf(var + 1e-5f);
#pragma unroll
            for (int j = 0; j < 4; ++j) {
                int e = (gh*4+j)*D + dd;
                zbuf[t][e] = (vz[j]-mean)*rstd*ld1<ISBF>(pack_g, e) + ld1<ISBF>(pack_b, e);
            }
        }
    }
    __syncthreads();
    {
        float accm[4][4];
#pragma unroll
        for (int t = 0; t < 4; ++t)
#pragma unroll
            for (int j = 0; j < 4; ++j) accm[t][j] = 0.f;
        for (int p4 = 0; p4 < PK; p4 += 4) {
            float4 z4[4];
#pragma unroll
            for (int t = 0; t < 4; ++t) z4[t] = *(const float4*)&zbuf[t][p4];
#pragma unroll
            for (int pp = 0; pp < 4; ++pp) {
                float4 w4 = ld4<ISBF>(Wm, (size_t)(p4 + pp) * DM + e0);
#pragma unroll
                for (int t = 0; t < 4; ++t) {
                    float zp = f4c(z4[t], pp);
                    accm[t][0] += zp * w4.x; accm[t][1] += zp * w4.y;
                    accm[t][2] += zp * w4.z; accm[t][3] += zp * w4.w;
                }
            }
        }
        float4 bm4 = ld4<ISBF>(bm, e0);
#pragma unroll
        for (int t = 0; t < 4; ++t) {
            const size_t tok = (size_t)blockIdx.x * 4 + t;
            st4<ISBF>(out, tok * DM + e0,
                      make_float4(accm[t][0]+bm4.x, accm[t][1]+bm4.y,
                                  accm[t][2]+bm4.z, accm[t][3]+bm4.w));
        }
    }
}

extern "C" void kernel_launch(void* const* d_in, const int* in_sizes, int n_in,
                              void* d_out, int out_size, void* d_ws, size_t ws_size,
                              hipStream_t stream) {
    const void* x   = d_in[0];
    const void* sg  = d_in[1];
    const void* sb  = d_in[2];
    const void* pg  = d_in[3];
    const void* pb  = d_in[4];
    const void* w1  = d_in[5];
    const void* b1  = d_in[6];
    const void* w2  = d_in[7];
    const void* b2  = d_in[8];
    const void* pkg = d_in[9];
    const void* pkb = d_in[10];
    const void* Wm  = d_in[11];
    const void* bm  = d_in[12];

    int* flag = (int*)d_ws;
    u16* base = (u16*)((char*)d_ws + 16);
    u16* w1p = base;                       // 98304 el
    u16* w2p = base + 98304;               // 98304 el
    u16* wmt = base + 196608;              // 1048576 el
    u16* zws = base + 196608 + 1048576;    // 16777216 el
    float* pf = (float*)(base + 18022400); // 5760 f32 params
    const size_t ws_needed = 16 + (size_t)18022400 * sizeof(u16) + PF_N * sizeof(float);

    detect_dtype<<<1, 256, 0, stream>>>(x, flag);

    if (ws_size >= ws_needed) {
        prep_mfma<<<640, 256, 0, stream>>>(w1, w2, Wm, pg, pb, b1, b2, pkg, pkb, bm,
                                           sg, sb, w1p, w2p, wmt, pf, flag);
        conv_fused<true ><<<NTOK / 8, 256, 0, stream>>>(x, zws, w1p, w2p, pf, flag);
        conv_fused<false><<<NTOK / 8, 256, 0, stream>>>(x, zws, w1p, w2p, pf, flag);
        gemm_out<<<(NTOK / 128) * (DM / 128), 256, 0, stream>>>(zws, wmt, pf + 2688, d_out, flag);
    } else {
        slotconv_scalar<true ><<<NTOK / 4, 256, 0, stream>>>(
            x, sg, sb, pg, pb, w1, b1, w2, b2, pkg, pkb, Wm, bm, d_out, flag);
        slotconv_scalar<false><<<NTOK / 4, 256, 0, stream>>>(
            x, sg, sb, pg, pb, w1, b1, w2, b2, pkg, pkb, Wm, bm, d_out, flag);
    }
}

// Round 15
// 288.796 us; speedup vs baseline: 1.0550x; 1.0093x over previous
//
#include <hip/hip_runtime.h>
#include <hip/hip_bf16.h>
#include <math.h>

typedef unsigned short u16;
typedef unsigned int   u32;
typedef __attribute__((ext_vector_type(8))) short short8;   // 8 bf16
typedef __attribute__((ext_vector_type(4))) float f32x4;    // MFMA acc

// Problem constants
constexpr int G  = 8;
constexpr int D  = 128;
constexpr int H  = 256;
constexpr int DM = 1024;
constexpr int PK = 1024;
constexpr int NTOK = 8 * 2048;   // 16384

// f32 param ws layout (floats): [0]pre_g(128) [128]pre_b(128) [256]b1(256)
// [512]b2(128) [640]pack_g(1024) [1664]pack_b(1024) [2688]bm(1024)
// [3712]gate=2*sigmoid(slot_gate)(1024) [4736]slot_bias(1024) -> 5760
constexpr int PF_N = 5760;

// ---------- scalar helpers ----------
__device__ __forceinline__ float bf2f(u16 u) {
    union { u32 i; float f; } v; v.i = ((u32)u) << 16; return v.f;
}
__device__ __forceinline__ u16 f2bf(float f) {
    union { float f; u32 i; } v; v.f = f;
    u32 x = v.i;
    return (u16)((x + 0x7fffu + ((x >> 16) & 1u)) >> 16);  // RNE
}
// packed f32x2 -> bf16x2 (RNE), single VALU op
__device__ __forceinline__ u32 pk_bf16(float lo, float hi) {
    u32 d;
    asm("v_cvt_pk_bf16_f32 %0, %1, %2" : "=v"(d) : "v"(lo), "v"(hi));
    return d;
}
__device__ __forceinline__ float f4c(const float4 v, int j) {
    return j == 0 ? v.x : j == 1 ? v.y : j == 2 ? v.z : v.w;
}
template <bool ISBF>
__device__ __forceinline__ float ld1(const void* p, size_t i) {
    if (ISBF) return bf2f(((const u16*)p)[i]);
    else      return ((const float*)p)[i];
}
template <bool ISBF>
__device__ __forceinline__ float4 ld4(const void* p, size_t i) {  // i % 4 == 0
    if (ISBF) {
        ushort4 v = *(const ushort4*)((const u16*)p + i);
        return make_float4(bf2f(v.x), bf2f(v.y), bf2f(v.z), bf2f(v.w));
    } else {
        return *(const float4*)((const float*)p + i);
    }
}
// runtime-dtype variants (uniform branch on flag) — OK for prologue/epilogue
// one-shot loads; NOT for hot loops (R12/R13: branchy x loads cost conv +36us)
__device__ __forceinline__ float ld1rt(const void* p, size_t i, bool isbf) {
    return isbf ? bf2f(((const u16*)p)[i]) : ((const float*)p)[i];
}
__device__ __forceinline__ float4 ld4rt(const void* p, size_t i, bool isbf) {
    if (isbf) {
        ushort4 v = *(const ushort4*)((const u16*)p + i);
        return make_float4(bf2f(v.x), bf2f(v.y), bf2f(v.z), bf2f(v.w));
    } else {
        return *(const float4*)((const float*)p + i);
    }
}
template <bool ISBF>
__device__ __forceinline__ void st4(void* p, size_t i, float4 v) {
    if (ISBF) {
        ushort4 o; o.x = f2bf(v.x); o.y = f2bf(v.y); o.z = f2bf(v.z); o.w = f2bf(v.w);
        *(ushort4*)((u16*)p + i) = o;
    } else {
        *(float4*)((float*)p + i) = v;
    }
}
__device__ __forceinline__ void st4rt(void* p, size_t i, float4 v, bool isbf) {
    if (isbf) {
        ushort4 o; o.x = f2bf(v.x); o.y = f2bf(v.y); o.z = f2bf(v.z); o.w = f2bf(v.w);
        *(ushort4*)((u16*)p + i) = o;
    } else {
        *(float4*)((float*)p + i) = v;
    }
}
// tanh-form GELU (max dev vs exact erf-GELU ~3e-4, tolerance 6.4e-2)
__device__ __forceinline__ float gelu_f(float v) {
    float u = v * (0.7978845608028654f + 0.0356774081f * v * v);
    float e = __expf(2.f * u);
    float th = 1.f - 2.f / (e + 1.f);
    return 0.5f * v * (1.f + th);
}
// async global->LDS, 16B per lane; LDS dest = wave-uniform base + lane*16
__device__ __forceinline__ void gload_lds16(const void* gp, void* lp) {
    __builtin_amdgcn_global_load_lds(
        (const __attribute__((address_space(1))) void*)gp,
        (__attribute__((address_space(3))) void*)lp, 16, 0, 0);
}

// ---------- dtype detect (proven R2) ----------
__global__ void detect_dtype(const void* xraw, int* flag) {
    __shared__ int cnt[256];
    const u32* xw = (const u32*)xraw;
    int tid = threadIdx.x, c = 0;
#pragma unroll
    for (int k = 0; k < 4; ++k) {
        u32 w = xw[tid * 4 + k];
#pragma unroll
        for (int h = 0; h < 2; ++h) {
            u16 u = (u16)(w >> (16 * h));
            int e = (u >> 7) & 0xFF;
            if ((u & 0x7FFF) == 0 || (e >= 112 && e <= 143)) ++c;
        }
    }
    cnt[tid] = c;
    __syncthreads();
    for (int s = 128; s > 0; s >>= 1) {
        if (tid < s) cnt[tid] += cnt[tid + s];
        __syncthreads();
    }
    if (tid == 0) flag[0] = (cnt[0] >= 1900) ? 1 : 0;
}

// ---------- MFMA-path weight prep (single dispatch, runtime isbf) ----------
// blocks [0,256): Wm -> wmt (WmT, bf16) via LDS 64x64 tile transpose
// blocks [256,640): fragment-major conv weights + f32 param conversion
// (incl. gate = 2*sigmoid(slot_gate) and slot_bias, both f32).
__global__ __launch_bounds__(256)
void prep_mfma(const void* __restrict__ w1, const void* __restrict__ w2,
               const void* __restrict__ Wm,
               const void* __restrict__ pre_g, const void* __restrict__ pre_b,
               const void* __restrict__ b1, const void* __restrict__ b2,
               const void* __restrict__ pkg, const void* __restrict__ pkb,
               const void* __restrict__ bm,
               const void* __restrict__ sg, const void* __restrict__ sb,
               u16* __restrict__ w1p, u16* __restrict__ w2p,
               u16* __restrict__ wmt, float* __restrict__ pf,
               const int* __restrict__ flag) {
    const bool isbf = (flag[0] != 0);
    __shared__ u16 tile[64][72];
    const int tid = threadIdx.x;
    if (blockIdx.x < 256) {
        const int kk0 = (blockIdx.x >> 4) * 64, n0 = (blockIdx.x & 15) * 64;
        const int r = tid >> 2, q = tid & 3;
#pragma unroll
        for (int j4 = 0; j4 < 4; ++j4) {
            float4 v = ld4rt(Wm, (size_t)(kk0 + r) * DM + n0 + q * 16 + j4 * 4, isbf);
            tile[r][q * 16 + j4 * 4 + 0] = f2bf(v.x);
            tile[r][q * 16 + j4 * 4 + 1] = f2bf(v.y);
            tile[r][q * 16 + j4 * 4 + 2] = f2bf(v.z);
            tile[r][q * 16 + j4 * 4 + 3] = f2bf(v.w);
        }
        __syncthreads();
        u16 op[16];
#pragma unroll
        for (int j = 0; j < 16; ++j) op[j] = tile[q * 16 + j][r];
        u16* dst = wmt + (size_t)(n0 + r) * DM + kk0 + q * 16;
        *(short8*)dst       = *(const short8*)&op[0];
        *(short8*)(dst + 8) = *(const short8*)&op[8];
        return;
    }
    int idx = (blockIdx.x - 256) * 256 + tid;
    if (idx < 3 * 4 * H * 32) {          // 98304 for each of w1p/w2p
        int jq = idx & 31;
        int t2 = idx >> 5;
        int h  = t2 & (H - 1);
        int ik = t2 >> 8;                // 0..11
        int kt1 = ik >> 2, kk1 = ik & 3;
        int dd = kk1 * 32 + jq;
        w1p[idx] = f2bf(ld1rt(w1, (size_t)(h * D + dd) * 3 + kt1, isbf));
        int d   = t2 & (D - 1);
        int ik2 = t2 >> 7;               // 0..23
        int kt2 = ik2 >> 3, kk2 = ik2 & 7;
        int hh = kk2 * 32 + jq;
        w2p[idx] = f2bf(ld1rt(w2, (size_t)(d * H + hh) * 3 + kt2, isbf));
    }
    if (idx < D) {
        pf[idx]       = ld1rt(pre_g, idx, isbf);
        pf[128 + idx] = ld1rt(pre_b, idx, isbf);
        pf[512 + idx] = ld1rt(b2, idx, isbf);
    }
    if (idx < H) pf[256 + idx] = ld1rt(b1, idx, isbf);
    if (idx < PK) {
        pf[640  + idx] = ld1rt(pkg, idx, isbf);
        pf[1664 + idx] = ld1rt(pkb, idx, isbf);
        pf[2688 + idx] = ld1rt(bm, idx, isbf);
        pf[3712 + idx] = 2.f / (1.f + __expf(-ld1rt(sg, idx, isbf)));
        pf[4736 + idx] = ld1rt(sb, idx, isbf);
    }
}

// ---------- fused gate+LN1+conv1+GELU+conv2+LN2 : x -> z (bf16, into zws) ----------
// R14-PROVEN: templated x-loads (runtime-branch loads cost +36us: R12/R13 A/B).
// Gate from f32 pf; x read twice (epilogue L2-hot). Twin dispatch.
// (256,3) -> VGPR 80, WRITE 33MB clean, ~136 us. (256,4) spills (R6/R9).
// LDS union uni[74*256 u16] (37888 B):
//   xnpad rows 0..72: r*128 | midpad M_lo r*256 | M_hi r*256+256
template <bool ISBF>
__global__ __launch_bounds__(256, 3)
void conv_fused(const void* __restrict__ x,
                u16* __restrict__ zout,
                const u16* __restrict__ w1p,
                const u16* __restrict__ w2p,
                const float* __restrict__ pf,
                const int* __restrict__ flag) {
    if ((flag[0] != 0) != ISBF) return;
    __shared__ u16 uni[74 * 256];          // 37888 B union
    __shared__ float red_s[8][4], red_ss[8][4];

    const int tid  = threadIdx.x;
    const int lane = tid & 63, w = tid >> 6;
    const int quad = lane >> 4, col = lane & 15;
    const size_t tok0 = (size_t)blockIdx.x * 8;

    // ---- stage 0: zero xnpad halo rows (9 x 128) + M_hi halo rows {45,54,63,72} ----
    if (tid < 72) {
        int li = tid * 16, hr = li >> 7, e = li & 127;
        u16* p = &uni[hr * 9 * 128 + e];
#pragma unroll
        for (int q = 0; q < 4; ++q) *(ushort4*)(p + 4 * q) = make_ushort4(0, 0, 0, 0);
    } else if (tid >= 128) {
        int li = (tid - 128) * 8, hr = li >> 8, e = li & 255;
        int row = 45 + hr * 9;                       // 45,54,63,72
        u16* p = &uni[row * 256 + 256 + e];          // M_hi mapping
        *(ushort4*)p       = make_ushort4(0, 0, 0, 0);
        *(ushort4*)(p + 4) = make_ushort4(0, 0, 0, 0);
    }

    const int e0 = 4 * tid;
    const int d0 = e0 & (D - 1);
    const int g0 = tid >> 5;
    float4 gg   = *(const float4*)(pf + 3712 + e0);   // 2*sigmoid(slot_gate)
    float4 sbb  = *(const float4*)(pf + 4736 + e0);   // slot_bias
    float4 pg4s = *(const float4*)(pf + d0);          // pre_g
    float4 pb4s = *(const float4*)(pf + 128 + d0);    // pre_b

    // ---- stage 1: gate+bias (f32), LN1 -> xnpad (bf16, swizzled) ----
#pragma unroll
    for (int t = 0; t < 8; ++t) {
        float4 x4 = ld4<ISBF>(x, (tok0 + t) * PK + e0);
        float v[4];
#pragma unroll
        for (int j = 0; j < 4; ++j) v[j] = f4c(x4, j) * f4c(gg, j) + f4c(sbb, j);
        float s = v[0] + v[1] + v[2] + v[3];
        float ss = v[0]*v[0] + v[1]*v[1] + v[2]*v[2] + v[3]*v[3];
#pragma unroll
        for (int m = 1; m < 32; m <<= 1) {
            s  += __shfl_xor(s,  m);
            ss += __shfl_xor(ss, m);
        }
        float mean = s * (1.f / 128.f);
        float var  = ss * (1.f / 128.f) - mean * mean;
        float rstd = rsqrtf(var + 1e-5f);
        uint2 o;
        o.x = pk_bf16((v[0] - mean) * rstd * pg4s.x + pb4s.x,
                      (v[1] - mean) * rstd * pg4s.y + pb4s.y);
        o.y = pk_bf16((v[2] - mean) * rstd * pg4s.z + pb4s.z,
                      (v[3] - mean) * rstd * pg4s.w + pb4s.w);
        int row  = t * 9 + g0 + 1;
        int addr = row * 128 + (((d0 >> 3) ^ (row & 7)) << 3) + (d0 & 7);
        *(uint2*)&uni[addr] = o;
    }
    __syncthreads();

    int rowb[4];
#pragma unroll
    for (int nt = 0; nt < 4; ++nt) {
        int n = nt * 16 + col;
        rowb[nt] = (n >> 3) * 9 + (n & 7);
    }
    const int alane1 = (w * 64 + col) * 32 + quad * 8;
    const int alane2 = (w * 32 + col) * 32 + quad * 8;

    // ---- stage 2: conv1 via MFMA, two nt-passes (32-AGPR live acc each) ----
#pragma unroll
    for (int pass = 0; pass < 2; ++pass) {
        const int ntb = (pass == 0) ? 2 : 0;
        f32x4 acc[4][2] = {};
#pragma unroll
        for (int it = 0; it < 12; ++it) {
            const int ktap = it >> 2, kk = it & 3;
            short8 afr[4];
#pragma unroll
            for (int mtl = 0; mtl < 4; ++mtl)
                afr[mtl] = *(const short8*)(w1p + it * 8192 + mtl * 512 + alane1);
            short8 bfr[2];
#pragma unroll
            for (int ntl = 0; ntl < 2; ++ntl) {
                int rr = rowb[ntb + ntl] + ktap;
                int a  = rr * 128 + (((kk * 4 + quad) ^ (rr & 7)) << 3);
                bfr[ntl] = *(const short8*)&uni[a];
            }
#pragma unroll
            for (int mtl = 0; mtl < 4; ++mtl)
#pragma unroll
                for (int ntl = 0; ntl < 2; ++ntl)
                    acc[mtl][ntl] = __builtin_amdgcn_mfma_f32_16x16x32_bf16(
                        afr[mtl], bfr[ntl], acc[mtl][ntl], 0, 0, 0);
        }
        if (pass == 1) {
            __syncthreads();
            if (tid < 160) {
                int li = tid * 8, hr = li >> 8, e = li & 255;
                u16* p = &uni[hr * 9 * 256 + e];
                *(ushort4*)p       = make_ushort4(0, 0, 0, 0);
                *(ushort4*)(p + 4) = make_ushort4(0, 0, 0, 0);
            }
        }
#pragma unroll
        for (int mtl = 0; mtl < 4; ++mtl) {
            int hq = w * 64 + mtl * 16 + quad * 4;
            float4 b1q = *(const float4*)(pf + 256 + hq);
#pragma unroll
            for (int ntl = 0; ntl < 2; ++ntl) {
                int row = rowb[ntb + ntl] + 1;
                uint2 o;
                o.x = pk_bf16(gelu_f(acc[mtl][ntl][0] + b1q.x),
                              gelu_f(acc[mtl][ntl][1] + b1q.y));
                o.y = pk_bf16(gelu_f(acc[mtl][ntl][2] + b1q.z),
                              gelu_f(acc[mtl][ntl][3] + b1q.w));
                int mb = row * 256 + ((row >= 37) ? 256 : 0);
                int a  = mb + (((hq >> 3) ^ (row & 7)) << 3) + (hq & 7);
                *(uint2*)&uni[a] = o;
            }
        }
    }
    __syncthreads();

    // ---- stage 3: conv2 via MFMA + bias + residual + LN2 + pack ----
    f32x4 acc2[2][4] = {};
#pragma unroll
    for (int it = 0; it < 24; ++it) {
        const int ktap = it >> 3, kk = it & 7;
        short8 cfr[2];
#pragma unroll
        for (int mtl = 0; mtl < 2; ++mtl)
            cfr[mtl] = *(const short8*)(w2p + it * 4096 + mtl * 512 + alane2);
        short8 bfr[4];
#pragma unroll
        for (int nt = 0; nt < 4; ++nt) {
            int rr = rowb[nt] + ktap;
            int mb = rr * 256 + ((rr >= 37) ? 256 : 0);
            int a  = mb + (((kk * 4 + quad) ^ (rr & 7)) << 3);
            bfr[nt] = *(const short8*)&uni[a];
        }
#pragma unroll
        for (int mtl = 0; mtl < 2; ++mtl)
#pragma unroll
            for (int nt = 0; nt < 4; ++nt)
                acc2[mtl][nt] = __builtin_amdgcn_mfma_f32_16x16x32_bf16(
                    cfr[mtl], bfr[nt], acc2[mtl][nt], 0, 0, 0);
    }
    {
        float vals[2][4][4];
        float s[4] = {0.f, 0.f, 0.f, 0.f}, ss[4] = {0.f, 0.f, 0.f, 0.f};
#pragma unroll
        for (int mtl = 0; mtl < 2; ++mtl) {
            int dq = w * 32 + mtl * 16 + quad * 4;
            float4 b2q = *(const float4*)(pf + 512 + dq);
#pragma unroll
            for (int nt = 0; nt < 4; ++nt) {
                int n = nt * 16 + col; int t = n >> 3, g = n & 7;
                int e = g * D + dq;
                float4 xr = ld4<ISBF>(x, (tok0 + t) * PK + e);   // L2-hot re-read
                float4 gq = *(const float4*)(pf + 3712 + e);
                float4 bq = *(const float4*)(pf + 4736 + e);
#pragma unroll
                for (int r = 0; r < 4; ++r) {
                    float resid = f4c(xr, r) * f4c(gq, r) + f4c(bq, r);
                    float val = acc2[mtl][nt][r] + f4c(b2q, r) + resid;
                    vals[mtl][nt][r] = val;
                    s[nt] += val; ss[nt] += val * val;
                }
            }
        }
        // reduce over lanes sharing token t: masks {1,2,4,16,32}
#pragma unroll
        for (int nt = 0; nt < 4; ++nt) {
            s[nt] += __shfl_xor(s[nt], 1);  ss[nt] += __shfl_xor(ss[nt], 1);
            s[nt] += __shfl_xor(s[nt], 2);  ss[nt] += __shfl_xor(ss[nt], 2);
            s[nt] += __shfl_xor(s[nt], 4);  ss[nt] += __shfl_xor(ss[nt], 4);
            s[nt] += __shfl_xor(s[nt], 16); ss[nt] += __shfl_xor(ss[nt], 16);
            s[nt] += __shfl_xor(s[nt], 32); ss[nt] += __shfl_xor(ss[nt], 32);
        }
        if (quad == 0 && (col & 7) == 0) {
#pragma unroll
            for (int nt = 0; nt < 4; ++nt) {
                int t = 2 * nt + (col >> 3);
                red_s[t][w] = s[nt]; red_ss[t][w] = ss[nt];
            }
        }
        __syncthreads();
        float mean[4], rstd[4];
#pragma unroll
        for (int nt = 0; nt < 4; ++nt) {
            int t = 2 * nt + (col >> 3);
            float st  = red_s[t][0] + red_s[t][1] + red_s[t][2] + red_s[t][3];
            float sst = red_ss[t][0] + red_ss[t][1] + red_ss[t][2] + red_ss[t][3];
            mean[nt] = st * (1.f / 1024.f);
            float var = sst * (1.f / 1024.f) - mean[nt] * mean[nt];
            rstd[nt] = rsqrtf(var + 1e-5f);
        }
#pragma unroll
        for (int mtl = 0; mtl < 2; ++mtl) {
            int dq = w * 32 + mtl * 16 + quad * 4;
#pragma unroll
            for (int nt = 0; nt < 4; ++nt) {
                int n = nt * 16 + col; int t = n >> 3, g = n & 7;
                int e = g * D + dq;
                float4 pg4 = *(const float4*)(pf + 640 + e);
                float4 pb4 = *(const float4*)(pf + 1664 + e);
                float zv[4];
#pragma unroll
                for (int r = 0; r < 4; ++r)
                    zv[r] = (vals[mtl][nt][r] - mean[nt]) * rstd[nt] * f4c(pg4, r)
                            + f4c(pb4, r);
                uint2 o;
                o.x = pk_bf16(zv[0], zv[1]);
                o.y = pk_bf16(zv[2], zv[3]);
                *(uint2*)(zout + (tok0 + t) * PK + e) = o;
            }
        }
    }
}

// ---------- z @ Wm + bm via MFMA ----------
// R15: (256,3) -> (256,4). gemm's footprint (64 AGPR acc + ~40 arch VGPR
// ~= 104) fits the 128-reg cap of 4 waves/SIMD — unlike conv (~150, spills).
// LDS 32KB x 4 = 128KB <= 160KB. Grid 1024 = 256 CU x 4: EXACTLY one
// dispatch wave (old 3/CU left a 256-block tail at 1/CU occupancy).
// Config otherwise R8-proven: BK=64 single-buffer, 32 MFMA/barrier-drain,
// both-sides chunk-XOR swizzle. FALSIFIER: spill -> revert to (256,3).
__global__ __launch_bounds__(256, 4)
void gemm_out(const u16* __restrict__ z, const u16* __restrict__ wmt,
              const float* __restrict__ bmf, void* __restrict__ out,
              const int* __restrict__ flag) {
    const bool isbf = (flag[0] != 0);
    __shared__ u16 As[128 * 64];   // z tile   [m][k], chunk-swizzled contents
    __shared__ u16 Bs[128 * 64];   // WmT tile [n][k], chunk-swizzled contents
    const int tid = threadIdx.x, lane = tid & 63, w = tid >> 6;
    const int quad = lane >> 4, col = lane & 15;
    // XCD-bijective swizzle (nwg = 1024, % 8 == 0)
    const int swz = ((blockIdx.x & 7) << 7) | ((int)blockIdx.x >> 3);
    const int bm0 = (swz >> 3) * 128, bn0 = (swz & 7) * 128;
    const int wm = w >> 1, wn = w & 1;
    f32x4 acc[4][4] = {};            // [nt][mt]

    const u16* zrow0 = z   + (size_t)bm0 * DM;
    const u16* wrow0 = wmt + (size_t)bn0 * DM;

    for (int k0 = 0; k0 < DM; k0 += 64) {
#pragma unroll
        for (int q = 0; q < 4; ++q) {
            int c = q * 256 + tid;
            int r = c >> 3;                    // row 0..127
            int jj = (c & 7) ^ (r & 7);        // pre-swizzled source chunk
            const int ldsoff = (q * 256 + w * 64) * 8;   // wave-uniform, u16
            gload_lds16(zrow0 + (size_t)r * DM + k0 + jj * 8, &As[ldsoff]);
            gload_lds16(wrow0 + (size_t)r * DM + k0 + jj * 8, &Bs[ldsoff]);
        }
        __syncthreads();   // vmcnt(0) drain + barrier: tile ready
#pragma unroll
        for (int kk = 0; kk < 2; ++kk) {
            short8 zfr[4], wfr[4];
#pragma unroll
            for (int mt = 0; mt < 4; ++mt) {
                int row = wm * 64 + mt * 16 + col;
                zfr[mt] = *(const short8*)
                    &As[row * 64 + (((kk * 4 + quad) ^ (row & 7)) << 3)];
            }
#pragma unroll
            for (int nt = 0; nt < 4; ++nt) {
                int row = wn * 64 + nt * 16 + col;
                wfr[nt] = *(const short8*)
                    &Bs[row * 64 + (((kk * 4 + quad) ^ (row & 7)) << 3)];
            }
#pragma unroll
            for (int nt = 0; nt < 4; ++nt)
#pragma unroll
                for (int mt = 0; mt < 4; ++mt)
                    acc[nt][mt] = __builtin_amdgcn_mfma_f32_16x16x32_bf16(
                        wfr[nt], zfr[mt], acc[nt][mt], 0, 0, 0);
        }
        __syncthreads();   // all reads done before next stage overwrites
    }
    // epilogue: C rows = n (quad*4+r), cols = m
#pragma unroll
    for (int nt = 0; nt < 4; ++nt) {
        int n = bn0 + wn * 64 + nt * 16 + quad * 4;
        float4 bq = *(const float4*)(bmf + n);
#pragma unroll
        for (int mt = 0; mt < 4; ++mt) {
            int m = bm0 + wm * 64 + mt * 16 + col;
            float4 o = make_float4(acc[nt][mt][0] + bq.x, acc[nt][mt][1] + bq.y,
                                   acc[nt][mt][2] + bq.z, acc[nt][mt][3] + bq.w);
            st4rt(out, (size_t)m * DM + n, o, isbf);
        }
    }
}

// ---------- scalar fallback (R2-proven), raw weights ----------
template <bool ISBF>
__global__ __launch_bounds__(256)
void slotconv_scalar(const void* __restrict__ x,
                     const void* __restrict__ slot_gate,
                     const void* __restrict__ slot_bias,
                     const void* __restrict__ pre_g,
                     const void* __restrict__ pre_b,
                     const void* __restrict__ w1raw,
                     const void* __restrict__ b1,
                     const void* __restrict__ w2raw,
                     const void* __restrict__ b2,
                     const void* __restrict__ pack_g,
                     const void* __restrict__ pack_b,
                     const void* __restrict__ Wm,
                     const void* __restrict__ bm,
                     void* __restrict__ out,
                     const int* __restrict__ flag) {
    if ((flag[0] != 0) != ISBF) return;
    __shared__ float resid[G * D];
    __shared__ float xnpadf[(G + 2) * D];
    __shared__ float midpadf[(G + 2) * H];
    __shared__ float zbuf[4][PK];
    __shared__ float red[8];
    const int tid = threadIdx.x;
    if (tid < D) { xnpadf[tid] = 0.f; xnpadf[(G + 1) * D + tid] = 0.f; }
    midpadf[tid] = 0.f; midpadf[(G + 1) * H + tid] = 0.f;
    const int e0 = 4 * tid;
    const int d0 = e0 & (D - 1);
    const int g0 = tid >> 5;
    float gate[4], bias[4], pgf[4], pbf[4];
    {
        float4 sg4 = ld4<ISBF>(slot_gate, e0);
        float4 sb4 = ld4<ISBF>(slot_bias, e0);
        float4 pg4 = ld4<ISBF>(pre_g, d0);
        float4 pb4 = ld4<ISBF>(pre_b, d0);
#pragma unroll
        for (int j = 0; j < 4; ++j) {
            gate[j] = 2.f / (1.f + __expf(-f4c(sg4, j)));
            bias[j] = f4c(sb4, j);
            pgf[j] = f4c(pg4, j); pbf[j] = f4c(pb4, j);
        }
    }
    for (int t = 0; t < 4; ++t) {
        __syncthreads();
        const size_t tok = (size_t)blockIdx.x * 4 + t;
        {
            float4 x4 = ld4<ISBF>(x, tok * PK + e0);
            float v[4];
#pragma unroll
            for (int j = 0; j < 4; ++j) v[j] = f4c(x4, j) * gate[j] + bias[j];
            *(float4*)&resid[e0] = make_float4(v[0], v[1], v[2], v[3]);
            float s = v[0]+v[1]+v[2]+v[3], ss = v[0]*v[0]+v[1]*v[1]+v[2]*v[2]+v[3]*v[3];
#pragma unroll
            for (int m = 1; m < 32; m <<= 1) { s += __shfl_xor(s, m); ss += __shfl_xor(ss, m); }
            float mean = s * (1.f/128.f), var = ss * (1.f/128.f) - mean*mean;
            float rstd = rsqrtf(var + 1e-5f);
            float xn[4];
#pragma unroll
            for (int j = 0; j < 4; ++j) xn[j] = (v[j]-mean)*rstd*pgf[j]+pbf[j];
            *(float4*)&xnpadf[(g0+1)*D + d0] = make_float4(xn[0],xn[1],xn[2],xn[3]);
        }
        __syncthreads();
        {
            const int h = tid;
            float acc[G];
#pragma unroll
            for (int g = 0; g < G; ++g) acc[g] = 0.f;
            for (int d4 = 0; d4 < D; d4 += 4) {
                float4 xr4[G + 2];
#pragma unroll
                for (int r = 0; r < G + 2; ++r) xr4[r] = *(const float4*)&xnpadf[r * D + d4];
#pragma unroll
                for (int j = 0; j < 4; ++j) {
                    size_t o = (size_t)h * (D * 3) + (d4 + j) * 3;
                    float wk0 = ld1<ISBF>(w1raw, o), wk1 = ld1<ISBF>(w1raw, o+1), wk2 = ld1<ISBF>(w1raw, o+2);
#pragma unroll
                    for (int g = 0; g < G; ++g) {
                        acc[g] += f4c(xr4[g+0], j) * wk0;
                        acc[g] += f4c(xr4[g+1], j) * wk1;
                        acc[g] += f4c(xr4[g+2], j) * wk2;
                    }
                }
            }
            float b1h = ld1<ISBF>(b1, tid);
#pragma unroll
            for (int g = 0; g < G; ++g) {
                float m = acc[g] + b1h;
                midpadf[(g+1)*H + h] = 0.5f * m * (1.f + erff(m * 0.70710678118654752f));
            }
        }
        __syncthreads();
        {
            const int dd = tid & (D - 1);
            const int gh = tid >> 7;
            float acc2[4] = {0.f,0.f,0.f,0.f};
            for (int h4 = 0; h4 < H; h4 += 4) {
                float4 mr4[6];
#pragma unroll
                for (int r = 0; r < 6; ++r) mr4[r] = *(const float4*)&midpadf[(gh*4+r)*H + h4];
#pragma unroll
                for (int j = 0; j < 4; ++j) {
                    size_t o = (size_t)dd * (H * 3) + (h4 + j) * 3;
                    float wk0 = ld1<ISBF>(w2raw, o), wk1 = ld1<ISBF>(w2raw, o+1), wk2 = ld1<ISBF>(w2raw, o+2);
#pragma unroll
                    for (int jj = 0; jj < 4; ++jj) {
                        acc2[jj] += f4c(mr4[jj+0], j) * wk0;
                        acc2[jj] += f4c(mr4[jj+1], j) * wk1;
                        acc2[jj] += f4c(mr4[jj+2], j) * wk2;
                    }
                }
            }
            float b2d = ld1<ISBF>(b2, dd);
            float vz[4], s = 0.f, ss = 0.f;
#pragma unroll
            for (int j = 0; j < 4; ++j) {
                int e = (gh*4+j)*D + dd;
                float val = acc2[j] + b2d + resid[e];
                vz[j] = val; s += val; ss += val*val;
            }
#pragma unroll
            for (int m = 1; m < 64; m <<= 1) { s += __shfl_xor(s, m); ss += __shfl_xor(ss, m); }
            const int wid = tid >> 6;
            if ((tid & 63) == 0) { red[wid*2] = s; red[wid*2+1] = ss; }
            __syncthreads();
            float st = red[0]+red[2]+red[4]+red[6], sst = red[1]+red[3]+red[5]+red[7];
            float mean = st * (1.f/1024.f), var = sst * (1.f/1024.f) - mean*mean;
            float rstd = rsqrtf(var + 1e-5f);
#pragma unroll
            for (int j = 0; j < 4; ++j) {
                int e = (gh*4+j)*D + dd;
                zbuf[t][e] = (vz[j]-mean)*rstd*ld1<ISBF>(pack_g, e) + ld1<ISBF>(pack_b, e);
            }
        }
    }
    __syncthreads();
    {
        float accm[4][4];
#pragma unroll
        for (int t = 0; t < 4; ++t)
#pragma unroll
            for (int j = 0; j < 4; ++j) accm[t][j] = 0.f;
        for (int p4 = 0; p4 < PK; p4 += 4) {
            float4 z4[4];
#pragma unroll
            for (int t = 0; t < 4; ++t) z4[t] = *(const float4*)&zbuf[t][p4];
#pragma unroll
            for (int pp = 0; pp < 4; ++pp) {
                float4 w4 = ld4<ISBF>(Wm, (size_t)(p4 + pp) * DM + e0);
#pragma unroll
                for (int t = 0; t < 4; ++t) {
                    float zp = f4c(z4[t], pp);
                    accm[t][0] += zp * w4.x; accm[t][1] += zp * w4.y;
                    accm[t][2] += zp * w4.z; accm[t][3] += zp * w4.w;
                }
            }
        }
        float4 bm4 = ld4<ISBF>(bm, e0);
#pragma unroll
        for (int t = 0; t < 4; ++t) {
            const size_t tok = (size_t)blockIdx.x * 4 + t;
            st4<ISBF>(out, tok * DM + e0,
                      make_float4(accm[t][0]+bm4.x, accm[t][1]+bm4.y,
                                  accm[t][2]+bm4.z, accm[t][3]+bm4.w));
        }
    }
}

extern "C" void kernel_launch(void* const* d_in, const int* in_sizes, int n_in,
                              void* d_out, int out_size, void* d_ws, size_t ws_size,
                              hipStream_t stream) {
    const void* x   = d_in[0];
    const void* sg  = d_in[1];
    const void* sb  = d_in[2];
    const void* pg  = d_in[3];
    const void* pb  = d_in[4];
    const void* w1  = d_in[5];
    const void* b1  = d_in[6];
    const void* w2  = d_in[7];
    const void* b2  = d_in[8];
    const void* pkg = d_in[9];
    const void* pkb = d_in[10];
    const void* Wm  = d_in[11];
    const void* bm  = d_in[12];

    int* flag = (int*)d_ws;
    u16* base = (u16*)((char*)d_ws + 16);
    u16* w1p = base;                       // 98304 el
    u16* w2p = base + 98304;               // 98304 el
    u16* wmt = base + 196608;              // 1048576 el
    u16* zws = base + 196608 + 1048576;    // 16777216 el
    float* pf = (float*)(base + 18022400); // 5760 f32 params
    const size_t ws_needed = 16 + (size_t)18022400 * sizeof(u16) + PF_N * sizeof(float);

    detect_dtype<<<1, 256, 0, stream>>>(x, flag);

    if (ws_size >= ws_needed) {
        prep_mfma<<<640, 256, 0, stream>>>(w1, w2, Wm, pg, pb, b1, b2, pkg, pkb, bm,
                                           sg, sb, w1p, w2p, wmt, pf, flag);
        conv_fused<true ><<<NTOK / 8, 256, 0, stream>>>(x, zws, w1p, w2p, pf, flag);
        conv_fused<false><<<NTOK / 8, 256, 0, stream>>>(x, zws, w1p, w2p, pf, flag);
        gemm_out<<<(NTOK / 128) * (DM / 128), 256, 0, stream>>>(zws, wmt, pf + 2688, d_out, flag);
    } else {
        slotconv_scalar<true ><<<NTOK / 4, 256, 0, stream>>>(
            x, sg, sb, pg, pb, w1, b1, w2, b2, pkg, pkb, Wm, bm, d_out, flag);
        slotconv_scalar<false><<<NTOK / 4, 256, 0, stream>>>(
            x, sg, sb, pg, pb, w1, b1, w2, b2, pkg, pkb, Wm, bm, d_out, flag);
    }
}

// Round 16
// 285.788 us; speedup vs baseline: 1.0661x; 1.0105x over previous
//
#include <hip/hip_runtime.h>
#include <hip/hip_bf16.h>
#include <math.h>

typedef unsigned short u16;
typedef unsigned int   u32;
typedef __attribute__((ext_vector_type(8))) short short8;   // 8 bf16
typedef __attribute__((ext_vector_type(4))) float f32x4;    // MFMA acc

// Problem constants
constexpr int G  = 8;
constexpr int D  = 128;
constexpr int H  = 256;
constexpr int DM = 1024;
constexpr int PK = 1024;
constexpr int NTOK = 8 * 2048;   // 16384

// f32 param ws layout (floats): [0]pre_g(128) [128]pre_b(128) [256]b1(256)
// [512]b2(128) [640]pack_g(1024) [1664]pack_b(1024) [2688]bm(1024)
// [3712]gate=2*sigmoid(slot_gate)(1024) [4736]slot_bias(1024) -> 5760
constexpr int PF_N = 5760;

// ---------- scalar helpers ----------
__device__ __forceinline__ float bf2f(u16 u) {
    union { u32 i; float f; } v; v.i = ((u32)u) << 16; return v.f;
}
__device__ __forceinline__ u16 f2bf(float f) {
    union { float f; u32 i; } v; v.f = f;
    u32 x = v.i;
    return (u16)((x + 0x7fffu + ((x >> 16) & 1u)) >> 16);  // RNE
}
// packed f32x2 -> bf16x2 (RNE), single VALU op
__device__ __forceinline__ u32 pk_bf16(float lo, float hi) {
    u32 d;
    asm("v_cvt_pk_bf16_f32 %0, %1, %2" : "=v"(d) : "v"(lo), "v"(hi));
    return d;
}
__device__ __forceinline__ float f4c(const float4 v, int j) {
    return j == 0 ? v.x : j == 1 ? v.y : j == 2 ? v.z : v.w;
}
template <bool ISBF>
__device__ __forceinline__ float ld1(const void* p, size_t i) {
    if (ISBF) return bf2f(((const u16*)p)[i]);
    else      return ((const float*)p)[i];
}
template <bool ISBF>
__device__ __forceinline__ float4 ld4(const void* p, size_t i) {  // i % 4 == 0
    if (ISBF) {
        ushort4 v = *(const ushort4*)((const u16*)p + i);
        return make_float4(bf2f(v.x), bf2f(v.y), bf2f(v.z), bf2f(v.w));
    } else {
        return *(const float4*)((const float*)p + i);
    }
}
// runtime-dtype variants (uniform branch on flag) — OK for prologue/epilogue
// one-shot loads; NOT for hot loops (R12/R13: branchy x loads cost conv +36us)
__device__ __forceinline__ float ld1rt(const void* p, size_t i, bool isbf) {
    return isbf ? bf2f(((const u16*)p)[i]) : ((const float*)p)[i];
}
__device__ __forceinline__ float4 ld4rt(const void* p, size_t i, bool isbf) {
    if (isbf) {
        ushort4 v = *(const ushort4*)((const u16*)p + i);
        return make_float4(bf2f(v.x), bf2f(v.y), bf2f(v.z), bf2f(v.w));
    } else {
        return *(const float4*)((const float*)p + i);
    }
}
template <bool ISBF>
__device__ __forceinline__ void st4(void* p, size_t i, float4 v) {
    if (ISBF) {
        ushort4 o; o.x = f2bf(v.x); o.y = f2bf(v.y); o.z = f2bf(v.z); o.w = f2bf(v.w);
        *(ushort4*)((u16*)p + i) = o;
    } else {
        *(float4*)((float*)p + i) = v;
    }
}
__device__ __forceinline__ void st4rt(void* p, size_t i, float4 v, bool isbf) {
    if (isbf) {
        ushort4 o; o.x = f2bf(v.x); o.y = f2bf(v.y); o.z = f2bf(v.z); o.w = f2bf(v.w);
        *(ushort4*)((u16*)p + i) = o;
    } else {
        *(float4*)((float*)p + i) = v;
    }
}
// tanh-form GELU (max dev vs exact erf-GELU ~3e-4, tolerance 6.4e-2)
__device__ __forceinline__ float gelu_f(float v) {
    float u = v * (0.7978845608028654f + 0.0356774081f * v * v);
    float e = __expf(2.f * u);
    float th = 1.f - 2.f / (e + 1.f);
    return 0.5f * v * (1.f + th);
}
// async global->LDS, 16B per lane; LDS dest = wave-uniform base + lane*16
__device__ __forceinline__ void gload_lds16(const void* gp, void* lp) {
    __builtin_amdgcn_global_load_lds(
        (const __attribute__((address_space(1))) void*)gp,
        (__attribute__((address_space(3))) void*)lp, 16, 0, 0);
}

// ---------- dtype detect (proven R2) ----------
__global__ void detect_dtype(const void* xraw, int* flag) {
    __shared__ int cnt[256];
    const u32* xw = (const u32*)xraw;
    int tid = threadIdx.x, c = 0;
#pragma unroll
    for (int k = 0; k < 4; ++k) {
        u32 w = xw[tid * 4 + k];
#pragma unroll
        for (int h = 0; h < 2; ++h) {
            u16 u = (u16)(w >> (16 * h));
            int e = (u >> 7) & 0xFF;
            if ((u & 0x7FFF) == 0 || (e >= 112 && e <= 143)) ++c;
        }
    }
    cnt[tid] = c;
    __syncthreads();
    for (int s = 128; s > 0; s >>= 1) {
        if (tid < s) cnt[tid] += cnt[tid + s];
        __syncthreads();
    }
    if (tid == 0) flag[0] = (cnt[0] >= 1900) ? 1 : 0;
}

// ---------- MFMA-path weight prep (single dispatch, runtime isbf) ----------
// blocks [0,256): Wm -> wmt (WmT, bf16) via LDS 64x64 tile transpose
// blocks [256,640): fragment-major conv weights + f32 param conversion
// (incl. gate = 2*sigmoid(slot_gate) and slot_bias, both f32).
__global__ __launch_bounds__(256)
void prep_mfma(const void* __restrict__ w1, const void* __restrict__ w2,
               const void* __restrict__ Wm,
               const void* __restrict__ pre_g, const void* __restrict__ pre_b,
               const void* __restrict__ b1, const void* __restrict__ b2,
               const void* __restrict__ pkg, const void* __restrict__ pkb,
               const void* __restrict__ bm,
               const void* __restrict__ sg, const void* __restrict__ sb,
               u16* __restrict__ w1p, u16* __restrict__ w2p,
               u16* __restrict__ wmt, float* __restrict__ pf,
               const int* __restrict__ flag) {
    const bool isbf = (flag[0] != 0);
    __shared__ u16 tile[64][72];
    const int tid = threadIdx.x;
    if (blockIdx.x < 256) {
        const int kk0 = (blockIdx.x >> 4) * 64, n0 = (blockIdx.x & 15) * 64;
        const int r = tid >> 2, q = tid & 3;
#pragma unroll
        for (int j4 = 0; j4 < 4; ++j4) {
            float4 v = ld4rt(Wm, (size_t)(kk0 + r) * DM + n0 + q * 16 + j4 * 4, isbf);
            tile[r][q * 16 + j4 * 4 + 0] = f2bf(v.x);
            tile[r][q * 16 + j4 * 4 + 1] = f2bf(v.y);
            tile[r][q * 16 + j4 * 4 + 2] = f2bf(v.z);
            tile[r][q * 16 + j4 * 4 + 3] = f2bf(v.w);
        }
        __syncthreads();
        u16 op[16];
#pragma unroll
        for (int j = 0; j < 16; ++j) op[j] = tile[q * 16 + j][r];
        u16* dst = wmt + (size_t)(n0 + r) * DM + kk0 + q * 16;
        *(short8*)dst       = *(const short8*)&op[0];
        *(short8*)(dst + 8) = *(const short8*)&op[8];
        return;
    }
    int idx = (blockIdx.x - 256) * 256 + tid;
    if (idx < 3 * 4 * H * 32) {          // 98304 for each of w1p/w2p
        int jq = idx & 31;
        int t2 = idx >> 5;
        int h  = t2 & (H - 1);
        int ik = t2 >> 8;                // 0..11
        int kt1 = ik >> 2, kk1 = ik & 3;
        int dd = kk1 * 32 + jq;
        w1p[idx] = f2bf(ld1rt(w1, (size_t)(h * D + dd) * 3 + kt1, isbf));
        int d   = t2 & (D - 1);
        int ik2 = t2 >> 7;               // 0..23
        int kt2 = ik2 >> 3, kk2 = ik2 & 7;
        int hh = kk2 * 32 + jq;
        w2p[idx] = f2bf(ld1rt(w2, (size_t)(d * H + hh) * 3 + kt2, isbf));
    }
    if (idx < D) {
        pf[idx]       = ld1rt(pre_g, idx, isbf);
        pf[128 + idx] = ld1rt(pre_b, idx, isbf);
        pf[512 + idx] = ld1rt(b2, idx, isbf);
    }
    if (idx < H) pf[256 + idx] = ld1rt(b1, idx, isbf);
    if (idx < PK) {
        pf[640  + idx] = ld1rt(pkg, idx, isbf);
        pf[1664 + idx] = ld1rt(pkb, idx, isbf);
        pf[2688 + idx] = ld1rt(bm, idx, isbf);
        pf[3712 + idx] = 2.f / (1.f + __expf(-ld1rt(sg, idx, isbf)));
        pf[4736 + idx] = ld1rt(sb, idx, isbf);
    }
}

// ---------- fused gate+LN1+conv1+GELU+conv2+LN2 : x -> z (bf16, into zws) ----------
// R16: two latency-hiding edits inside the R14/R15-proven config:
//  (1) stage-1 BATCH-ISSUES all 8 x loads before the LN chains (+32 VGPR,
//      no AGPRs live in stage 1 -> fits the 170-reg cap of (256,3));
//  (2) epilogue x re-reads issued BEFORE the conv2 MFMA loop (T14
//      issue-early; loads are independent of the MFMAs, held ~150 regs).
// Everything else PROVEN: templated x-loads, gate from f32 pf, (256,3),
// WRITE 33MB clean. FALSIFIER: WRITE > 40MB = spill -> revert both edits.
// LDS union uni[74*256 u16] (37888 B):
//   xnpad rows 0..72: r*128 | midpad M_lo r*256 | M_hi r*256+256
template <bool ISBF>
__global__ __launch_bounds__(256, 3)
void conv_fused(const void* __restrict__ x,
                u16* __restrict__ zout,
                const u16* __restrict__ w1p,
                const u16* __restrict__ w2p,
                const float* __restrict__ pf,
                const int* __restrict__ flag) {
    if ((flag[0] != 0) != ISBF) return;
    __shared__ u16 uni[74 * 256];          // 37888 B union
    __shared__ float red_s[8][4], red_ss[8][4];

    const int tid  = threadIdx.x;
    const int lane = tid & 63, w = tid >> 6;
    const int quad = lane >> 4, col = lane & 15;
    const size_t tok0 = (size_t)blockIdx.x * 8;

    const int e0 = 4 * tid;
    const int d0 = e0 & (D - 1);
    const int g0 = tid >> 5;

    // ---- stage 1a: BATCH-ISSUE all 8 x loads (hide HBM latency) ----
    float4 xs[8];
#pragma unroll
    for (int t = 0; t < 8; ++t)
        xs[t] = ld4<ISBF>(x, (tok0 + t) * PK + e0);

    // ---- stage 0: zero xnpad halo rows (9 x 128) + M_hi halo rows {45,54,63,72} ----
    if (tid < 72) {
        int li = tid * 16, hr = li >> 7, e = li & 127;
        u16* p = &uni[hr * 9 * 128 + e];
#pragma unroll
        for (int q = 0; q < 4; ++q) *(ushort4*)(p + 4 * q) = make_ushort4(0, 0, 0, 0);
    } else if (tid >= 128) {
        int li = (tid - 128) * 8, hr = li >> 8, e = li & 255;
        int row = 45 + hr * 9;                       // 45,54,63,72
        u16* p = &uni[row * 256 + 256 + e];          // M_hi mapping
        *(ushort4*)p       = make_ushort4(0, 0, 0, 0);
        *(ushort4*)(p + 4) = make_ushort4(0, 0, 0, 0);
    }

    float4 gg   = *(const float4*)(pf + 3712 + e0);   // 2*sigmoid(slot_gate)
    float4 sbb  = *(const float4*)(pf + 4736 + e0);   // slot_bias
    float4 pg4s = *(const float4*)(pf + d0);          // pre_g
    float4 pb4s = *(const float4*)(pf + 128 + d0);    // pre_b

    // ---- stage 1b: gate+bias (f32), LN1 -> xnpad (bf16, swizzled) ----
#pragma unroll
    for (int t = 0; t < 8; ++t) {
        float v[4];
#pragma unroll
        for (int j = 0; j < 4; ++j) v[j] = f4c(xs[t], j) * f4c(gg, j) + f4c(sbb, j);
        float s = v[0] + v[1] + v[2] + v[3];
        float ss = v[0]*v[0] + v[1]*v[1] + v[2]*v[2] + v[3]*v[3];
#pragma unroll
        for (int m = 1; m < 32; m <<= 1) {
            s  += __shfl_xor(s,  m);
            ss += __shfl_xor(ss, m);
        }
        float mean = s * (1.f / 128.f);
        float var  = ss * (1.f / 128.f) - mean * mean;
        float rstd = rsqrtf(var + 1e-5f);
        uint2 o;
        o.x = pk_bf16((v[0] - mean) * rstd * pg4s.x + pb4s.x,
                      (v[1] - mean) * rstd * pg4s.y + pb4s.y);
        o.y = pk_bf16((v[2] - mean) * rstd * pg4s.z + pb4s.z,
                      (v[3] - mean) * rstd * pg4s.w + pb4s.w);
        int row  = t * 9 + g0 + 1;
        int addr = row * 128 + (((d0 >> 3) ^ (row & 7)) << 3) + (d0 & 7);
        *(uint2*)&uni[addr] = o;
    }
    __syncthreads();

    int rowb[4];
#pragma unroll
    for (int nt = 0; nt < 4; ++nt) {
        int n = nt * 16 + col;
        rowb[nt] = (n >> 3) * 9 + (n & 7);
    }
    const int alane1 = (w * 64 + col) * 32 + quad * 8;
    const int alane2 = (w * 32 + col) * 32 + quad * 8;

    // ---- stage 2: conv1 via MFMA, two nt-passes (32-AGPR live acc each) ----
#pragma unroll
    for (int pass = 0; pass < 2; ++pass) {
        const int ntb = (pass == 0) ? 2 : 0;
        f32x4 acc[4][2] = {};
#pragma unroll
        for (int it = 0; it < 12; ++it) {
            const int ktap = it >> 2, kk = it & 3;
            short8 afr[4];
#pragma unroll
            for (int mtl = 0; mtl < 4; ++mtl)
                afr[mtl] = *(const short8*)(w1p + it * 8192 + mtl * 512 + alane1);
            short8 bfr[2];
#pragma unroll
            for (int ntl = 0; ntl < 2; ++ntl) {
                int rr = rowb[ntb + ntl] + ktap;
                int a  = rr * 128 + (((kk * 4 + quad) ^ (rr & 7)) << 3);
                bfr[ntl] = *(const short8*)&uni[a];
            }
#pragma unroll
            for (int mtl = 0; mtl < 4; ++mtl)
#pragma unroll
                for (int ntl = 0; ntl < 2; ++ntl)
                    acc[mtl][ntl] = __builtin_amdgcn_mfma_f32_16x16x32_bf16(
                        afr[mtl], bfr[ntl], acc[mtl][ntl], 0, 0, 0);
        }
        if (pass == 1) {
            __syncthreads();
            if (tid < 160) {
                int li = tid * 8, hr = li >> 8, e = li & 255;
                u16* p = &uni[hr * 9 * 256 + e];
                *(ushort4*)p       = make_ushort4(0, 0, 0, 0);
                *(ushort4*)(p + 4) = make_ushort4(0, 0, 0, 0);
            }
        }
#pragma unroll
        for (int mtl = 0; mtl < 4; ++mtl) {
            int hq = w * 64 + mtl * 16 + quad * 4;
            float4 b1q = *(const float4*)(pf + 256 + hq);
#pragma unroll
            for (int ntl = 0; ntl < 2; ++ntl) {
                int row = rowb[ntb + ntl] + 1;
                uint2 o;
                o.x = pk_bf16(gelu_f(acc[mtl][ntl][0] + b1q.x),
                              gelu_f(acc[mtl][ntl][1] + b1q.y));
                o.y = pk_bf16(gelu_f(acc[mtl][ntl][2] + b1q.z),
                              gelu_f(acc[mtl][ntl][3] + b1q.w));
                int mb = row * 256 + ((row >= 37) ? 256 : 0);
                int a  = mb + (((hq >> 3) ^ (row & 7)) << 3) + (hq & 7);
                *(uint2*)&uni[a] = o;
            }
        }
    }
    __syncthreads();

    // ---- stage 3a: issue-early epilogue x re-reads (T14; L2-hot, hide
    //      their latency under the conv2 MFMA loop) ----
    float4 xr_pre[2][4];
#pragma unroll
    for (int mtl = 0; mtl < 2; ++mtl) {
        int dq = w * 32 + mtl * 16 + quad * 4;
#pragma unroll
        for (int nt = 0; nt < 4; ++nt) {
            int n = nt * 16 + col; int t = n >> 3, g = n & 7;
            xr_pre[mtl][nt] = ld4<ISBF>(x, (tok0 + t) * PK + g * D + dq);
        }
    }

    // ---- stage 3b: conv2 via MFMA ----
    f32x4 acc2[2][4] = {};
#pragma unroll
    for (int it = 0; it < 24; ++it) {
        const int ktap = it >> 3, kk = it & 7;
        short8 cfr[2];
#pragma unroll
        for (int mtl = 0; mtl < 2; ++mtl)
            cfr[mtl] = *(const short8*)(w2p + it * 4096 + mtl * 512 + alane2);
        short8 bfr[4];
#pragma unroll
        for (int nt = 0; nt < 4; ++nt) {
            int rr = rowb[nt] + ktap;
            int mb = rr * 256 + ((rr >= 37) ? 256 : 0);
            int a  = mb + (((kk * 4 + quad) ^ (rr & 7)) << 3);
            bfr[nt] = *(const short8*)&uni[a];
        }
#pragma unroll
        for (int mtl = 0; mtl < 2; ++mtl)
#pragma unroll
            for (int nt = 0; nt < 4; ++nt)
                acc2[mtl][nt] = __builtin_amdgcn_mfma_f32_16x16x32_bf16(
                    cfr[mtl], bfr[nt], acc2[mtl][nt], 0, 0, 0);
    }
    {
        float vals[2][4][4];
        float s[4] = {0.f, 0.f, 0.f, 0.f}, ss[4] = {0.f, 0.f, 0.f, 0.f};
#pragma unroll
        for (int mtl = 0; mtl < 2; ++mtl) {
            int dq = w * 32 + mtl * 16 + quad * 4;
            float4 b2q = *(const float4*)(pf + 512 + dq);
#pragma unroll
            for (int nt = 0; nt < 4; ++nt) {
                int n = nt * 16 + col; int g = n & 7;
                int e = g * D + dq;
                float4 xr = xr_pre[mtl][nt];
                float4 gq = *(const float4*)(pf + 3712 + e);
                float4 bq = *(const float4*)(pf + 4736 + e);
#pragma unroll
                for (int r = 0; r < 4; ++r) {
                    float resid = f4c(xr, r) * f4c(gq, r) + f4c(bq, r);
                    float val = acc2[mtl][nt][r] + f4c(b2q, r) + resid;
                    vals[mtl][nt][r] = val;
                    s[nt] += val; ss[nt] += val * val;
                }
            }
        }
        // reduce over lanes sharing token t: masks {1,2,4,16,32}
#pragma unroll
        for (int nt = 0; nt < 4; ++nt) {
            s[nt] += __shfl_xor(s[nt], 1);  ss[nt] += __shfl_xor(ss[nt], 1);
            s[nt] += __shfl_xor(s[nt], 2);  ss[nt] += __shfl_xor(ss[nt], 2);
            s[nt] += __shfl_xor(s[nt], 4);  ss[nt] += __shfl_xor(ss[nt], 4);
            s[nt] += __shfl_xor(s[nt], 16); ss[nt] += __shfl_xor(ss[nt], 16);
            s[nt] += __shfl_xor(s[nt], 32); ss[nt] += __shfl_xor(ss[nt], 32);
        }
        if (quad == 0 && (col & 7) == 0) {
#pragma unroll
            for (int nt = 0; nt < 4; ++nt) {
                int t = 2 * nt + (col >> 3);
                red_s[t][w] = s[nt]; red_ss[t][w] = ss[nt];
            }
        }
        __syncthreads();
        float mean[4], rstd[4];
#pragma unroll
        for (int nt = 0; nt < 4; ++nt) {
            int t = 2 * nt + (col >> 3);
            float st  = red_s[t][0] + red_s[t][1] + red_s[t][2] + red_s[t][3];
            float sst = red_ss[t][0] + red_ss[t][1] + red_ss[t][2] + red_ss[t][3];
            mean[nt] = st * (1.f / 1024.f);
            float var = sst * (1.f / 1024.f) - mean[nt] * mean[nt];
            rstd[nt] = rsqrtf(var + 1e-5f);
        }
#pragma unroll
        for (int mtl = 0; mtl < 2; ++mtl) {
            int dq = w * 32 + mtl * 16 + quad * 4;
#pragma unroll
            for (int nt = 0; nt < 4; ++nt) {
                int n = nt * 16 + col; int t = n >> 3, g = n & 7;
                int e = g * D + dq;
                float4 pg4 = *(const float4*)(pf + 640 + e);
                float4 pb4 = *(const float4*)(pf + 1664 + e);
                float zv[4];
#pragma unroll
                for (int r = 0; r < 4; ++r)
                    zv[r] = (vals[mtl][nt][r] - mean[nt]) * rstd[nt] * f4c(pg4, r)
                            + f4c(pb4, r);
                uint2 o;
                o.x = pk_bf16(zv[0], zv[1]);
                o.y = pk_bf16(zv[2], zv[3]);
                *(uint2*)(zout + (tok0 + t) * PK + e) = o;
            }
        }
    }
}

// ---------- z @ Wm + bm via MFMA ----------
// R15-PROVEN: (256,4) — footprint ~104 fits 128-reg cap, LDS 32KB x 4 =
// 128KB, grid 1024 = exactly one dispatch wave. BK=64 single-buffer,
// 32 MFMA/barrier-drain, both-sides chunk-XOR swizzle.
__global__ __launch_bounds__(256, 4)
void gemm_out(const u16* __restrict__ z, const u16* __restrict__ wmt,
              const float* __restrict__ bmf, void* __restrict__ out,
              const int* __restrict__ flag) {
    const bool isbf = (flag[0] != 0);
    __shared__ u16 As[128 * 64];   // z tile   [m][k], chunk-swizzled contents
    __shared__ u16 Bs[128 * 64];   // WmT tile [n][k], chunk-swizzled contents
    const int tid = threadIdx.x, lane = tid & 63, w = tid >> 6;
    const int quad = lane >> 4, col = lane & 15;
    // XCD-bijective swizzle (nwg = 1024, % 8 == 0)
    const int swz = ((blockIdx.x & 7) << 7) | ((int)blockIdx.x >> 3);
    const int bm0 = (swz >> 3) * 128, bn0 = (swz & 7) * 128;
    const int wm = w >> 1, wn = w & 1;
    f32x4 acc[4][4] = {};            // [nt][mt]

    const u16* zrow0 = z   + (size_t)bm0 * DM;
    const u16* wrow0 = wmt + (size_t)bn0 * DM;

    for (int k0 = 0; k0 < DM; k0 += 64) {
#pragma unroll
        for (int q = 0; q < 4; ++q) {
            int c = q * 256 + tid;
            int r = c >> 3;                    // row 0..127
            int jj = (c & 7) ^ (r & 7);        // pre-swizzled source chunk
            const int ldsoff = (q * 256 + w * 64) * 8;   // wave-uniform, u16
            gload_lds16(zrow0 + (size_t)r * DM + k0 + jj * 8, &As[ldsoff]);
            gload_lds16(wrow0 + (size_t)r * DM + k0 + jj * 8, &Bs[ldsoff]);
        }
        __syncthreads();   // vmcnt(0) drain + barrier: tile ready
#pragma unroll
        for (int kk = 0; kk < 2; ++kk) {
            short8 zfr[4], wfr[4];
#pragma unroll
            for (int mt = 0; mt < 4; ++mt) {
                int row = wm * 64 + mt * 16 + col;
                zfr[mt] = *(const short8*)
                    &As[row * 64 + (((kk * 4 + quad) ^ (row & 7)) << 3)];
            }
#pragma unroll
            for (int nt = 0; nt < 4; ++nt) {
                int row = wn * 64 + nt * 16 + col;
                wfr[nt] = *(const short8*)
                    &Bs[row * 64 + (((kk * 4 + quad) ^ (row & 7)) << 3)];
            }
#pragma unroll
            for (int nt = 0; nt < 4; ++nt)
#pragma unroll
                for (int mt = 0; mt < 4; ++mt)
                    acc[nt][mt] = __builtin_amdgcn_mfma_f32_16x16x32_bf16(
                        wfr[nt], zfr[mt], acc[nt][mt], 0, 0, 0);
        }
        __syncthreads();   // all reads done before next stage overwrites
    }
    // epilogue: C rows = n (quad*4+r), cols = m
#pragma unroll
    for (int nt = 0; nt < 4; ++nt) {
        int n = bn0 + wn * 64 + nt * 16 + quad * 4;
        float4 bq = *(const float4*)(bmf + n);
#pragma unroll
        for (int mt = 0; mt < 4; ++mt) {
            int m = bm0 + wm * 64 + mt * 16 + col;
            float4 o = make_float4(acc[nt][mt][0] + bq.x, acc[nt][mt][1] + bq.y,
                                   acc[nt][mt][2] + bq.z, acc[nt][mt][3] + bq.w);
            st4rt(out, (size_t)m * DM + n, o, isbf);
        }
    }
}

// ---------- scalar fallback (R2-proven), raw weights ----------
template <bool ISBF>
__global__ __launch_bounds__(256)
void slotconv_scalar(const void* __restrict__ x,
                     const void* __restrict__ slot_gate,
                     const void* __restrict__ slot_bias,
                     const void* __restrict__ pre_g,
                     const void* __restrict__ pre_b,
                     const void* __restrict__ w1raw,
                     const void* __restrict__ b1,
                     const void* __restrict__ w2raw,
                     const void* __restrict__ b2,
                     const void* __restrict__ pack_g,
                     const void* __restrict__ pack_b,
                     const void* __restrict__ Wm,
                     const void* __restrict__ bm,
                     void* __restrict__ out,
                     const int* __restrict__ flag) {
    if ((flag[0] != 0) != ISBF) return;
    __shared__ float resid[G * D];
    __shared__ float xnpadf[(G + 2) * D];
    __shared__ float midpadf[(G + 2) * H];
    __shared__ float zbuf[4][PK];
    __shared__ float red[8];
    const int tid = threadIdx.x;
    if (tid < D) { xnpadf[tid] = 0.f; xnpadf[(G + 1) * D + tid] = 0.f; }
    midpadf[tid] = 0.f; midpadf[(G + 1) * H + tid] = 0.f;
    const int e0 = 4 * tid;
    const int d0 = e0 & (D - 1);
    const int g0 = tid >> 5;
    float gate[4], bias[4], pgf[4], pbf[4];
    {
        float4 sg4 = ld4<ISBF>(slot_gate, e0);
        float4 sb4 = ld4<ISBF>(slot_bias, e0);
        float4 pg4 = ld4<ISBF>(pre_g, d0);
        float4 pb4 = ld4<ISBF>(pre_b, d0);
#pragma unroll
        for (int j = 0; j < 4; ++j) {
            gate[j] = 2.f / (1.f + __expf(-f4c(sg4, j)));
            bias[j] = f4c(sb4, j);
            pgf[j] = f4c(pg4, j); pbf[j] = f4c(pb4, j);
        }
    }
    for (int t = 0; t < 4; ++t) {
        __syncthreads();
        const size_t tok = (size_t)blockIdx.x * 4 + t;
        {
            float4 x4 = ld4<ISBF>(x, tok * PK + e0);
            float v[4];
#pragma unroll
            for (int j = 0; j < 4; ++j) v[j] = f4c(x4, j) * gate[j] + bias[j];
            *(float4*)&resid[e0] = make_float4(v[0], v[1], v[2], v[3]);
            float s = v[0]+v[1]+v[2]+v[3], ss = v[0]*v[0]+v[1]*v[1]+v[2]*v[2]+v[3]*v[3];
#pragma unroll
            for (int m = 1; m < 32; m <<= 1) { s += __shfl_xor(s, m); ss += __shfl_xor(ss, m); }
            float mean = s * (1.f/128.f), var = ss * (1.f/128.f) - mean*mean;
            float rstd = rsqrtf(var + 1e-5f);
            float xn[4];
#pragma unroll
            for (int j = 0; j < 4; ++j) xn[j] = (v[j]-mean)*rstd*pgf[j]+pbf[j];
            *(float4*)&xnpadf[(g0+1)*D + d0] = make_float4(xn[0],xn[1],xn[2],xn[3]);
        }
        __syncthreads();
        {
            const int h = tid;
            float acc[G];
#pragma unroll
            for (int g = 0; g < G; ++g) acc[g] = 0.f;
            for (int d4 = 0; d4 < D; d4 += 4) {
                float4 xr4[G + 2];
#pragma unroll
                for (int r = 0; r < G + 2; ++r) xr4[r] = *(const float4*)&xnpadf[r * D + d4];
#pragma unroll
                for (int j = 0; j < 4; ++j) {
                    size_t o = (size_t)h * (D * 3) + (d4 + j) * 3;
                    float wk0 = ld1<ISBF>(w1raw, o), wk1 = ld1<ISBF>(w1raw, o+1), wk2 = ld1<ISBF>(w1raw, o+2);
#pragma unroll
                    for (int g = 0; g < G; ++g) {
                        acc[g] += f4c(xr4[g+0], j) * wk0;
                        acc[g] += f4c(xr4[g+1], j) * wk1;
                        acc[g] += f4c(xr4[g+2], j) * wk2;
                    }
                }
            }
            float b1h = ld1<ISBF>(b1, tid);
#pragma unroll
            for (int g = 0; g < G; ++g) {
                float m = acc[g] + b1h;
                midpadf[(g+1)*H + h] = 0.5f * m * (1.f + erff(m * 0.70710678118654752f));
            }
        }
        __syncthreads();
        {
            const int dd = tid & (D - 1);
            const int gh = tid >> 7;
            float acc2[4] = {0.f,0.f,0.f,0.f};
            for (int h4 = 0; h4 < H; h4 += 4) {
                float4 mr4[6];
#pragma unroll
                for (int r = 0; r < 6; ++r) mr4[r] = *(const float4*)&midpadf[(gh*4+r)*H + h4];
#pragma unroll
                for (int j = 0; j < 4; ++j) {
                    size_t o = (size_t)dd * (H * 3) + (h4 + j) * 3;
                    float wk0 = ld1<ISBF>(w2raw, o), wk1 = ld1<ISBF>(w2raw, o+1), wk2 = ld1<ISBF>(w2raw, o+2);
#pragma unroll
                    for (int jj = 0; jj < 4; ++jj) {
                        acc2[jj] += f4c(mr4[jj+0], j) * wk0;
                        acc2[jj] += f4c(mr4[jj+1], j) * wk1;
                        acc2[jj] += f4c(mr4[jj+2], j) * wk2;
                    }
                }
            }
            float b2d = ld1<ISBF>(b2, dd);
            float vz[4], s = 0.f, ss = 0.f;
#pragma unroll
            for (int j = 0; j < 4; ++j) {
                int e = (gh*4+j)*D + dd;
                float val = acc2[j] + b2d + resid[e];
                vz[j] = val; s += val; ss += val*val;
            }
#pragma unroll
            for (int m = 1; m < 64; m <<= 1) { s += __shfl_xor(s, m); ss += __shfl_xor(ss, m); }
            const int wid = tid >> 6;
            if ((tid & 63) == 0) { red[wid*2] = s; red[wid*2+1] = ss; }
            __syncthreads();
            float st = red[0]+red[2]+red[4]+red[6], sst = red[1]+red[3]+red[5]+red[7];
            float mean = st * (1.f/1024.f), var = sst * (1.f/1024.f) - mean*mean;
            float rstd = rsqrtf(var + 1e-5f);
#pragma unroll
            for (int j = 0; j < 4; ++j) {
                int e = (gh*4+j)*D + dd;
                zbuf[t][e] = (vz[j]-mean)*rstd*ld1<ISBF>(pack_g, e) + ld1<ISBF>(pack_b, e);
            }
        }
    }
    __syncthreads();
    {
        float accm[4][4];
#pragma unroll
        for (int t = 0; t < 4; ++t)
#pragma unroll
            for (int j = 0; j < 4; ++j) accm[t][j] = 0.f;
        for (int p4 = 0; p4 < PK; p4 += 4) {
            float4 z4[4];
#pragma unroll
            for (int t = 0; t < 4; ++t) z4[t] = *(const float4*)&zbuf[t][p4];
#pragma unroll
            for (int pp = 0; pp < 4; ++pp) {
                float4 w4 = ld4<ISBF>(Wm, (size_t)(p4 + pp) * DM + e0);
#pragma unroll
                for (int t = 0; t < 4; ++t) {
                    float zp = f4c(z4[t], pp);
                    accm[t][0] += zp * w4.x; accm[t][1] += zp * w4.y;
                    accm[t][2] += zp * w4.z; accm[t][3] += zp * w4.w;
                }
            }
        }
        float4 bm4 = ld4<ISBF>(bm, e0);
#pragma unroll
        for (int t = 0; t < 4; ++t) {
            const size_t tok = (size_t)blockIdx.x * 4 + t;
            st4<ISBF>(out, tok * DM + e0,
                      make_float4(accm[t][0]+bm4.x, accm[t][1]+bm4.y,
                                  accm[t][2]+bm4.z, accm[t][3]+bm4.w));
        }
    }
}

extern "C" void kernel_launch(void* const* d_in, const int* in_sizes, int n_in,
                              void* d_out, int out_size, void* d_ws, size_t ws_size,
                              hipStream_t stream) {
    const void* x   = d_in[0];
    const void* sg  = d_in[1];
    const void* sb  = d_in[2];
    const void* pg  = d_in[3];
    const void* pb  = d_in[4];
    const void* w1  = d_in[5];
    const void* b1  = d_in[6];
    const void* w2  = d_in[7];
    const void* b2  = d_in[8];
    const void* pkg = d_in[9];
    const void* pkb = d_in[10];
    const void* Wm  = d_in[11];
    const void* bm  = d_in[12];

    int* flag = (int*)d_ws;
    u16* base = (u16*)((char*)d_ws + 16);
    u16* w1p = base;                       // 98304 el
    u16* w2p = base + 98304;               // 98304 el
    u16* wmt = base + 196608;              // 1048576 el
    u16* zws = base + 196608 + 1048576;    // 16777216 el
    float* pf = (float*)(base + 18022400); // 5760 f32 params
    const size_t ws_needed = 16 + (size_t)18022400 * sizeof(u16) + PF_N * sizeof(float);

    detect_dtype<<<1, 256, 0, stream>>>(x, flag);

    if (ws_size >= ws_needed) {
        prep_mfma<<<640, 256, 0, stream>>>(w1, w2, Wm, pg, pb, b1, b2, pkg, pkb, bm,
                                           sg, sb, w1p, w2p, wmt, pf, flag);
        conv_fused<true ><<<NTOK / 8, 256, 0, stream>>>(x, zws, w1p, w2p, pf, flag);
        conv_fused<false><<<NTOK / 8, 256, 0, stream>>>(x, zws, w1p, w2p, pf, flag);
        gemm_out<<<(NTOK / 128) * (DM / 128), 256, 0, stream>>>(zws, wmt, pf + 2688, d_out, flag);
    } else {
        slotconv_scalar<true ><<<NTOK / 4, 256, 0, stream>>>(
            x, sg, sb, pg, pb, w1, b1, w2, b2, pkg, pkb, Wm, bm, d_out, flag);
        slotconv_scalar<false><<<NTOK / 4, 256, 0, stream>>>(
            x, sg, sb, pg, pb, w1, b1, w2, b2, pkg, pkb, Wm, bm, d_out, flag);
    }
}

// Round 17
// 283.497 us; speedup vs baseline: 1.0747x; 1.0081x over previous
//
#include <hip/hip_runtime.h>
#include <hip/hip_bf16.h>
#include <math.h>

typedef unsigned short u16;
typedef unsigned int   u32;
typedef __attribute__((ext_vector_type(8))) short short8;   // 8 bf16
typedef __attribute__((ext_vector_type(4))) float f32x4;    // MFMA acc

// Problem constants
constexpr int G  = 8;
constexpr int D  = 128;
constexpr int H  = 256;
constexpr int DM = 1024;
constexpr int PK = 1024;
constexpr int NTOK = 8 * 2048;   // 16384

// f32 param ws layout (floats): [0]pre_g(128) [128]pre_b(128) [256]b1(256)
// [512]b2(128) [640]pack_g(1024) [1664]pack_b(1024) [2688]bm(1024)
// [3712]gate=2*sigmoid(slot_gate)(1024) [4736]slot_bias(1024) -> 5760
constexpr int PF_N = 5760;

// ---------- scalar helpers ----------
__device__ __forceinline__ float bf2f(u16 u) {
    union { u32 i; float f; } v; v.i = ((u32)u) << 16; return v.f;
}
__device__ __forceinline__ u16 f2bf(float f) {
    union { float f; u32 i; } v; v.f = f;
    u32 x = v.i;
    return (u16)((x + 0x7fffu + ((x >> 16) & 1u)) >> 16);  // RNE
}
// packed f32x2 -> bf16x2 (RNE), single VALU op
__device__ __forceinline__ u32 pk_bf16(float lo, float hi) {
    u32 d;
    asm("v_cvt_pk_bf16_f32 %0, %1, %2" : "=v"(d) : "v"(lo), "v"(hi));
    return d;
}
__device__ __forceinline__ float f4c(const float4 v, int j) {
    return j == 0 ? v.x : j == 1 ? v.y : j == 2 ? v.z : v.w;
}
template <bool ISBF>
__device__ __forceinline__ float ld1(const void* p, size_t i) {
    if (ISBF) return bf2f(((const u16*)p)[i]);
    else      return ((const float*)p)[i];
}
template <bool ISBF>
__device__ __forceinline__ float4 ld4(const void* p, size_t i) {  // i % 4 == 0
    if (ISBF) {
        ushort4 v = *(const ushort4*)((const u16*)p + i);
        return make_float4(bf2f(v.x), bf2f(v.y), bf2f(v.z), bf2f(v.w));
    } else {
        return *(const float4*)((const float*)p + i);
    }
}
// runtime-dtype variants (uniform branch) — OK for one-shot loads;
// NOT for hot loops (R12/R13: branchy x loads cost conv +36us)
__device__ __forceinline__ float ld1rt(const void* p, size_t i, bool isbf) {
    return isbf ? bf2f(((const u16*)p)[i]) : ((const float*)p)[i];
}
__device__ __forceinline__ float4 ld4rt(const void* p, size_t i, bool isbf) {
    if (isbf) {
        ushort4 v = *(const ushort4*)((const u16*)p + i);
        return make_float4(bf2f(v.x), bf2f(v.y), bf2f(v.z), bf2f(v.w));
    } else {
        return *(const float4*)((const float*)p + i);
    }
}
template <bool ISBF>
__device__ __forceinline__ void st4(void* p, size_t i, float4 v) {
    if (ISBF) {
        ushort4 o; o.x = f2bf(v.x); o.y = f2bf(v.y); o.z = f2bf(v.z); o.w = f2bf(v.w);
        *(ushort4*)((u16*)p + i) = o;
    } else {
        *(float4*)((float*)p + i) = v;
    }
}
__device__ __forceinline__ void st4rt(void* p, size_t i, float4 v, bool isbf) {
    if (isbf) {
        ushort4 o; o.x = f2bf(v.x); o.y = f2bf(v.y); o.z = f2bf(v.z); o.w = f2bf(v.w);
        *(ushort4*)((u16*)p + i) = o;
    } else {
        *(float4*)((float*)p + i) = v;
    }
}
// tanh-form GELU (max dev vs exact erf-GELU ~3e-4, tolerance 6.4e-2)
__device__ __forceinline__ float gelu_f(float v) {
    float u = v * (0.7978845608028654f + 0.0356774081f * v * v);
    float e = __expf(2.f * u);
    float th = 1.f - 2.f / (e + 1.f);
    return 0.5f * v * (1.f + th);
}
// async global->LDS, 16B per lane; LDS dest = wave-uniform base + lane*16
__device__ __forceinline__ void gload_lds16(const void* gp, void* lp) {
    __builtin_amdgcn_global_load_lds(
        (const __attribute__((address_space(1))) void*)gp,
        (__attribute__((address_space(3))) void*)lp, 16, 0, 0);
}

// in-block dtype detection (R17: detect_dtype folded into prep — each block
// recomputes from x's first 4KB; deterministic, identical in all blocks).
__device__ __forceinline__ bool detect_isbf(const void* xraw, int* cnt) {
    const u32* xw = (const u32*)xraw;
    const int tid = threadIdx.x;
    int c = 0;
#pragma unroll
    for (int k = 0; k < 4; ++k) {
        u32 w = xw[tid * 4 + k];
#pragma unroll
        for (int h = 0; h < 2; ++h) {
            u16 u = (u16)(w >> (16 * h));
            int e = (u >> 7) & 0xFF;
            if ((u & 0x7FFF) == 0 || (e >= 112 && e <= 143)) ++c;
        }
    }
    cnt[tid] = c;
    __syncthreads();
    for (int s = 128; s > 0; s >>= 1) {
        if (tid < s) cnt[tid] += cnt[tid + s];
        __syncthreads();
    }
    bool isbf = (cnt[0] >= 1900);
    __syncthreads();           // cnt reusable afterwards
    return isbf;
}

// ---------- MFMA-path weight prep (single dispatch; in-block detect) ----------
// blocks [0,256): Wm -> wmt (WmT, bf16) via LDS 64x64 tile transpose
// blocks [256,640): fragment-major conv weights + f32 param conversion
// (incl. gate = 2*sigmoid(slot_gate) and slot_bias, both f32).
// Block 0 writes flag for the downstream conv/gemm kernels.
__global__ __launch_bounds__(256)
void prep_mfma(const void* __restrict__ x,
               const void* __restrict__ w1, const void* __restrict__ w2,
               const void* __restrict__ Wm,
               const void* __restrict__ pre_g, const void* __restrict__ pre_b,
               const void* __restrict__ b1, const void* __restrict__ b2,
               const void* __restrict__ pkg, const void* __restrict__ pkb,
               const void* __restrict__ bm,
               const void* __restrict__ sg, const void* __restrict__ sb,
               u16* __restrict__ w1p, u16* __restrict__ w2p,
               u16* __restrict__ wmt, float* __restrict__ pf,
               int* __restrict__ flag) {
    __shared__ int cnt[256];
    __shared__ u16 tile[64][72];
    const int tid = threadIdx.x;
    const bool isbf = detect_isbf(x, cnt);
    if (blockIdx.x == 0 && tid == 0) flag[0] = isbf ? 1 : 0;
    if (blockIdx.x < 256) {
        const int kk0 = (blockIdx.x >> 4) * 64, n0 = (blockIdx.x & 15) * 64;
        const int r = tid >> 2, q = tid & 3;
#pragma unroll
        for (int j4 = 0; j4 < 4; ++j4) {
            float4 v = ld4rt(Wm, (size_t)(kk0 + r) * DM + n0 + q * 16 + j4 * 4, isbf);
            tile[r][q * 16 + j4 * 4 + 0] = f2bf(v.x);
            tile[r][q * 16 + j4 * 4 + 1] = f2bf(v.y);
            tile[r][q * 16 + j4 * 4 + 2] = f2bf(v.z);
            tile[r][q * 16 + j4 * 4 + 3] = f2bf(v.w);
        }
        __syncthreads();
        u16 op[16];
#pragma unroll
        for (int j = 0; j < 16; ++j) op[j] = tile[q * 16 + j][r];
        u16* dst = wmt + (size_t)(n0 + r) * DM + kk0 + q * 16;
        *(short8*)dst       = *(const short8*)&op[0];
        *(short8*)(dst + 8) = *(const short8*)&op[8];
        return;
    }
    int idx = (blockIdx.x - 256) * 256 + tid;
    if (idx < 3 * 4 * H * 32) {          // 98304 for each of w1p/w2p
        int jq = idx & 31;
        int t2 = idx >> 5;
        int h  = t2 & (H - 1);
        int ik = t2 >> 8;                // 0..11
        int kt1 = ik >> 2, kk1 = ik & 3;
        int dd = kk1 * 32 + jq;
        w1p[idx] = f2bf(ld1rt(w1, (size_t)(h * D + dd) * 3 + kt1, isbf));
        int d   = t2 & (D - 1);
        int ik2 = t2 >> 7;               // 0..23
        int kt2 = ik2 >> 3, kk2 = ik2 & 7;
        int hh = kk2 * 32 + jq;
        w2p[idx] = f2bf(ld1rt(w2, (size_t)(d * H + hh) * 3 + kt2, isbf));
    }
    if (idx < D) {
        pf[idx]       = ld1rt(pre_g, idx, isbf);
        pf[128 + idx] = ld1rt(pre_b, idx, isbf);
        pf[512 + idx] = ld1rt(b2, idx, isbf);
    }
    if (idx < H) pf[256 + idx] = ld1rt(b1, idx, isbf);
    if (idx < PK) {
        pf[640  + idx] = ld1rt(pkg, idx, isbf);
        pf[1664 + idx] = ld1rt(pkb, idx, isbf);
        pf[2688 + idx] = ld1rt(bm, idx, isbf);
        pf[3712 + idx] = 2.f / (1.f + __expf(-ld1rt(sg, idx, isbf)));
        pf[4736 + idx] = ld1rt(sb, idx, isbf);
    }
}

// ---------- fused gate+LN1+conv1+GELU+conv2+LN2 : x -> z (bf16, into zws) ----------
// R16-PROVEN (285.8 total, conv ~131us, WRITE 33MB clean):
//  - templated x-loads (runtime-branch loads cost +36us: R12/R13 A/B)
//  - stage-1 batch-issues all 8 x loads; epilogue x re-reads issued BEFORE
//    the conv2 MFMA loop (T14 issue-early)
//  - (256,3); (256,4) spills (R6/R9). Twin dispatch; ghost early-exits.
// LDS union uni[74*256 u16] (37888 B):
//   xnpad rows 0..72: r*128 | midpad M_lo r*256 | M_hi r*256+256
template <bool ISBF>
__global__ __launch_bounds__(256, 3)
void conv_fused(const void* __restrict__ x,
                u16* __restrict__ zout,
                const u16* __restrict__ w1p,
                const u16* __restrict__ w2p,
                const float* __restrict__ pf,
                const int* __restrict__ flag) {
    if ((flag[0] != 0) != ISBF) return;
    __shared__ u16 uni[74 * 256];          // 37888 B union
    __shared__ float red_s[8][4], red_ss[8][4];

    const int tid  = threadIdx.x;
    const int lane = tid & 63, w = tid >> 6;
    const int quad = lane >> 4, col = lane & 15;
    const size_t tok0 = (size_t)blockIdx.x * 8;

    const int e0 = 4 * tid;
    const int d0 = e0 & (D - 1);
    const int g0 = tid >> 5;

    // ---- stage 1a: BATCH-ISSUE all 8 x loads (hide HBM latency) ----
    float4 xs[8];
#pragma unroll
    for (int t = 0; t < 8; ++t)
        xs[t] = ld4<ISBF>(x, (tok0 + t) * PK + e0);

    // ---- stage 0: zero xnpad halo rows (9 x 128) + M_hi halo rows {45,54,63,72} ----
    if (tid < 72) {
        int li = tid * 16, hr = li >> 7, e = li & 127;
        u16* p = &uni[hr * 9 * 128 + e];
#pragma unroll
        for (int q = 0; q < 4; ++q) *(ushort4*)(p + 4 * q) = make_ushort4(0, 0, 0, 0);
    } else if (tid >= 128) {
        int li = (tid - 128) * 8, hr = li >> 8, e = li & 255;
        int row = 45 + hr * 9;                       // 45,54,63,72
        u16* p = &uni[row * 256 + 256 + e];          // M_hi mapping
        *(ushort4*)p       = make_ushort4(0, 0, 0, 0);
        *(ushort4*)(p + 4) = make_ushort4(0, 0, 0, 0);
    }

    float4 gg   = *(const float4*)(pf + 3712 + e0);   // 2*sigmoid(slot_gate)
    float4 sbb  = *(const float4*)(pf + 4736 + e0);   // slot_bias
    float4 pg4s = *(const float4*)(pf + d0);          // pre_g
    float4 pb4s = *(const float4*)(pf + 128 + d0);    // pre_b

    // ---- stage 1b: gate+bias (f32), LN1 -> xnpad (bf16, swizzled) ----
#pragma unroll
    for (int t = 0; t < 8; ++t) {
        float v[4];
#pragma unroll
        for (int j = 0; j < 4; ++j) v[j] = f4c(xs[t], j) * f4c(gg, j) + f4c(sbb, j);
        float s = v[0] + v[1] + v[2] + v[3];
        float ss = v[0]*v[0] + v[1]*v[1] + v[2]*v[2] + v[3]*v[3];
#pragma unroll
        for (int m = 1; m < 32; m <<= 1) {
            s  += __shfl_xor(s,  m);
            ss += __shfl_xor(ss, m);
        }
        float mean = s * (1.f / 128.f);
        float var  = ss * (1.f / 128.f) - mean * mean;
        float rstd = rsqrtf(var + 1e-5f);
        uint2 o;
        o.x = pk_bf16((v[0] - mean) * rstd * pg4s.x + pb4s.x,
                      (v[1] - mean) * rstd * pg4s.y + pb4s.y);
        o.y = pk_bf16((v[2] - mean) * rstd * pg4s.z + pb4s.z,
                      (v[3] - mean) * rstd * pg4s.w + pb4s.w);
        int row  = t * 9 + g0 + 1;
        int addr = row * 128 + (((d0 >> 3) ^ (row & 7)) << 3) + (d0 & 7);
        *(uint2*)&uni[addr] = o;
    }
    __syncthreads();

    int rowb[4];
#pragma unroll
    for (int nt = 0; nt < 4; ++nt) {
        int n = nt * 16 + col;
        rowb[nt] = (n >> 3) * 9 + (n & 7);
    }
    const int alane1 = (w * 64 + col) * 32 + quad * 8;
    const int alane2 = (w * 32 + col) * 32 + quad * 8;

    // ---- stage 2: conv1 via MFMA, two nt-passes (32-AGPR live acc each) ----
#pragma unroll
    for (int pass = 0; pass < 2; ++pass) {
        const int ntb = (pass == 0) ? 2 : 0;
        f32x4 acc[4][2] = {};
#pragma unroll
        for (int it = 0; it < 12; ++it) {
            const int ktap = it >> 2, kk = it & 3;
            short8 afr[4];
#pragma unroll
            for (int mtl = 0; mtl < 4; ++mtl)
                afr[mtl] = *(const short8*)(w1p + it * 8192 + mtl * 512 + alane1);
            short8 bfr[2];
#pragma unroll
            for (int ntl = 0; ntl < 2; ++ntl) {
                int rr = rowb[ntb + ntl] + ktap;
                int a  = rr * 128 + (((kk * 4 + quad) ^ (rr & 7)) << 3);
                bfr[ntl] = *(const short8*)&uni[a];
            }
#pragma unroll
            for (int mtl = 0; mtl < 4; ++mtl)
#pragma unroll
                for (int ntl = 0; ntl < 2; ++ntl)
                    acc[mtl][ntl] = __builtin_amdgcn_mfma_f32_16x16x32_bf16(
                        afr[mtl], bfr[ntl], acc[mtl][ntl], 0, 0, 0);
        }
        if (pass == 1) {
            __syncthreads();
            if (tid < 160) {
                int li = tid * 8, hr = li >> 8, e = li & 255;
                u16* p = &uni[hr * 9 * 256 + e];
                *(ushort4*)p       = make_ushort4(0, 0, 0, 0);
                *(ushort4*)(p + 4) = make_ushort4(0, 0, 0, 0);
            }
        }
#pragma unroll
        for (int mtl = 0; mtl < 4; ++mtl) {
            int hq = w * 64 + mtl * 16 + quad * 4;
            float4 b1q = *(const float4*)(pf + 256 + hq);
#pragma unroll
            for (int ntl = 0; ntl < 2; ++ntl) {
                int row = rowb[ntb + ntl] + 1;
                uint2 o;
                o.x = pk_bf16(gelu_f(acc[mtl][ntl][0] + b1q.x),
                              gelu_f(acc[mtl][ntl][1] + b1q.y));
                o.y = pk_bf16(gelu_f(acc[mtl][ntl][2] + b1q.z),
                              gelu_f(acc[mtl][ntl][3] + b1q.w));
                int mb = row * 256 + ((row >= 37) ? 256 : 0);
                int a  = mb + (((hq >> 3) ^ (row & 7)) << 3) + (hq & 7);
                *(uint2*)&uni[a] = o;
            }
        }
    }
    __syncthreads();

    // ---- stage 3a: issue-early epilogue x re-reads (T14; L2-hot) ----
    float4 xr_pre[2][4];
#pragma unroll
    for (int mtl = 0; mtl < 2; ++mtl) {
        int dq = w * 32 + mtl * 16 + quad * 4;
#pragma unroll
        for (int nt = 0; nt < 4; ++nt) {
            int n = nt * 16 + col; int t = n >> 3, g = n & 7;
            xr_pre[mtl][nt] = ld4<ISBF>(x, (tok0 + t) * PK + g * D + dq);
        }
    }

    // ---- stage 3b: conv2 via MFMA ----
    f32x4 acc2[2][4] = {};
#pragma unroll
    for (int it = 0; it < 24; ++it) {
        const int ktap = it >> 3, kk = it & 7;
        short8 cfr[2];
#pragma unroll
        for (int mtl = 0; mtl < 2; ++mtl)
            cfr[mtl] = *(const short8*)(w2p + it * 4096 + mtl * 512 + alane2);
        short8 bfr[4];
#pragma unroll
        for (int nt = 0; nt < 4; ++nt) {
            int rr = rowb[nt] + ktap;
            int mb = rr * 256 + ((rr >= 37) ? 256 : 0);
            int a  = mb + (((kk * 4 + quad) ^ (rr & 7)) << 3);
            bfr[nt] = *(const short8*)&uni[a];
        }
#pragma unroll
        for (int mtl = 0; mtl < 2; ++mtl)
#pragma unroll
            for (int nt = 0; nt < 4; ++nt)
                acc2[mtl][nt] = __builtin_amdgcn_mfma_f32_16x16x32_bf16(
                    cfr[mtl], bfr[nt], acc2[mtl][nt], 0, 0, 0);
    }
    {
        float vals[2][4][4];
        float s[4] = {0.f, 0.f, 0.f, 0.f}, ss[4] = {0.f, 0.f, 0.f, 0.f};
#pragma unroll
        for (int mtl = 0; mtl < 2; ++mtl) {
            int dq = w * 32 + mtl * 16 + quad * 4;
            float4 b2q = *(const float4*)(pf + 512 + dq);
#pragma unroll
            for (int nt = 0; nt < 4; ++nt) {
                int n = nt * 16 + col; int g = n & 7;
                int e = g * D + dq;
                float4 xr = xr_pre[mtl][nt];
                float4 gq = *(const float4*)(pf + 3712 + e);
                float4 bq = *(const float4*)(pf + 4736 + e);
#pragma unroll
                for (int r = 0; r < 4; ++r) {
                    float resid = f4c(xr, r) * f4c(gq, r) + f4c(bq, r);
                    float val = acc2[mtl][nt][r] + f4c(b2q, r) + resid;
                    vals[mtl][nt][r] = val;
                    s[nt] += val; ss[nt] += val * val;
                }
            }
        }
        // reduce over lanes sharing token t: masks {1,2,4,16,32}
#pragma unroll
        for (int nt = 0; nt < 4; ++nt) {
            s[nt] += __shfl_xor(s[nt], 1);  ss[nt] += __shfl_xor(ss[nt], 1);
            s[nt] += __shfl_xor(s[nt], 2);  ss[nt] += __shfl_xor(ss[nt], 2);
            s[nt] += __shfl_xor(s[nt], 4);  ss[nt] += __shfl_xor(ss[nt], 4);
            s[nt] += __shfl_xor(s[nt], 16); ss[nt] += __shfl_xor(ss[nt], 16);
            s[nt] += __shfl_xor(s[nt], 32); ss[nt] += __shfl_xor(ss[nt], 32);
        }
        if (quad == 0 && (col & 7) == 0) {
#pragma unroll
            for (int nt = 0; nt < 4; ++nt) {
                int t = 2 * nt + (col >> 3);
                red_s[t][w] = s[nt]; red_ss[t][w] = ss[nt];
            }
        }
        __syncthreads();
        float mean[4], rstd[4];
#pragma unroll
        for (int nt = 0; nt < 4; ++nt) {
            int t = 2 * nt + (col >> 3);
            float st  = red_s[t][0] + red_s[t][1] + red_s[t][2] + red_s[t][3];
            float sst = red_ss[t][0] + red_ss[t][1] + red_ss[t][2] + red_ss[t][3];
            mean[nt] = st * (1.f / 1024.f);
            float var = sst * (1.f / 1024.f) - mean[nt] * mean[nt];
            rstd[nt] = rsqrtf(var + 1e-5f);
        }
#pragma unroll
        for (int mtl = 0; mtl < 2; ++mtl) {
            int dq = w * 32 + mtl * 16 + quad * 4;
#pragma unroll
            for (int nt = 0; nt < 4; ++nt) {
                int n = nt * 16 + col; int t = n >> 3, g = n & 7;
                int e = g * D + dq;
                float4 pg4 = *(const float4*)(pf + 640 + e);
                float4 pb4 = *(const float4*)(pf + 1664 + e);
                float zv[4];
#pragma unroll
                for (int r = 0; r < 4; ++r)
                    zv[r] = (vals[mtl][nt][r] - mean[nt]) * rstd[nt] * f4c(pg4, r)
                            + f4c(pb4, r);
                uint2 o;
                o.x = pk_bf16(zv[0], zv[1]);
                o.y = pk_bf16(zv[2], zv[3]);
                *(uint2*)(zout + (tok0 + t) * PK + e) = o;
            }
        }
    }
}

// ---------- z @ Wm + bm via MFMA ----------
// R15-PROVEN: (256,4) — footprint ~104 fits 128-reg cap, LDS 32KB x 4 =
// 128KB, grid 1024 = exactly one dispatch wave. BK=64 single-buffer,
// 32 MFMA/barrier-drain, both-sides chunk-XOR swizzle.
__global__ __launch_bounds__(256, 4)
void gemm_out(const u16* __restrict__ z, const u16* __restrict__ wmt,
              const float* __restrict__ bmf, void* __restrict__ out,
              const int* __restrict__ flag) {
    const bool isbf = (flag[0] != 0);
    __shared__ u16 As[128 * 64];   // z tile   [m][k], chunk-swizzled contents
    __shared__ u16 Bs[128 * 64];   // WmT tile [n][k], chunk-swizzled contents
    const int tid = threadIdx.x, lane = tid & 63, w = tid >> 6;
    const int quad = lane >> 4, col = lane & 15;
    // XCD-bijective swizzle (nwg = 1024, % 8 == 0)
    const int swz = ((blockIdx.x & 7) << 7) | ((int)blockIdx.x >> 3);
    const int bm0 = (swz >> 3) * 128, bn0 = (swz & 7) * 128;
    const int wm = w >> 1, wn = w & 1;
    f32x4 acc[4][4] = {};            // [nt][mt]

    const u16* zrow0 = z   + (size_t)bm0 * DM;
    const u16* wrow0 = wmt + (size_t)bn0 * DM;

    for (int k0 = 0; k0 < DM; k0 += 64) {
#pragma unroll
        for (int q = 0; q < 4; ++q) {
            int c = q * 256 + tid;
            int r = c >> 3;                    // row 0..127
            int jj = (c & 7) ^ (r & 7);        // pre-swizzled source chunk
            const int ldsoff = (q * 256 + w * 64) * 8;   // wave-uniform, u16
            gload_lds16(zrow0 + (size_t)r * DM + k0 + jj * 8, &As[ldsoff]);
            gload_lds16(wrow0 + (size_t)r * DM + k0 + jj * 8, &Bs[ldsoff]);
        }
        __syncthreads();   // vmcnt(0) drain + barrier: tile ready
#pragma unroll
        for (int kk = 0; kk < 2; ++kk) {
            short8 zfr[4], wfr[4];
#pragma unroll
            for (int mt = 0; mt < 4; ++mt) {
                int row = wm * 64 + mt * 16 + col;
                zfr[mt] = *(const short8*)
                    &As[row * 64 + (((kk * 4 + quad) ^ (row & 7)) << 3)];
            }
#pragma unroll
            for (int nt = 0; nt < 4; ++nt) {
                int row = wn * 64 + nt * 16 + col;
                wfr[nt] = *(const short8*)
                    &Bs[row * 64 + (((kk * 4 + quad) ^ (row & 7)) << 3)];
            }
#pragma unroll
            for (int nt = 0; nt < 4; ++nt)
#pragma unroll
                for (int mt = 0; mt < 4; ++mt)
                    acc[nt][mt] = __builtin_amdgcn_mfma_f32_16x16x32_bf16(
                        wfr[nt], zfr[mt], acc[nt][mt], 0, 0, 0);
        }
        __syncthreads();   // all reads done before next stage overwrites
    }
    // epilogue: C rows = n (quad*4+r), cols = m
#pragma unroll
    for (int nt = 0; nt < 4; ++nt) {
        int n = bn0 + wn * 64 + nt * 16 + quad * 4;
        float4 bq = *(const float4*)(bmf + n);
#pragma unroll
        for (int mt = 0; mt < 4; ++mt) {
            int m = bm0 + wm * 64 + mt * 16 + col;
            float4 o = make_float4(acc[nt][mt][0] + bq.x, acc[nt][mt][1] + bq.y,
                                   acc[nt][mt][2] + bq.z, acc[nt][mt][3] + bq.w);
            st4rt(out, (size_t)m * DM + n, o, isbf);
        }
    }
}

// ---------- scalar fallback (R2-proven), raw weights ----------
template <bool ISBF>
__global__ __launch_bounds__(256)
void slotconv_scalar(const void* __restrict__ x,
                     const void* __restrict__ slot_gate,
                     const void* __restrict__ slot_bias,
                     const void* __restrict__ pre_g,
                     const void* __restrict__ pre_b,
                     const void* __restrict__ w1raw,
                     const void* __restrict__ b1,
                     const void* __restrict__ w2raw,
                     const void* __restrict__ b2,
                     const void* __restrict__ pack_g,
                     const void* __restrict__ pack_b,
                     const void* __restrict__ Wm,
                     const void* __restrict__ bm,
                     void* __restrict__ out,
                     int* __restrict__ flag) {
    __shared__ int cnt[256];
    const bool isbf_det = detect_isbf(x, cnt);
    if ((isbf_det) != ISBF) return;
    __shared__ float resid[G * D];
    __shared__ float xnpadf[(G + 2) * D];
    __shared__ float midpadf[(G + 2) * H];
    __shared__ float zbuf[4][PK];
    __shared__ float red[8];
    const int tid = threadIdx.x;
    if (tid < D) { xnpadf[tid] = 0.f; xnpadf[(G + 1) * D + tid] = 0.f; }
    midpadf[tid] = 0.f; midpadf[(G + 1) * H + tid] = 0.f;
    const int e0 = 4 * tid;
    const int d0 = e0 & (D - 1);
    const int g0 = tid >> 5;
    float gate[4], bias[4], pgf[4], pbf[4];
    {
        float4 sg4 = ld4<ISBF>(slot_gate, e0);
        float4 sb4 = ld4<ISBF>(slot_bias, e0);
        float4 pg4 = ld4<ISBF>(pre_g, d0);
        float4 pb4 = ld4<ISBF>(pre_b, d0);
#pragma unroll
        for (int j = 0; j < 4; ++j) {
            gate[j] = 2.f / (1.f + __expf(-f4c(sg4, j)));
            bias[j] = f4c(sb4, j);
            pgf[j] = f4c(pg4, j); pbf[j] = f4c(pb4, j);
        }
    }
    for (int t = 0; t < 4; ++t) {
        __syncthreads();
        const size_t tok = (size_t)blockIdx.x * 4 + t;
        {
            float4 x4 = ld4<ISBF>(x, tok * PK + e0);
            float v[4];
#pragma unroll
            for (int j = 0; j < 4; ++j) v[j] = f4c(x4, j) * gate[j] + bias[j];
            *(float4*)&resid[e0] = make_float4(v[0], v[1], v[2], v[3]);
            float s = v[0]+v[1]+v[2]+v[3], ss = v[0]*v[0]+v[1]*v[1]+v[2]*v[2]+v[3]*v[3];
#pragma unroll
            for (int m = 1; m < 32; m <<= 1) { s += __shfl_xor(s, m); ss += __shfl_xor(ss, m); }
            float mean = s * (1.f/128.f), var = ss * (1.f/128.f) - mean*mean;
            float rstd = rsqrtf(var + 1e-5f);
            float xn[4];
#pragma unroll
            for (int j = 0; j < 4; ++j) xn[j] = (v[j]-mean)*rstd*pgf[j]+pbf[j];
            *(float4*)&xnpadf[(g0+1)*D + d0] = make_float4(xn[0],xn[1],xn[2],xn[3]);
        }
        __syncthreads();
        {
            const int h = tid;
            float acc[G];
#pragma unroll
            for (int g = 0; g < G; ++g) acc[g] = 0.f;
            for (int d4 = 0; d4 < D; d4 += 4) {
                float4 xr4[G + 2];
#pragma unroll
                for (int r = 0; r < G + 2; ++r) xr4[r] = *(const float4*)&xnpadf[r * D + d4];
#pragma unroll
                for (int j = 0; j < 4; ++j) {
                    size_t o = (size_t)h * (D * 3) + (d4 + j) * 3;
                    float wk0 = ld1<ISBF>(w1raw, o), wk1 = ld1<ISBF>(w1raw, o+1), wk2 = ld1<ISBF>(w1raw, o+2);
#pragma unroll
                    for (int g = 0; g < G; ++g) {
                        acc[g] += f4c(xr4[g+0], j) * wk0;
                        acc[g] += f4c(xr4[g+1], j) * wk1;
                        acc[g] += f4c(xr4[g+2], j) * wk2;
                    }
                }
            }
            float b1h = ld1<ISBF>(b1, tid);
#pragma unroll
            for (int g = 0; g < G; ++g) {
                float m = acc[g] + b1h;
                midpadf[(g+1)*H + h] = 0.5f * m * (1.f + erff(m * 0.70710678118654752f));
            }
        }
        __syncthreads();
        {
            const int dd = tid & (D - 1);
            const int gh = tid >> 7;
            float acc2[4] = {0.f,0.f,0.f,0.f};
            for (int h4 = 0; h4 < H; h4 += 4) {
                float4 mr4[6];
#pragma unroll
                for (int r = 0; r < 6; ++r) mr4[r] = *(const float4*)&midpadf[(gh*4+r)*H + h4];
#pragma unroll
                for (int j = 0; j < 4; ++j) {
                    size_t o = (size_t)dd * (H * 3) + (h4 + j) * 3;
                    float wk0 = ld1<ISBF>(w2raw, o), wk1 = ld1<ISBF>(w2raw, o+1), wk2 = ld1<ISBF>(w2raw, o+2);
#pragma unroll
                    for (int jj = 0; jj < 4; ++jj) {
                        acc2[jj] += f4c(mr4[jj+0], j) * wk0;
                        acc2[jj] += f4c(mr4[jj+1], j) * wk1;
                        acc2[jj] += f4c(mr4[jj+2], j) * wk2;
                    }
                }
            }
            float b2d = ld1<ISBF>(b2, dd);
            float vz[4], s = 0.f, ss = 0.f;
#pragma unroll
            for (int j = 0; j < 4; ++j) {
                int e = (gh*4+j)*D + dd;
                float val = acc2[j] + b2d + resid[e];
                vz[j] = val; s += val; ss += val*val;
            }
#pragma unroll
            for (int m = 1; m < 64; m <<= 1) { s += __shfl_xor(s, m); ss += __shfl_xor(ss, m); }
            const int wid = tid >> 6;
            if ((tid & 63) == 0) { red[wid*2] = s; red[wid*2+1] = ss; }
            __syncthreads();
            float st = red[0]+red[2]+red[4]+red[6], sst = red[1]+red[3]+red[5]+red[7];
            float mean = st * (1.f/1024.f), var = sst * (1.f/1024.f) - mean*mean;
            float rstd = rsqrtf(var + 1e-5f);
#pragma unroll
            for (int j = 0; j < 4; ++j) {
                int e = (gh*4+j)*D + dd;
                zbuf[t][e] = (vz[j]-mean)*rstd*ld1<ISBF>(pack_g, e) + ld1<ISBF>(pack_b, e);
            }
        }
    }
    __syncthreads();
    {
        float accm[4][4];
#pragma unroll
        for (int t = 0; t < 4; ++t)
#pragma unroll
            for (int j = 0; j < 4; ++j) accm[t][j] = 0.f;
        for (int p4 = 0; p4 < PK; p4 += 4) {
            float4 z4[4];
#pragma unroll
            for (int t = 0; t < 4; ++t) z4[t] = *(const float4*)&zbuf[t][p4];
#pragma unroll
            for (int pp = 0; pp < 4; ++pp) {
                float4 w4 = ld4<ISBF>(Wm, (size_t)(p4 + pp) * DM + e0);
#pragma unroll
                for (int t = 0; t < 4; ++t) {
                    float zp = f4c(z4[t], pp);
                    accm[t][0] += zp * w4.x; accm[t][1] += zp * w4.y;
                    accm[t][2] += zp * w4.z; accm[t][3] += zp * w4.w;
                }
            }
        }
        float4 bm4 = ld4<ISBF>(bm, e0);
#pragma unroll
        for (int t = 0; t < 4; ++t) {
            const size_t tok = (size_t)blockIdx.x * 4 + t;
            st4<ISBF>(out, tok * DM + e0,
                      make_float4(accm[t][0]+bm4.x, accm[t][1]+bm4.y,
                                  accm[t][2]+bm4.z, accm[t][3]+bm4.w));
        }
    }
}

extern "C" void kernel_launch(void* const* d_in, const int* in_sizes, int n_in,
                              void* d_out, int out_size, void* d_ws, size_t ws_size,
                              hipStream_t stream) {
    const void* x   = d_in[0];
    const void* sg  = d_in[1];
    const void* sb  = d_in[2];
    const void* pg  = d_in[3];
    const void* pb  = d_in[4];
    const void* w1  = d_in[5];
    const void* b1  = d_in[6];
    const void* w2  = d_in[7];
    const void* b2  = d_in[8];
    const void* pkg = d_in[9];
    const void* pkb = d_in[10];
    const void* Wm  = d_in[11];
    const void* bm  = d_in[12];

    int* flag = (int*)d_ws;
    u16* base = (u16*)((char*)d_ws + 16);
    u16* w1p = base;                       // 98304 el
    u16* w2p = base + 98304;               // 98304 el
    u16* wmt = base + 196608;              // 1048576 el
    u16* zws = base + 196608 + 1048576;    // 16777216 el
    float* pf = (float*)(base + 18022400); // 5760 f32 params
    const size_t ws_needed = 16 + (size_t)18022400 * sizeof(u16) + PF_N * sizeof(float);

    if (ws_size >= ws_needed) {
        // R17: detect folded into prep (in-block recompute; block 0 writes
        // flag for conv/gemm) — one fewer serialized dispatch.
        prep_mfma<<<640, 256, 0, stream>>>(x, w1, w2, Wm, pg, pb, b1, b2, pkg, pkb,
                                           bm, sg, sb, w1p, w2p, wmt, pf, flag);
        conv_fused<true ><<<NTOK / 8, 256, 0, stream>>>(x, zws, w1p, w2p, pf, flag);
        conv_fused<false><<<NTOK / 8, 256, 0, stream>>>(x, zws, w1p, w2p, pf, flag);
        gemm_out<<<(NTOK / 128) * (DM / 128), 256, 0, stream>>>(zws, wmt, pf + 2688, d_out, flag);
    } else {
        slotconv_scalar<true ><<<NTOK / 4, 256, 0, stream>>>(
            x, sg, sb, pg, pb, w1, b1, w2, b2, pkg, pkb, Wm, bm, d_out, flag);
        slotconv_scalar<false><<<NTOK / 4, 256, 0, stream>>>(
            x, sg, sb, pg, pb, w1, b1, w2, b2, pkg, pkb, Wm, bm, d_out, flag);
    }
}